// Round 4
// baseline (236.482 us; speedup 1.0000x reference)
//
#include <hip/hip_runtime.h>
#include <math.h>

#define NB   2
#define CIN  256
#define NN   6400
#define CKd  64
#define CVd  128
#define COd  256

using bf16   = __bf16;
using bf16x4 = __attribute__((ext_vector_type(4))) bf16;
using bf16x8 = __attribute__((ext_vector_type(8))) bf16;
using f32x4  = __attribute__((ext_vector_type(4))) float;

__device__ __forceinline__ void lds_cp16(const bf16* g, bf16* l) {
    __builtin_amdgcn_global_load_lds((const __attribute__((address_space(1))) void*)g,
                                     (__attribute__((address_space(3))) void*)l, 16, 0, 0);
}

// ---------------------------------------------------------------------------
// Fold BN into bf16 weights + fp32 biases.
// ---------------------------------------------------------------------------
__global__ void prep_kernel(const float* __restrict__ fk_w, const float* __restrict__ fk_g,
                            const float* __restrict__ fk_b, const float* __restrict__ fk_m,
                            const float* __restrict__ fk_v,
                            const float* __restrict__ fq_w, const float* __restrict__ fq_g,
                            const float* __restrict__ fq_b, const float* __restrict__ fq_m,
                            const float* __restrict__ fq_v,
                            const float* __restrict__ fv_w, const float* __restrict__ fv_b,
                            const float* __restrict__ W_w,  const float* __restrict__ W_b,
                            bf16* __restrict__ wkb, bf16* __restrict__ wqb,
                            bf16* __restrict__ wvb, bf16* __restrict__ wob,
                            float* __restrict__ bias)
{
    const int idx = blockIdx.x * 256 + threadIdx.x;
    if (idx < 16384) {
        const int co = idx >> 8;
        const float a = fk_g[co] * rsqrtf(fk_v[co] + 1e-5f);
        wkb[idx] = (bf16)(fk_w[idx] * a);
    } else if (idx < 32768) {
        const int i = idx - 16384, co = i >> 8;
        const float a = fq_g[co] * rsqrtf(fq_v[co] + 1e-5f) * 0.125f;
        wqb[i] = (bf16)(fq_w[i] * a);
    } else if (idx < 65536) {
        const int i = idx - 32768;
        wvb[i] = (bf16)fv_w[i];
    } else if (idx < 98304) {
        const int i = idx - 65536;
        wob[i] = (bf16)W_w[i];
    } else if (idx < 98816) {
        const int j = idx - 98304;
        if (j < 64)       { const float a = fk_g[j] * rsqrtf(fk_v[j] + 1e-5f); bias[j] = fk_b[j] - fk_m[j] * a; }
        else if (j < 128) { const int c = j - 64; const float a = fq_g[c] * rsqrtf(fq_v[c] + 1e-5f); bias[j] = (fq_b[c] - fq_m[c] * a) * 0.125f; }
        else if (j < 256) bias[j] = fv_b[j - 128];
        else              bias[j] = W_b[j - 256];
    }
}

// ---------------------------------------------------------------------------
// x,y [b][256][6400] f32 -> xT,yT [b][6400][256] bf16
// ---------------------------------------------------------------------------
__launch_bounds__(256)
__global__ void tcvt_kernel(const float* __restrict__ x, const float* __restrict__ y,
                            bf16* __restrict__ xT, bf16* __restrict__ yT)
{
    __shared__ __align__(16) bf16 t_lds[64][68];
    const int b = blockIdx.z & 1;
    const float* src = (blockIdx.z >> 1) ? y : x;
    bf16* dst = (blockIdx.z >> 1) ? yT : xT;
    const int n0 = blockIdx.x * 64, c0 = blockIdx.y * 64;
    const int tid = threadIdx.x;
    const int nl = (tid & 15) * 4;
#pragma unroll
    for (int p = 0; p < 4; ++p) {
        const int cl = (tid >> 4) + p * 16;
        const float4 v = *(const float4*)(src + (size_t)(b * CIN + c0 + cl) * NN + n0 + nl);
        t_lds[nl + 0][cl] = (bf16)v.x;
        t_lds[nl + 1][cl] = (bf16)v.y;
        t_lds[nl + 2][cl] = (bf16)v.z;
        t_lds[nl + 3][cl] = (bf16)v.w;
    }
    __syncthreads();
#pragma unroll
    for (int p = 0; p < 4; ++p) {
        const int u = tid + p * 256;
        const int n = u >> 4, c4 = (u & 15) * 4;
        const bf16x4 pk = *(const bf16x4*)&t_lds[n][c4];
        *(bf16x4*)(dst + ((size_t)b * NN + n0 + n) * CIN + c0 + c4) = pk;
    }
}

// ---------------------------------------------------------------------------
// k/q/v projections with LDS-staged src+weight tiles (global_load_lds DMA,
// source-side XOR swizzle so fragment ds_read_b128 is conflict-free).
// grid (100, 4, NB): y=0 k (x->kb[n][64]), y=1 q, y=2,3 v (->vb[cv][n]).
// LDS 64KB -> 2 blocks/CU.
// ---------------------------------------------------------------------------
__launch_bounds__(256, 2)
__global__ void projkqv_kernel(const bf16* __restrict__ xT, const bf16* __restrict__ yT,
                               const bf16* __restrict__ wkb, const bf16* __restrict__ wqb,
                               const bf16* __restrict__ wvb, const float* __restrict__ bias,
                               bf16* __restrict__ kb, bf16* __restrict__ qb, bf16* __restrict__ vb)
{
    __shared__ __align__(16) bf16 sbuf[64 * 256];   // src rows (n), swizzled
    __shared__ __align__(16) bf16 wbuf[64 * 256];   // weight rows, swizzled

    const int tid  = threadIdx.x;
    const int lane = tid & 63, wav = tid >> 6;
    const int l15  = lane & 15, quad = lane >> 4;
    const int b    = blockIdx.z, m = blockIdx.y;
    const int n0   = blockIdx.x * 64;

    const bf16* srcg = ((m == 0) ? xT : yT) + ((size_t)b * NN + n0) * CIN;
    const bf16* wg   = (m == 0) ? wkb : (m == 1) ? wqb : (wvb + (size_t)(m - 2) * 64 * CIN);

    // ---- DMA stage: lds[r][c16] = g[r][c16 ^ (r&7)]  (rows 512B, 2 rows/inst)
    const int r2  = lane >> 5;        // row within 2-row group
    const int c32 = lane & 31;        // 16B chunk within row
#pragma unroll
    for (int i = 0; i < 8; ++i) {
        const int rg = wav * 16 + i * 2;          // group base row (wave-uniform)
        const int r  = rg + r2;
        const int cs = c32 ^ (r & 7);
        lds_cp16(srcg + (size_t)r * 256 + cs * 8, &sbuf[rg * 256]);
        lds_cp16(wg   + (size_t)r * 256 + cs * 8, &wbuf[rg * 256]);
    }
    __syncthreads();

    const int key = l15 & 7;
    f32x4 acc[4];
#pragma unroll
    for (int j = 0; j < 4; ++j) acc[j] = (f32x4){0.f, 0.f, 0.f, 0.f};

    if (m < 2) {
        // D[n][ck]: A = src rows n (wave's 16), B = weight rows ck (64)
        const int arow = wav * 16 + l15;
#pragma unroll
        for (int k4 = 0; k4 < 32; k4 += 4) {
            const bf16x8 af = *(const bf16x8*)&sbuf[arow * 256 + ((k4 + quad) ^ key) * 8];
#pragma unroll
            for (int nt = 0; nt < 4; ++nt) {
                const int brow = nt * 16 + l15;
                const bf16x8 bfw = *(const bf16x8*)&wbuf[brow * 256 + ((k4 + quad) ^ key) * 8];
                acc[nt] = __builtin_amdgcn_mfma_f32_16x16x32_bf16(af, bfw, acc[nt], 0, 0, 0);
            }
        }
        const float* bs = bias + m * 64;
        bf16* dst = (m == 0) ? kb : qb;
        const int nb = n0 + wav * 16;
#pragma unroll
        for (int nt = 0; nt < 4; ++nt) {
            const float bv = bs[nt * 16 + l15];
#pragma unroll
            for (int r = 0; r < 4; ++r) {
                const int n = nb + quad * 4 + r;
                dst[((size_t)b * NN + n) * CKd + nt * 16 + l15] = (bf16)(acc[nt][r] + bv);
            }
        }
    } else {
        // D[cv][n]: A = weight rows cv (wave's 16), B = src rows n (64)
        const int arow = wav * 16 + l15;
#pragma unroll
        for (int k4 = 0; k4 < 32; k4 += 4) {
            const bf16x8 af = *(const bf16x8*)&wbuf[arow * 256 + ((k4 + quad) ^ key) * 8];
#pragma unroll
            for (int nt = 0; nt < 4; ++nt) {
                const int brow = nt * 16 + l15;
                const bf16x8 bfy = *(const bf16x8*)&sbuf[brow * 256 + ((k4 + quad) ^ key) * 8];
                acc[nt] = __builtin_amdgcn_mfma_f32_16x16x32_bf16(af, bfy, acc[nt], 0, 0, 0);
            }
        }
        const int cv0 = (m - 2) * 64 + wav * 16;
#pragma unroll
        for (int r = 0; r < 4; ++r) {
            const int cv = cv0 + quad * 4 + r;
            const float bv = bias[128 + cv];
#pragma unroll
            for (int nt = 0; nt < 4; ++nt)
                vb[((size_t)b * CVd + cv) * NN + n0 + nt * 16 + l15] = (bf16)(acc[nt][r] + bv);
        }
    }
}

// ---------------------------------------------------------------------------
// Flash attention, LDS-staged K/V (XOR swizzle), fixed-shift softmax, and
// XOR-swizzled p_lds (no pad) -> total LDS 40960 B = 4 blocks/CU.
// grid (50, NB, KS), block 4 waves x 32 queries.
// ---------------------------------------------------------------------------
__launch_bounds__(256, 4)
__global__ void attn_kernel(const bf16* __restrict__ qb, const bf16* __restrict__ kb,
                            const bf16* __restrict__ vb,
                            bf16* __restrict__ pO, float* __restrict__ pl, int tpc)
{
    __shared__ __align__(16) bf16 kbuf[64 * 64];         // 8 KB
    __shared__ __align__(16) bf16 vbuf[128 * 64];        // 16 KB
    __shared__ __align__(16) bf16 p_lds[4][2][16][64];   // 16 KB, XOR swizzled

    const int lane = threadIdx.x & 63;
    const int wav  = threadIdx.x >> 6;
    const int l15  = lane & 15;
    const int quad = lane >> 4;
    const int r8   = lane >> 3;
    const int c_st = lane & 7;
    const int c_src = c_st ^ r8;
    const int sw   = l15 & 7;
    const int pkey = (l15 & 7) << 1;
    const int b    = blockIdx.y;
    const int q0   = blockIdx.x * 128 + wav * 32;

    const bf16* qrow = qb + (size_t)b * NN * CKd;
    const bf16* krow = kb + (size_t)b * NN * CKd;
    const bf16* vrow = vb + (size_t)b * CVd * NN;

    bf16x8 qf[2][2];
#pragma unroll
    for (int qt = 0; qt < 2; ++qt)
#pragma unroll
        for (int s = 0; s < 2; ++s)
            qf[qt][s] = *(const bf16x8*)(qrow + (size_t)(q0 + qt * 16 + l15) * CKd + s * 32 + quad * 8);

    f32x4 acc[2][8];
#pragma unroll
    for (int qt = 0; qt < 2; ++qt)
#pragma unroll
        for (int cv = 0; cv < 8; ++cv) acc[qt][cv] = (f32x4){0.f, 0.f, 0.f, 0.f};
    float psum[2] = {0.f, 0.f};

    const int t0  = blockIdx.z * tpc;
    const int rem = 100 - t0;
    const int nt  = (tpc < rem) ? tpc : rem;

    for (int t = 0; t < nt; ++t) {
        const int key0 = (t0 + t) * 64;

        __syncthreads();
        lds_cp16(krow + (size_t)(key0 + wav * 8 + r8) * CKd + c_src * 8,
                 &kbuf[(wav * 8) * 64]);
        lds_cp16(krow + (size_t)(key0 + (wav + 4) * 8 + r8) * CKd + c_src * 8,
                 &kbuf[((wav + 4) * 8) * 64]);
#pragma unroll
        for (int g4 = 0; g4 < 4; ++g4) {
            const int g = wav * 4 + g4;
            lds_cp16(vrow + (size_t)(g * 8 + r8) * NN + key0 + c_src * 8,
                     &vbuf[(g * 8) * 64]);
        }
        __syncthreads();

        // ---- S^T = K * Q^T ----
        f32x4 s4[2][4];
#pragma unroll
        for (int kt = 0; kt < 4; ++kt) {
            const int rr = kt * 16 + l15;
            const bf16x8 kf0 = *(const bf16x8*)&kbuf[rr * 64 + ((quad ^ sw) * 8)];
            const bf16x8 kf1 = *(const bf16x8*)&kbuf[rr * 64 + (((4 + quad) ^ sw) * 8)];
#pragma unroll
            for (int qt = 0; qt < 2; ++qt) {
                f32x4 z = (f32x4){0.f, 0.f, 0.f, 0.f};
                z = __builtin_amdgcn_mfma_f32_16x16x32_bf16(kf0, qf[qt][0], z, 0, 0, 0);
                z = __builtin_amdgcn_mfma_f32_16x16x32_bf16(kf1, qf[qt][1], z, 0, 0, 0);
                s4[qt][kt] = z;
            }
        }

        // ---- p = exp2(s*log2e - 8*log2e), row-sum, pack to swizzled LDS ----
#pragma unroll
        for (int qt = 0; qt < 2; ++qt) {
            float ps = 0.f;
#pragma unroll
            for (int kt = 0; kt < 4; ++kt) {
                bf16x4 pk;
#pragma unroll
                for (int r = 0; r < 4; ++r) {
                    const float p = exp2f(fmaf(s4[qt][kt][r], 1.4426950408889634f, -11.541560327111707f));
                    ps += p;
                    pk[r] = (bf16)p;
                }
                *(bf16x4*)&p_lds[wav][qt][l15][((kt * 4 + quad) ^ pkey) * 4] = pk;
            }
            psum[qt] += ps;
        }

        // ---- P to B-operand layout (swizzled b128 reads) ----
        bf16x8 pf[2][2];
#pragma unroll
        for (int qt = 0; qt < 2; ++qt)
#pragma unroll
            for (int sp = 0; sp < 2; ++sp)
                pf[qt][sp] = *(const bf16x8*)&p_lds[wav][qt][l15][((sp * 8 + quad * 2) ^ pkey) * 4];

        // ---- ctx^T += V^T * P^T ----
#pragma unroll
        for (int sp = 0; sp < 2; ++sp)
#pragma unroll
            for (int cvt = 0; cvt < 8; ++cvt) {
                const int rr = cvt * 16 + l15;
                const bf16x8 vf = *(const bf16x8*)&vbuf[rr * 64 + (((sp * 4 + quad) ^ sw) * 8)];
                acc[0][cvt] = __builtin_amdgcn_mfma_f32_16x16x32_bf16(vf, pf[0][sp], acc[0][cvt], 0, 0, 0);
                acc[1][cvt] = __builtin_amdgcn_mfma_f32_16x16x32_bf16(vf, pf[1][sp], acc[1][cvt], 0, 0, 0);
            }
    }

    const size_t pb = (size_t)blockIdx.z * NB + b;
#pragma unroll
    for (int qt = 0; qt < 2; ++qt) {
        psum[qt] += __shfl_xor(psum[qt], 16);
        psum[qt] += __shfl_xor(psum[qt], 32);
        const int qa = q0 + qt * 16 + l15;
#pragma unroll
        for (int cvt = 0; cvt < 8; ++cvt) {
            bf16x4 pk;
#pragma unroll
            for (int r = 0; r < 4; ++r) pk[r] = (bf16)acc[qt][cvt][r];
            *(bf16x4*)(pO + (pb * NN + qa) * CVd + cvt * 16 + quad * 4) = pk;
        }
        if (quad == 0) pl[pb * NN + qa] = psum[qt];
    }
}

// ---------------------------------------------------------------------------
// Merge KS chunks: ctxT[b][n][cv] bf16 = sum_ks pO / sum_ks pl
// ---------------------------------------------------------------------------
__global__ void combine_kernel(const bf16* __restrict__ pO, const float* __restrict__ pl,
                               bf16* __restrict__ ctxT, int KS)
{
    const int idx = blockIdx.x * 256 + threadIdx.x;
    const int c4  = (idx & 31) * 4;
    const int rest = idx >> 5;
    const int n = rest % NN, b = rest / NN;

    float v0 = 0.f, v1 = 0.f, v2 = 0.f, v3 = 0.f, L = 0.f;
    for (int ks = 0; ks < KS; ++ks) {
        const size_t base = (size_t)(ks * NB + b) * NN + n;
        const bf16x4 tv = *(const bf16x4*)(pO + base * CVd + c4);
        v0 += (float)tv[0]; v1 += (float)tv[1]; v2 += (float)tv[2]; v3 += (float)tv[3];
        L += pl[base];
    }
    const float r = 1.0f / L;
    bf16x4 o;
    o[0] = (bf16)(v0 * r); o[1] = (bf16)(v1 * r); o[2] = (bf16)(v2 * r); o[3] = (bf16)(v3 * r);
    *(bf16x4*)(ctxT + ((size_t)b * NN + n) * CVd + c4) = o;
}

// ---------------------------------------------------------------------------
// out[b][co][n] f32 = gamma*(W·ctx + W_b) + x.  grid (100, 4, NB).
// ---------------------------------------------------------------------------
__launch_bounds__(256, 4)
__global__ void outproj_kernel(const bf16* __restrict__ ctxT, const bf16* __restrict__ wob,
                               const float* __restrict__ bias, const float* __restrict__ x,
                               const float* __restrict__ gam, float* __restrict__ out)
{
    const int tid  = threadIdx.x;
    const int lane = tid & 63, wav = tid >> 6;
    const int l15  = lane & 15, quad = lane >> 4;
    const int b    = blockIdx.z;
    const int co0  = blockIdx.y * 64 + wav * 16;
    const int n0   = blockIdx.x * 64;

    f32x4 acc[4];
#pragma unroll
    for (int j = 0; j < 4; ++j) acc[j] = (f32x4){0.f, 0.f, 0.f, 0.f};

    for (int kk = 0; kk < CVd; kk += 32) {
        const bf16x8 af = *(const bf16x8*)(wob + (size_t)(co0 + l15) * CVd + kk + quad * 8);
#pragma unroll
        for (int nt = 0; nt < 4; ++nt) {
            const bf16x8 bfc = *(const bf16x8*)(ctxT + ((size_t)b * NN + n0 + nt * 16 + l15) * CVd + kk + quad * 8);
            acc[nt] = __builtin_amdgcn_mfma_f32_16x16x32_bf16(af, bfc, acc[nt], 0, 0, 0);
        }
    }

    const float gm = gam[0];
#pragma unroll
    for (int r = 0; r < 4; ++r) {
        const int co = co0 + quad * 4 + r;
        const float bv = bias[256 + co];
#pragma unroll
        for (int nt = 0; nt < 4; ++nt) {
            const int n = n0 + nt * 16 + l15;
            const size_t a = ((size_t)b * COd + co) * NN + n;
            out[a] = gm * (acc[nt][r] + bv) + x[a];
        }
    }
}

// ---------------------------------------------------------------------------
extern "C" void kernel_launch(void* const* d_in, const int* in_sizes, int n_in,
                              void* d_out, int out_size, void* d_ws, size_t ws_size,
                              hipStream_t stream)
{
    const float* x     = (const float*)d_in[0];
    const float* y     = (const float*)d_in[1];
    const float* fk_w  = (const float*)d_in[2];
    const float* fk_g  = (const float*)d_in[3];
    const float* fk_b  = (const float*)d_in[4];
    const float* fk_m  = (const float*)d_in[5];
    const float* fk_v  = (const float*)d_in[6];
    const float* fq_w  = (const float*)d_in[7];
    const float* fq_g  = (const float*)d_in[8];
    const float* fq_b  = (const float*)d_in[9];
    const float* fq_m  = (const float*)d_in[10];
    const float* fq_v  = (const float*)d_in[11];
    const float* fv_w  = (const float*)d_in[12];
    const float* fv_b  = (const float*)d_in[13];
    const float* W_w   = (const float*)d_in[14];
    const float* W_b   = (const float*)d_in[15];
    const float* gamma = (const float*)d_in[16];
    float* out = (float*)d_out;

    char* ws = (char*)d_ws;
    size_t off = 0;
    auto carve = [&](size_t bytes) -> char* {
        char* p = ws + off;
        off = (off + bytes + 255) & ~(size_t)255;
        return p;
    };

    bf16*  kb   = (bf16*)carve((size_t)NB * NN * CKd * 2);
    bf16*  qbuf = (bf16*)carve((size_t)NB * NN * CKd * 2);
    bf16*  vb   = (bf16*)carve((size_t)NB * CVd * NN * 2);
    bf16*  wkb  = (bf16*)carve((size_t)CKd * CIN * 2);
    bf16*  wqb  = (bf16*)carve((size_t)CKd * CIN * 2);
    bf16*  wvb  = (bf16*)carve((size_t)CVd * CIN * 2);
    bf16*  wob  = (bf16*)carve((size_t)COd * CVd * 2);
    float* bias = (float*)carve(512 * 4);
    bf16*  ctxT = (bf16*)carve((size_t)NB * NN * CVd * 2);

    const size_t alias_start = off;
    bf16* xT = (bf16*)carve((size_t)NB * NN * CIN * 2);
    bf16* yT = (bf16*)carve((size_t)NB * NN * CIN * 2);

    const size_t region = ws_size - alias_start;
    const size_t per_ks = (size_t)NB * NN * CVd * 2 + (size_t)NB * NN * 4 + 512;
    int KS = 1;
    {
        const int cand[6] = {10, 8, 5, 4, 2, 1};
        for (int i = 0; i < 6; ++i)
            if ((size_t)cand[i] * per_ks <= region) { KS = cand[i]; break; }
    }
    bf16*  pO = (bf16*)(ws + alias_start);
    float* pl = (float*)(ws + alias_start + (size_t)KS * NB * NN * CVd * 2);
    const int tpc = (100 + KS - 1) / KS;

    const dim3 blk(256);
    prep_kernel<<<386, blk, 0, stream>>>(fk_w, fk_g, fk_b, fk_m, fk_v,
                                         fq_w, fq_g, fq_b, fq_m, fq_v,
                                         fv_w, fv_b, W_w, W_b,
                                         wkb, wqb, wvb, wob, bias);
    tcvt_kernel<<<dim3(100, 4, 4), blk, 0, stream>>>(x, y, xT, yT);
    projkqv_kernel<<<dim3(100, 4, NB), blk, 0, stream>>>(xT, yT, wkb, wqb, wvb, bias, kb, qbuf, vb);
    attn_kernel<<<dim3(50, NB, KS), blk, 0, stream>>>(qbuf, kb, vb, pO, pl, tpc);
    combine_kernel<<<dim3((NB * NN * CVd / 4) / 256), blk, 0, stream>>>(pO, pl, ctxT, KS);
    outproj_kernel<<<dim3(100, 4, NB), blk, 0, stream>>>(ctxT, wob, bias, x, gamma, out);
}

// Round 5
// 198.935 us; speedup vs baseline: 1.1887x; 1.1887x over previous
//
#include <hip/hip_runtime.h>
#include <math.h>

#define NB   2
#define CIN  256
#define NN   6400
#define CKd  64
#define CVd  128
#define COd  256

using bf16   = __bf16;
using bf16x4 = __attribute__((ext_vector_type(4))) bf16;
using bf16x8 = __attribute__((ext_vector_type(8))) bf16;
using f32x4  = __attribute__((ext_vector_type(4))) float;

__device__ __forceinline__ void lds_cp16(const bf16* g, bf16* l) {
    __builtin_amdgcn_global_load_lds((const __attribute__((address_space(1))) void*)g,
                                     (__attribute__((address_space(3))) void*)l, 16, 0, 0);
}

// ---------------------------------------------------------------------------
// Fold BN into bf16 weights + fp32 biases.
// ---------------------------------------------------------------------------
__global__ void prep_kernel(const float* __restrict__ fk_w, const float* __restrict__ fk_g,
                            const float* __restrict__ fk_b, const float* __restrict__ fk_m,
                            const float* __restrict__ fk_v,
                            const float* __restrict__ fq_w, const float* __restrict__ fq_g,
                            const float* __restrict__ fq_b, const float* __restrict__ fq_m,
                            const float* __restrict__ fq_v,
                            const float* __restrict__ fv_w, const float* __restrict__ fv_b,
                            const float* __restrict__ W_w,  const float* __restrict__ W_b,
                            bf16* __restrict__ wkb, bf16* __restrict__ wqb,
                            bf16* __restrict__ wvb, bf16* __restrict__ wob,
                            float* __restrict__ bias)
{
    const int idx = blockIdx.x * 256 + threadIdx.x;
    if (idx < 16384) {
        const int co = idx >> 8;
        const float a = fk_g[co] * rsqrtf(fk_v[co] + 1e-5f);
        wkb[idx] = (bf16)(fk_w[idx] * a);
    } else if (idx < 32768) {
        const int i = idx - 16384, co = i >> 8;
        const float a = fq_g[co] * rsqrtf(fq_v[co] + 1e-5f) * 0.125f;
        wqb[i] = (bf16)(fq_w[i] * a);
    } else if (idx < 65536) {
        const int i = idx - 32768;
        wvb[i] = (bf16)fv_w[i];
    } else if (idx < 98304) {
        const int i = idx - 65536;
        wob[i] = (bf16)W_w[i];
    } else if (idx < 98816) {
        const int j = idx - 98304;
        if (j < 64)       { const float a = fk_g[j] * rsqrtf(fk_v[j] + 1e-5f); bias[j] = fk_b[j] - fk_m[j] * a; }
        else if (j < 128) { const int c = j - 64; const float a = fq_g[c] * rsqrtf(fq_v[c] + 1e-5f); bias[j] = (fq_b[c] - fq_m[c] * a) * 0.125f; }
        else if (j < 256) bias[j] = fv_b[j - 128];
        else              bias[j] = W_b[j - 256];
    }
}

// ---------------------------------------------------------------------------
// x,y [b][256][6400] f32 -> xT,yT [b][6400][256] bf16
// ---------------------------------------------------------------------------
__launch_bounds__(256)
__global__ void tcvt_kernel(const float* __restrict__ x, const float* __restrict__ y,
                            bf16* __restrict__ xT, bf16* __restrict__ yT)
{
    __shared__ __align__(16) bf16 t_lds[64][68];
    const int b = blockIdx.z & 1;
    const float* src = (blockIdx.z >> 1) ? y : x;
    bf16* dst = (blockIdx.z >> 1) ? yT : xT;
    const int n0 = blockIdx.x * 64, c0 = blockIdx.y * 64;
    const int tid = threadIdx.x;
    const int nl = (tid & 15) * 4;
#pragma unroll
    for (int p = 0; p < 4; ++p) {
        const int cl = (tid >> 4) + p * 16;
        const float4 v = *(const float4*)(src + (size_t)(b * CIN + c0 + cl) * NN + n0 + nl);
        t_lds[nl + 0][cl] = (bf16)v.x;
        t_lds[nl + 1][cl] = (bf16)v.y;
        t_lds[nl + 2][cl] = (bf16)v.z;
        t_lds[nl + 3][cl] = (bf16)v.w;
    }
    __syncthreads();
#pragma unroll
    for (int p = 0; p < 4; ++p) {
        const int u = tid + p * 256;
        const int n = u >> 4, c4 = (u & 15) * 4;
        const bf16x4 pk = *(const bf16x4*)&t_lds[n][c4];
        *(bf16x4*)(dst + ((size_t)b * NN + n0 + n) * CIN + c0 + c4) = pk;
    }
}

// ---------------------------------------------------------------------------
// k/q/v projections with LDS-staged src+weight tiles (global_load_lds DMA,
// source-side XOR swizzle so fragment ds_read_b128 is conflict-free).
// grid (100, 4, NB). LDS 64KB -> 2 blocks/CU.
// ---------------------------------------------------------------------------
__launch_bounds__(256, 2)
__global__ void projkqv_kernel(const bf16* __restrict__ xT, const bf16* __restrict__ yT,
                               const bf16* __restrict__ wkb, const bf16* __restrict__ wqb,
                               const bf16* __restrict__ wvb, const float* __restrict__ bias,
                               bf16* __restrict__ kb, bf16* __restrict__ qb, bf16* __restrict__ vb)
{
    __shared__ __align__(16) bf16 sbuf[64 * 256];
    __shared__ __align__(16) bf16 wbuf[64 * 256];

    const int tid  = threadIdx.x;
    const int lane = tid & 63, wav = tid >> 6;
    const int l15  = lane & 15, quad = lane >> 4;
    const int b    = blockIdx.z, m = blockIdx.y;
    const int n0   = blockIdx.x * 64;

    const bf16* srcg = ((m == 0) ? xT : yT) + ((size_t)b * NN + n0) * CIN;
    const bf16* wg   = (m == 0) ? wkb : (m == 1) ? wqb : (wvb + (size_t)(m - 2) * 64 * CIN);

    const int r2  = lane >> 5;
    const int c32 = lane & 31;
#pragma unroll
    for (int i = 0; i < 8; ++i) {
        const int rg = wav * 16 + i * 2;
        const int r  = rg + r2;
        const int cs = c32 ^ (r & 7);
        lds_cp16(srcg + (size_t)r * 256 + cs * 8, &sbuf[rg * 256]);
        lds_cp16(wg   + (size_t)r * 256 + cs * 8, &wbuf[rg * 256]);
    }
    __syncthreads();

    const int key = l15 & 7;
    f32x4 acc[4];
#pragma unroll
    for (int j = 0; j < 4; ++j) acc[j] = (f32x4){0.f, 0.f, 0.f, 0.f};

    if (m < 2) {
        const int arow = wav * 16 + l15;
#pragma unroll
        for (int k4 = 0; k4 < 32; k4 += 4) {
            const bf16x8 af = *(const bf16x8*)&sbuf[arow * 256 + ((k4 + quad) ^ key) * 8];
#pragma unroll
            for (int nt = 0; nt < 4; ++nt) {
                const int brow = nt * 16 + l15;
                const bf16x8 bfw = *(const bf16x8*)&wbuf[brow * 256 + ((k4 + quad) ^ key) * 8];
                acc[nt] = __builtin_amdgcn_mfma_f32_16x16x32_bf16(af, bfw, acc[nt], 0, 0, 0);
            }
        }
        const float* bs = bias + m * 64;
        bf16* dst = (m == 0) ? kb : qb;
        const int nb = n0 + wav * 16;
#pragma unroll
        for (int nt = 0; nt < 4; ++nt) {
            const float bv = bs[nt * 16 + l15];
#pragma unroll
            for (int r = 0; r < 4; ++r) {
                const int n = nb + quad * 4 + r;
                dst[((size_t)b * NN + n) * CKd + nt * 16 + l15] = (bf16)(acc[nt][r] + bv);
            }
        }
    } else {
        const int arow = wav * 16 + l15;
#pragma unroll
        for (int k4 = 0; k4 < 32; k4 += 4) {
            const bf16x8 af = *(const bf16x8*)&wbuf[arow * 256 + ((k4 + quad) ^ key) * 8];
#pragma unroll
            for (int nt = 0; nt < 4; ++nt) {
                const int brow = nt * 16 + l15;
                const bf16x8 bfy = *(const bf16x8*)&sbuf[brow * 256 + ((k4 + quad) ^ key) * 8];
                acc[nt] = __builtin_amdgcn_mfma_f32_16x16x32_bf16(af, bfy, acc[nt], 0, 0, 0);
            }
        }
        const int cv0 = (m - 2) * 64 + wav * 16;
#pragma unroll
        for (int r = 0; r < 4; ++r) {
            const int cv = cv0 + quad * 4 + r;
            const float bv = bias[128 + cv];
#pragma unroll
            for (int nt = 0; nt < 4; ++nt)
                vb[((size_t)b * CVd + cv) * NN + n0 + nt * 16 + l15] = (bf16)(acc[nt][r] + bv);
        }
    }
}

// ---------------------------------------------------------------------------
// Flash attention.  LDS-staged K/V (XOR swizzle), fixed-shift softmax
// p=exp(s-8), XOR-swizzled p_lds.  LDS 40 KB; __launch_bounds__(256,3) gives
// 170 regs/wave (64 AGPR acc + ~90 VGPR fits -- (256,4)=128 regs SPILLS,
// measured r4: FETCH 10x from rematerialized Q loads + scratch writes).
// 1D grid 50*NB*KS; id&(KS-1)=ks pins each key-chunk to one XCD (L2 locality).
// Epilogue transposes acc via p_lds so pO stores are lane-contiguous dwordx4.
// ---------------------------------------------------------------------------
__launch_bounds__(256, 3)
__global__ void attn_kernel(const bf16* __restrict__ qb, const bf16* __restrict__ kb,
                            const bf16* __restrict__ vb,
                            bf16* __restrict__ pO, float* __restrict__ pl,
                            int tpc, int kmask, int kbits)
{
    __shared__ __align__(16) bf16 kbuf[64 * 64];         // 8 KB
    __shared__ __align__(16) bf16 vbuf[128 * 64];        // 16 KB
    __shared__ __align__(16) bf16 p_lds[4][2][16][64];   // 16 KB, XOR swizzled

    const int lane = threadIdx.x & 63;
    const int wav  = threadIdx.x >> 6;
    const int l15  = lane & 15;
    const int quad = lane >> 4;
    const int r8   = lane >> 3;
    const int c_st = lane & 7;
    const int c_src = c_st ^ r8;
    const int sw   = l15 & 7;
    const int pkey = (l15 & 7) << 1;

    const int id    = blockIdx.x;
    const int ks    = id & kmask;
    const int b     = (id >> kbits) & 1;
    const int qtile = id >> (kbits + 1);
    const int q0    = qtile * 128 + wav * 32;

    const bf16* qrow = qb + (size_t)b * NN * CKd;
    const bf16* krow = kb + (size_t)b * NN * CKd;
    const bf16* vrow = vb + (size_t)b * CVd * NN;

    bf16x8 qf[2][2];
#pragma unroll
    for (int qt = 0; qt < 2; ++qt)
#pragma unroll
        for (int s = 0; s < 2; ++s)
            qf[qt][s] = *(const bf16x8*)(qrow + (size_t)(q0 + qt * 16 + l15) * CKd + s * 32 + quad * 8);

    f32x4 acc[2][8];
#pragma unroll
    for (int qt = 0; qt < 2; ++qt)
#pragma unroll
        for (int cv = 0; cv < 8; ++cv) acc[qt][cv] = (f32x4){0.f, 0.f, 0.f, 0.f};
    float psum[2] = {0.f, 0.f};

    const int t0  = ks * tpc;
    const int rem = 100 - t0;
    const int nt  = (tpc < rem) ? tpc : rem;

    for (int t = 0; t < nt; ++t) {
        const int key0 = (t0 + t) * 64;

        __syncthreads();
        lds_cp16(krow + (size_t)(key0 + wav * 8 + r8) * CKd + c_src * 8,
                 &kbuf[(wav * 8) * 64]);
        lds_cp16(krow + (size_t)(key0 + (wav + 4) * 8 + r8) * CKd + c_src * 8,
                 &kbuf[((wav + 4) * 8) * 64]);
#pragma unroll
        for (int g4 = 0; g4 < 4; ++g4) {
            const int g = wav * 4 + g4;
            lds_cp16(vrow + (size_t)(g * 8 + r8) * NN + key0 + c_src * 8,
                     &vbuf[(g * 8) * 64]);
        }
        __syncthreads();

        // ---- S^T = K * Q^T ----
        f32x4 s4[2][4];
#pragma unroll
        for (int kt = 0; kt < 4; ++kt) {
            const int rr = kt * 16 + l15;
            const bf16x8 kf0 = *(const bf16x8*)&kbuf[rr * 64 + ((quad ^ sw) * 8)];
            const bf16x8 kf1 = *(const bf16x8*)&kbuf[rr * 64 + (((4 + quad) ^ sw) * 8)];
#pragma unroll
            for (int qt = 0; qt < 2; ++qt) {
                f32x4 z = (f32x4){0.f, 0.f, 0.f, 0.f};
                z = __builtin_amdgcn_mfma_f32_16x16x32_bf16(kf0, qf[qt][0], z, 0, 0, 0);
                z = __builtin_amdgcn_mfma_f32_16x16x32_bf16(kf1, qf[qt][1], z, 0, 0, 0);
                s4[qt][kt] = z;
            }
        }

        // ---- p = exp2(s*log2e - 8*log2e), row-sum, pack to swizzled LDS ----
#pragma unroll
        for (int qt = 0; qt < 2; ++qt) {
            float ps = 0.f;
#pragma unroll
            for (int kt = 0; kt < 4; ++kt) {
                bf16x4 pk;
#pragma unroll
                for (int r = 0; r < 4; ++r) {
                    const float p = exp2f(fmaf(s4[qt][kt][r], 1.4426950408889634f, -11.541560327111707f));
                    ps += p;
                    pk[r] = (bf16)p;
                }
                *(bf16x4*)&p_lds[wav][qt][l15][((kt * 4 + quad) ^ pkey) * 4] = pk;
            }
            psum[qt] += ps;
        }

        // ---- P to B-operand layout ----
        bf16x8 pf[2][2];
#pragma unroll
        for (int qt = 0; qt < 2; ++qt)
#pragma unroll
            for (int sp = 0; sp < 2; ++sp)
                pf[qt][sp] = *(const bf16x8*)&p_lds[wav][qt][l15][((sp * 8 + quad * 2) ^ pkey) * 4];

        // ---- ctx^T += V^T * P^T ----
#pragma unroll
        for (int sp = 0; sp < 2; ++sp)
#pragma unroll
            for (int cvt = 0; cvt < 8; ++cvt) {
                const int rr = cvt * 16 + l15;
                const bf16x8 vf = *(const bf16x8*)&vbuf[rr * 64 + (((sp * 4 + quad) ^ sw) * 8)];
                acc[0][cvt] = __builtin_amdgcn_mfma_f32_16x16x32_bf16(vf, pf[0][sp], acc[0][cvt], 0, 0, 0);
                acc[1][cvt] = __builtin_amdgcn_mfma_f32_16x16x32_bf16(vf, pf[1][sp], acc[1][cvt], 0, 0, 0);
            }
    }

    // ---- epilogue: transpose acc through LDS -> coalesced pO stores ----
    __syncthreads();   // p_lds reuse is per-wave, but keep waves aligned after loop
    bf16* tbuf = &p_lds[wav][0][0][0];   // per-wave 2048 bf16 = [16 rows][128]
    const size_t pb = (size_t)ks * NB + b;
#pragma unroll
    for (int qt = 0; qt < 2; ++qt) {
        psum[qt] += __shfl_xor(psum[qt], 16);
        psum[qt] += __shfl_xor(psum[qt], 32);
        // scatter acc into per-query rows (8B units, XOR swizzled; 2-way max)
#pragma unroll
        for (int cvt = 0; cvt < 8; ++cvt) {
            bf16x4 pk;
#pragma unroll
            for (int r = 0; r < 4; ++r) pk[r] = (bf16)acc[qt][cvt][r];
            const int u = (cvt * 4 + quad) ^ ((l15 & 15) << 1);
            *(bf16x4*)&tbuf[l15 * 128 + u * 4] = pk;
        }
        // gather rows, contiguous dwordx4 global stores (1 KB/wave/inst)
#pragma unroll
        for (int j = 0; j < 4; ++j) {
            const int row = j * 4 + (lane >> 4);
            const int g   = ((lane & 15) * 2) ^ ((row & 15) << 1);
            const bf16x8 vv = *(const bf16x8*)&tbuf[row * 128 + g * 4];
            *(bf16x8*)(pO + (pb * NN + q0 + qt * 16) * CVd + j * 512 + lane * 8) = vv;
        }
        if (quad == 0) pl[pb * NN + q0 + qt * 16 + l15] = psum[qt];
    }
}

// ---------------------------------------------------------------------------
// Merge KS chunks: ctxT[b][n][cv] bf16 = sum_ks pO / sum_ks pl
// ---------------------------------------------------------------------------
__global__ void combine_kernel(const bf16* __restrict__ pO, const float* __restrict__ pl,
                               bf16* __restrict__ ctxT, int KS)
{
    const int idx = blockIdx.x * 256 + threadIdx.x;
    const int c4  = (idx & 31) * 4;
    const int rest = idx >> 5;
    const int n = rest % NN, b = rest / NN;

    float v0 = 0.f, v1 = 0.f, v2 = 0.f, v3 = 0.f, L = 0.f;
    for (int ks = 0; ks < KS; ++ks) {
        const size_t base = (size_t)(ks * NB + b) * NN + n;
        const bf16x4 tv = *(const bf16x4*)(pO + base * CVd + c4);
        v0 += (float)tv[0]; v1 += (float)tv[1]; v2 += (float)tv[2]; v3 += (float)tv[3];
        L += pl[base];
    }
    const float r = 1.0f / L;
    bf16x4 o;
    o[0] = (bf16)(v0 * r); o[1] = (bf16)(v1 * r); o[2] = (bf16)(v2 * r); o[3] = (bf16)(v3 * r);
    *(bf16x4*)(ctxT + ((size_t)b * NN + n) * CVd + c4) = o;
}

// ---------------------------------------------------------------------------
// out[b][co][n] f32 = gamma*(W·ctx + W_b) + x.  grid (100, 4, NB).
// ---------------------------------------------------------------------------
__launch_bounds__(256, 4)
__global__ void outproj_kernel(const bf16* __restrict__ ctxT, const bf16* __restrict__ wob,
                               const float* __restrict__ bias, const float* __restrict__ x,
                               const float* __restrict__ gam, float* __restrict__ out)
{
    const int tid  = threadIdx.x;
    const int lane = tid & 63, wav = tid >> 6;
    const int l15  = lane & 15, quad = lane >> 4;
    const int b    = blockIdx.z;
    const int co0  = blockIdx.y * 64 + wav * 16;
    const int n0   = blockIdx.x * 64;

    f32x4 acc[4];
#pragma unroll
    for (int j = 0; j < 4; ++j) acc[j] = (f32x4){0.f, 0.f, 0.f, 0.f};

    for (int kk = 0; kk < CVd; kk += 32) {
        const bf16x8 af = *(const bf16x8*)(wob + (size_t)(co0 + l15) * CVd + kk + quad * 8);
#pragma unroll
        for (int nt = 0; nt < 4; ++nt) {
            const bf16x8 bfc = *(const bf16x8*)(ctxT + ((size_t)b * NN + n0 + nt * 16 + l15) * CVd + kk + quad * 8);
            acc[nt] = __builtin_amdgcn_mfma_f32_16x16x32_bf16(af, bfc, acc[nt], 0, 0, 0);
        }
    }

    const float gm = gam[0];
#pragma unroll
    for (int r = 0; r < 4; ++r) {
        const int co = co0 + quad * 4 + r;
        const float bv = bias[256 + co];
#pragma unroll
        for (int nt = 0; nt < 4; ++nt) {
            const int n = n0 + nt * 16 + l15;
            const size_t a = ((size_t)b * COd + co) * NN + n;
            out[a] = gm * (acc[nt][r] + bv) + x[a];
        }
    }
}

// ---------------------------------------------------------------------------
extern "C" void kernel_launch(void* const* d_in, const int* in_sizes, int n_in,
                              void* d_out, int out_size, void* d_ws, size_t ws_size,
                              hipStream_t stream)
{
    const float* x     = (const float*)d_in[0];
    const float* y     = (const float*)d_in[1];
    const float* fk_w  = (const float*)d_in[2];
    const float* fk_g  = (const float*)d_in[3];
    const float* fk_b  = (const float*)d_in[4];
    const float* fk_m  = (const float*)d_in[5];
    const float* fk_v  = (const float*)d_in[6];
    const float* fq_w  = (const float*)d_in[7];
    const float* fq_g  = (const float*)d_in[8];
    const float* fq_b  = (const float*)d_in[9];
    const float* fq_m  = (const float*)d_in[10];
    const float* fq_v  = (const float*)d_in[11];
    const float* fv_w  = (const float*)d_in[12];
    const float* fv_b  = (const float*)d_in[13];
    const float* W_w   = (const float*)d_in[14];
    const float* W_b   = (const float*)d_in[15];
    const float* gamma = (const float*)d_in[16];
    float* out = (float*)d_out;

    char* ws = (char*)d_ws;
    size_t off = 0;
    auto carve = [&](size_t bytes) -> char* {
        char* p = ws + off;
        off = (off + bytes + 255) & ~(size_t)255;
        return p;
    };

    bf16*  kb   = (bf16*)carve((size_t)NB * NN * CKd * 2);
    bf16*  qbuf = (bf16*)carve((size_t)NB * NN * CKd * 2);
    bf16*  vb   = (bf16*)carve((size_t)NB * CVd * NN * 2);
    bf16*  wkb  = (bf16*)carve((size_t)CKd * CIN * 2);
    bf16*  wqb  = (bf16*)carve((size_t)CKd * CIN * 2);
    bf16*  wvb  = (bf16*)carve((size_t)CVd * CIN * 2);
    bf16*  wob  = (bf16*)carve((size_t)COd * CVd * 2);
    float* bias = (float*)carve(512 * 4);
    bf16*  ctxT = (bf16*)carve((size_t)NB * NN * CVd * 2);

    const size_t alias_start = off;
    bf16* xT = (bf16*)carve((size_t)NB * NN * CIN * 2);
    bf16* yT = (bf16*)carve((size_t)NB * NN * CIN * 2);

    const size_t region = ws_size - alias_start;
    const size_t per_ks = (size_t)NB * NN * CVd * 2 + (size_t)NB * NN * 4 + 512;
    // KS: power of 2 so id&(KS-1) decodes the chunk AND chunks pin to XCDs
    int KS = 1, kbits = 0;
    {
        const int cand[4] = {8, 4, 2, 1};
        const int cbit[4] = {3, 2, 1, 0};
        for (int i = 0; i < 4; ++i)
            if ((size_t)cand[i] * per_ks <= region) { KS = cand[i]; kbits = cbit[i]; break; }
    }
    bf16*  pO = (bf16*)(ws + alias_start);
    float* pl = (float*)(ws + alias_start + (size_t)KS * NB * NN * CVd * 2);
    const int tpc = (100 + KS - 1) / KS;

    const dim3 blk(256);
    prep_kernel<<<386, blk, 0, stream>>>(fk_w, fk_g, fk_b, fk_m, fk_v,
                                         fq_w, fq_g, fq_b, fq_m, fq_v,
                                         fv_w, fv_b, W_w, W_b,
                                         wkb, wqb, wvb, wob, bias);
    tcvt_kernel<<<dim3(100, 4, 4), blk, 0, stream>>>(x, y, xT, yT);
    projkqv_kernel<<<dim3(100, 4, NB), blk, 0, stream>>>(xT, yT, wkb, wqb, wvb, bias, kb, qbuf, vb);
    attn_kernel<<<dim3(50 * NB * KS), blk, 0, stream>>>(qbuf, kb, vb, pO, pl, tpc, KS - 1, kbits);
    combine_kernel<<<dim3((NB * NN * CVd / 4) / 256), blk, 0, stream>>>(pO, pl, ctxT, KS);
    outproj_kernel<<<dim3(100, 4, NB), blk, 0, stream>>>(ctxT, wob, bias, x, gamma, out);
}

// Round 6
// 193.204 us; speedup vs baseline: 1.2240x; 1.0297x over previous
//
#include <hip/hip_runtime.h>
#include <math.h>

#define NB   2
#define CIN  256
#define NN   6400
#define CKd  64
#define CVd  128
#define COd  256

using bf16   = __bf16;
using bf16x4 = __attribute__((ext_vector_type(4))) bf16;
using bf16x8 = __attribute__((ext_vector_type(8))) bf16;
using f32x4  = __attribute__((ext_vector_type(4))) float;

__device__ __forceinline__ void lds_cp16(const bf16* g, bf16* l) {
    __builtin_amdgcn_global_load_lds((const __attribute__((address_space(1))) void*)g,
                                     (__attribute__((address_space(3))) void*)l, 16, 0, 0);
}

// ---------------------------------------------------------------------------
// Fold BN into bf16 weights + fp32 biases.
// ---------------------------------------------------------------------------
__global__ void prep_kernel(const float* __restrict__ fk_w, const float* __restrict__ fk_g,
                            const float* __restrict__ fk_b, const float* __restrict__ fk_m,
                            const float* __restrict__ fk_v,
                            const float* __restrict__ fq_w, const float* __restrict__ fq_g,
                            const float* __restrict__ fq_b, const float* __restrict__ fq_m,
                            const float* __restrict__ fq_v,
                            const float* __restrict__ fv_w, const float* __restrict__ fv_b,
                            const float* __restrict__ W_w,  const float* __restrict__ W_b,
                            bf16* __restrict__ wkb, bf16* __restrict__ wqb,
                            bf16* __restrict__ wvb, bf16* __restrict__ wob,
                            float* __restrict__ bias)
{
    const int idx = blockIdx.x * 256 + threadIdx.x;
    if (idx < 16384) {
        const int co = idx >> 8;
        const float a = fk_g[co] * rsqrtf(fk_v[co] + 1e-5f);
        wkb[idx] = (bf16)(fk_w[idx] * a);
    } else if (idx < 32768) {
        const int i = idx - 16384, co = i >> 8;
        const float a = fq_g[co] * rsqrtf(fq_v[co] + 1e-5f) * 0.125f;
        wqb[i] = (bf16)(fq_w[i] * a);
    } else if (idx < 65536) {
        const int i = idx - 32768;
        wvb[i] = (bf16)fv_w[i];
    } else if (idx < 98304) {
        const int i = idx - 65536;
        wob[i] = (bf16)W_w[i];
    } else if (idx < 98816) {
        const int j = idx - 98304;
        if (j < 64)       { const float a = fk_g[j] * rsqrtf(fk_v[j] + 1e-5f); bias[j] = fk_b[j] - fk_m[j] * a; }
        else if (j < 128) { const int c = j - 64; const float a = fq_g[c] * rsqrtf(fq_v[c] + 1e-5f); bias[j] = (fq_b[c] - fq_m[c] * a) * 0.125f; }
        else if (j < 256) bias[j] = fv_b[j - 128];
        else              bias[j] = W_b[j - 256];
    }
}

// ---------------------------------------------------------------------------
// x,y [b][256][6400] f32 -> xT,yT [b][6400][256] bf16
// ---------------------------------------------------------------------------
__launch_bounds__(256)
__global__ void tcvt_kernel(const float* __restrict__ x, const float* __restrict__ y,
                            bf16* __restrict__ xT, bf16* __restrict__ yT)
{
    __shared__ __align__(16) bf16 t_lds[64][68];
    const int b = blockIdx.z & 1;
    const float* src = (blockIdx.z >> 1) ? y : x;
    bf16* dst = (blockIdx.z >> 1) ? yT : xT;
    const int n0 = blockIdx.x * 64, c0 = blockIdx.y * 64;
    const int tid = threadIdx.x;
    const int nl = (tid & 15) * 4;
#pragma unroll
    for (int p = 0; p < 4; ++p) {
        const int cl = (tid >> 4) + p * 16;
        const float4 v = *(const float4*)(src + (size_t)(b * CIN + c0 + cl) * NN + n0 + nl);
        t_lds[nl + 0][cl] = (bf16)v.x;
        t_lds[nl + 1][cl] = (bf16)v.y;
        t_lds[nl + 2][cl] = (bf16)v.z;
        t_lds[nl + 3][cl] = (bf16)v.w;
    }
    __syncthreads();
#pragma unroll
    for (int p = 0; p < 4; ++p) {
        const int u = tid + p * 256;
        const int n = u >> 4, c4 = (u & 15) * 4;
        const bf16x4 pk = *(const bf16x4*)&t_lds[n][c4];
        *(bf16x4*)(dst + ((size_t)b * NN + n0 + n) * CIN + c0 + c4) = pk;
    }
}

// ---------------------------------------------------------------------------
// k/q/v projections with LDS-staged src+weight tiles.
// grid (100, 4, NB). LDS 64KB -> 2 blocks/CU.
// ---------------------------------------------------------------------------
__launch_bounds__(256, 2)
__global__ void projkqv_kernel(const bf16* __restrict__ xT, const bf16* __restrict__ yT,
                               const bf16* __restrict__ wkb, const bf16* __restrict__ wqb,
                               const bf16* __restrict__ wvb, const float* __restrict__ bias,
                               bf16* __restrict__ kb, bf16* __restrict__ qb, bf16* __restrict__ vb)
{
    __shared__ __align__(16) bf16 sbuf[64 * 256];
    __shared__ __align__(16) bf16 wbuf[64 * 256];

    const int tid  = threadIdx.x;
    const int lane = tid & 63, wav = tid >> 6;
    const int l15  = lane & 15, quad = lane >> 4;
    const int b    = blockIdx.z, m = blockIdx.y;
    const int n0   = blockIdx.x * 64;

    const bf16* srcg = ((m == 0) ? xT : yT) + ((size_t)b * NN + n0) * CIN;
    const bf16* wg   = (m == 0) ? wkb : (m == 1) ? wqb : (wvb + (size_t)(m - 2) * 64 * CIN);

    const int r2  = lane >> 5;
    const int c32 = lane & 31;
#pragma unroll
    for (int i = 0; i < 8; ++i) {
        const int rg = wav * 16 + i * 2;
        const int r  = rg + r2;
        const int cs = c32 ^ (r & 7);
        lds_cp16(srcg + (size_t)r * 256 + cs * 8, &sbuf[rg * 256]);
        lds_cp16(wg   + (size_t)r * 256 + cs * 8, &wbuf[rg * 256]);
    }
    __syncthreads();

    const int key = l15 & 7;
    f32x4 acc[4];
#pragma unroll
    for (int j = 0; j < 4; ++j) acc[j] = (f32x4){0.f, 0.f, 0.f, 0.f};

    if (m < 2) {
        const int arow = wav * 16 + l15;
#pragma unroll
        for (int k4 = 0; k4 < 32; k4 += 4) {
            const bf16x8 af = *(const bf16x8*)&sbuf[arow * 256 + ((k4 + quad) ^ key) * 8];
#pragma unroll
            for (int nt = 0; nt < 4; ++nt) {
                const int brow = nt * 16 + l15;
                const bf16x8 bfw = *(const bf16x8*)&wbuf[brow * 256 + ((k4 + quad) ^ key) * 8];
                acc[nt] = __builtin_amdgcn_mfma_f32_16x16x32_bf16(af, bfw, acc[nt], 0, 0, 0);
            }
        }
        const float* bs = bias + m * 64;
        bf16* dst = (m == 0) ? kb : qb;
        const int nb = n0 + wav * 16;
#pragma unroll
        for (int nt = 0; nt < 4; ++nt) {
            const float bv = bs[nt * 16 + l15];
#pragma unroll
            for (int r = 0; r < 4; ++r) {
                const int n = nb + quad * 4 + r;
                dst[((size_t)b * NN + n) * CKd + nt * 16 + l15] = (bf16)(acc[nt][r] + bv);
            }
        }
    } else {
        const int arow = wav * 16 + l15;
#pragma unroll
        for (int k4 = 0; k4 < 32; k4 += 4) {
            const bf16x8 af = *(const bf16x8*)&wbuf[arow * 256 + ((k4 + quad) ^ key) * 8];
#pragma unroll
            for (int nt = 0; nt < 4; ++nt) {
                const int brow = nt * 16 + l15;
                const bf16x8 bfy = *(const bf16x8*)&sbuf[brow * 256 + ((k4 + quad) ^ key) * 8];
                acc[nt] = __builtin_amdgcn_mfma_f32_16x16x32_bf16(af, bfy, acc[nt], 0, 0, 0);
            }
        }
        const int cv0 = (m - 2) * 64 + wav * 16;
#pragma unroll
        for (int r = 0; r < 4; ++r) {
            const int cv = cv0 + quad * 4 + r;
            const float bv = bias[128 + cv];
#pragma unroll
            for (int nt = 0; nt < 4; ++nt)
                vb[((size_t)b * CVd + cv) * NN + n0 + nt * 16 + l15] = (bf16)(acc[nt][r] + bv);
        }
    }
}

// ---------------------------------------------------------------------------
// Flash attention, 4 query-tiles/wave (64 q/wave, 256 q/block): each K/V LDS
// fragment read now feeds 4 MFMAs (r5 was LDS-throughput-bound at 2).
// Fixed-shift softmax p=exp(s-8).  LDS 56KB (K 8 + V 16 + P 32) -> 2 blk/CU.
// Regs: acc 128 AGPR + qf 32 + s4 64 transient ~ 245 -> (256,2) = 256 budget.
// grid 25*NB*KS (KS=10 -> 500 blocks ~ full residency), balanced key split.
// ---------------------------------------------------------------------------
__launch_bounds__(256, 2)
__global__ void attn_kernel(const bf16* __restrict__ qb, const bf16* __restrict__ kb,
                            const bf16* __restrict__ vb,
                            bf16* __restrict__ pO, float* __restrict__ pl, int KS)
{
    __shared__ __align__(16) bf16 kbuf[64 * 64];          // 8 KB
    __shared__ __align__(16) bf16 vbuf[128 * 64];         // 16 KB
    __shared__ __align__(16) bf16 p_lds[4][4][16][64];    // 32 KB, XOR swizzled

    const int lane = threadIdx.x & 63;
    const int wav  = threadIdx.x >> 6;
    const int l15  = lane & 15;
    const int quad = lane >> 4;
    const int r8   = lane >> 3;
    const int c_src = (lane & 7) ^ r8;
    const int sw   = l15 & 7;
    const int pkey = (l15 & 7) << 1;

    const int id    = blockIdx.x;
    const int ks    = id % KS;
    const int rst   = id / KS;
    const int b     = rst & 1;
    const int qtile = rst >> 1;
    const int q0    = qtile * 256 + wav * 64;

    const bf16* qrow = qb + (size_t)b * NN * CKd;
    const bf16* krow = kb + (size_t)b * NN * CKd;
    const bf16* vrow = vb + (size_t)b * CVd * NN;

    bf16x8 qf[4][2];
#pragma unroll
    for (int qt = 0; qt < 4; ++qt)
#pragma unroll
        for (int s = 0; s < 2; ++s)
            qf[qt][s] = *(const bf16x8*)(qrow + (size_t)(q0 + qt * 16 + l15) * CKd + s * 32 + quad * 8);

    f32x4 acc[4][8];
#pragma unroll
    for (int qt = 0; qt < 4; ++qt)
#pragma unroll
        for (int cv = 0; cv < 8; ++cv) acc[qt][cv] = (f32x4){0.f, 0.f, 0.f, 0.f};
    float psum[4] = {0.f, 0.f, 0.f, 0.f};

    const int t0 = (100 * ks) / KS;
    const int t1 = (100 * (ks + 1)) / KS;

    for (int t = t0; t < t1; ++t) {
        const int key0 = t * 64;

        __syncthreads();
        lds_cp16(krow + (size_t)(key0 + wav * 8 + r8) * CKd + c_src * 8,
                 &kbuf[(wav * 8) * 64]);
        lds_cp16(krow + (size_t)(key0 + (wav + 4) * 8 + r8) * CKd + c_src * 8,
                 &kbuf[((wav + 4) * 8) * 64]);
#pragma unroll
        for (int g4 = 0; g4 < 4; ++g4) {
            const int g = wav * 4 + g4;
            lds_cp16(vrow + (size_t)(g * 8 + r8) * NN + key0 + c_src * 8,
                     &vbuf[(g * 8) * 64]);
        }
        __syncthreads();

        // ---- S^T = K * Q^T : 16x16 tiles, all 4 query-tiles per K frag ----
        f32x4 s4[4][4];
#pragma unroll
        for (int kt = 0; kt < 4; ++kt) {
            const int rr = kt * 16 + l15;
            const bf16x8 kf0 = *(const bf16x8*)&kbuf[rr * 64 + ((quad ^ sw) * 8)];
            const bf16x8 kf1 = *(const bf16x8*)&kbuf[rr * 64 + (((4 + quad) ^ sw) * 8)];
#pragma unroll
            for (int qt = 0; qt < 4; ++qt) {
                f32x4 z = (f32x4){0.f, 0.f, 0.f, 0.f};
                z = __builtin_amdgcn_mfma_f32_16x16x32_bf16(kf0, qf[qt][0], z, 0, 0, 0);
                z = __builtin_amdgcn_mfma_f32_16x16x32_bf16(kf1, qf[qt][1], z, 0, 0, 0);
                s4[qt][kt] = z;
            }
        }

        // ---- p = exp(s - 8), row-sum, pack to swizzled LDS ----
#pragma unroll
        for (int qt = 0; qt < 4; ++qt) {
            float ps = 0.f;
#pragma unroll
            for (int kt = 0; kt < 4; ++kt) {
                bf16x4 pk;
#pragma unroll
                for (int r = 0; r < 4; ++r) {
                    const float p = exp2f(fmaf(s4[qt][kt][r], 1.4426950408889634f, -11.541560327111707f));
                    ps += p;
                    pk[r] = (bf16)p;
                }
                *(bf16x4*)&p_lds[wav][qt][l15][((kt * 4 + quad) ^ pkey) * 4] = pk;
            }
            psum[qt] += ps;
        }

        // ---- P to B-operand layout ----
        bf16x8 pf[4][2];
#pragma unroll
        for (int qt = 0; qt < 4; ++qt)
#pragma unroll
            for (int sp = 0; sp < 2; ++sp)
                pf[qt][sp] = *(const bf16x8*)&p_lds[wav][qt][l15][((sp * 8 + quad * 2) ^ pkey) * 4];

        // ---- ctx^T += V^T * P^T : each V frag feeds 4 MFMAs ----
#pragma unroll
        for (int sp = 0; sp < 2; ++sp)
#pragma unroll
            for (int cvt = 0; cvt < 8; ++cvt) {
                const int rr = cvt * 16 + l15;
                const bf16x8 vf = *(const bf16x8*)&vbuf[rr * 64 + (((sp * 4 + quad) ^ sw) * 8)];
#pragma unroll
                for (int qt = 0; qt < 4; ++qt)
                    acc[qt][cvt] = __builtin_amdgcn_mfma_f32_16x16x32_bf16(vf, pf[qt][sp], acc[qt][cvt], 0, 0, 0);
            }
    }

    // ---- epilogue: transpose acc via per-wave LDS -> coalesced pO stores ----
    __syncthreads();
    bf16* tbuf = &p_lds[wav][0][0][0];   // per-wave scratch [16][128]
    const size_t pb = (size_t)ks * NB + b;
#pragma unroll
    for (int qt = 0; qt < 4; ++qt) {
        psum[qt] += __shfl_xor(psum[qt], 16);
        psum[qt] += __shfl_xor(psum[qt], 32);
#pragma unroll
        for (int cvt = 0; cvt < 8; ++cvt) {
            bf16x4 pk;
#pragma unroll
            for (int r = 0; r < 4; ++r) pk[r] = (bf16)acc[qt][cvt][r];
            const int u = (cvt * 4 + quad) ^ (l15 << 1);
            *(bf16x4*)&tbuf[l15 * 128 + u * 4] = pk;
        }
#pragma unroll
        for (int j = 0; j < 4; ++j) {
            const int row = j * 4 + (lane >> 4);
            const int g   = ((lane & 15) * 2) ^ ((row & 15) << 1);
            const bf16x8 vv = *(const bf16x8*)&tbuf[row * 128 + g * 4];
            *(bf16x8*)(pO + (pb * NN + q0 + qt * 16) * CVd + j * 512 + lane * 8) = vv;
        }
        if (quad == 0) pl[pb * NN + q0 + qt * 16 + l15] = psum[qt];
    }
}

// ---------------------------------------------------------------------------
// Merge KS chunks: ctxT[b][n][cv] bf16 = sum_ks pO / sum_ks pl
// ---------------------------------------------------------------------------
__global__ void combine_kernel(const bf16* __restrict__ pO, const float* __restrict__ pl,
                               bf16* __restrict__ ctxT, int KS)
{
    const int idx = blockIdx.x * 256 + threadIdx.x;
    const int c4  = (idx & 31) * 4;
    const int rest = idx >> 5;
    const int n = rest % NN, b = rest / NN;

    float v0 = 0.f, v1 = 0.f, v2 = 0.f, v3 = 0.f, L = 0.f;
    for (int ks = 0; ks < KS; ++ks) {
        const size_t base = (size_t)(ks * NB + b) * NN + n;
        const bf16x4 tv = *(const bf16x4*)(pO + base * CVd + c4);
        v0 += (float)tv[0]; v1 += (float)tv[1]; v2 += (float)tv[2]; v3 += (float)tv[3];
        L += pl[base];
    }
    const float r = 1.0f / L;
    bf16x4 o;
    o[0] = (bf16)(v0 * r); o[1] = (bf16)(v1 * r); o[2] = (bf16)(v2 * r); o[3] = (bf16)(v3 * r);
    *(bf16x4*)(ctxT + ((size_t)b * NN + n) * CVd + c4) = o;
}

// ---------------------------------------------------------------------------
// out[b][co][n] f32 = gamma*(W·ctx + W_b) + x, LDS-staged tiles.
// grid (100, 4, NB), LDS 32KB, regs ~60 -> (256,4) = 4 blocks/CU.
// ---------------------------------------------------------------------------
__launch_bounds__(256, 4)
__global__ void outproj_kernel(const bf16* __restrict__ ctxT, const bf16* __restrict__ wob,
                               const float* __restrict__ bias, const float* __restrict__ x,
                               const float* __restrict__ gam, float* __restrict__ out)
{
    __shared__ __align__(16) bf16 cbuf[64 * 128];   // ctxT n-rows (256B each)
    __shared__ __align__(16) bf16 wbuf[64 * 128];   // wob  co-rows

    const int tid  = threadIdx.x;
    const int lane = tid & 63, wav = tid >> 6;
    const int l15  = lane & 15, quad = lane >> 4;
    const int b    = blockIdx.z;
    const int co0  = blockIdx.y * 64;
    const int n0   = blockIdx.x * 64;

    const bf16* cg = ctxT + ((size_t)b * NN + n0) * CVd;
    const bf16* wg = wob + (size_t)co0 * CVd;

    // DMA stage: 64 rows x 16 chunks(16B) per buf; 4-row groups per inst.
    const int r4  = lane >> 4;
    const int c16 = lane & 15;
#pragma unroll
    for (int i = 0; i < 4; ++i) {
        const int rg = wav * 16 + i * 4;
        const int r  = rg + r4;
        const int cs = c16 ^ (r & 7);
        lds_cp16(cg + (size_t)r * 128 + cs * 8, &cbuf[rg * 128]);
        lds_cp16(wg + (size_t)r * 128 + cs * 8, &wbuf[rg * 128]);
    }
    __syncthreads();

    const int key = l15 & 7;
    const int arow = wav * 16 + l15;
    f32x4 acc[4];
#pragma unroll
    for (int j = 0; j < 4; ++j) acc[j] = (f32x4){0.f, 0.f, 0.f, 0.f};

#pragma unroll
    for (int kk = 0; kk < 4; ++kk) {
        const bf16x8 af = *(const bf16x8*)&wbuf[arow * 128 + (((kk * 4 + quad) ^ key) * 8)];
#pragma unroll
        for (int nt = 0; nt < 4; ++nt) {
            const bf16x8 bfc = *(const bf16x8*)&cbuf[(nt * 16 + l15) * 128 + (((kk * 4 + quad) ^ key) * 8)];
            acc[nt] = __builtin_amdgcn_mfma_f32_16x16x32_bf16(af, bfc, acc[nt], 0, 0, 0);
        }
    }

    const float gm = gam[0];
    const int cob = co0 + wav * 16;
#pragma unroll
    for (int r = 0; r < 4; ++r) {
        const int co = cob + quad * 4 + r;
        const float bv = bias[256 + co];
#pragma unroll
        for (int nt = 0; nt < 4; ++nt) {
            const int n = n0 + nt * 16 + l15;
            const size_t a = ((size_t)b * COd + co) * NN + n;
            out[a] = gm * (acc[nt][r] + bv) + x[a];
        }
    }
}

// ---------------------------------------------------------------------------
extern "C" void kernel_launch(void* const* d_in, const int* in_sizes, int n_in,
                              void* d_out, int out_size, void* d_ws, size_t ws_size,
                              hipStream_t stream)
{
    const float* x     = (const float*)d_in[0];
    const float* y     = (const float*)d_in[1];
    const float* fk_w  = (const float*)d_in[2];
    const float* fk_g  = (const float*)d_in[3];
    const float* fk_b  = (const float*)d_in[4];
    const float* fk_m  = (const float*)d_in[5];
    const float* fk_v  = (const float*)d_in[6];
    const float* fq_w  = (const float*)d_in[7];
    const float* fq_g  = (const float*)d_in[8];
    const float* fq_b  = (const float*)d_in[9];
    const float* fq_m  = (const float*)d_in[10];
    const float* fq_v  = (const float*)d_in[11];
    const float* fv_w  = (const float*)d_in[12];
    const float* fv_b  = (const float*)d_in[13];
    const float* W_w   = (const float*)d_in[14];
    const float* W_b   = (const float*)d_in[15];
    const float* gamma = (const float*)d_in[16];
    float* out = (float*)d_out;

    char* ws = (char*)d_ws;
    size_t off = 0;
    auto carve = [&](size_t bytes) -> char* {
        char* p = ws + off;
        off = (off + bytes + 255) & ~(size_t)255;
        return p;
    };

    bf16*  kb   = (bf16*)carve((size_t)NB * NN * CKd * 2);
    bf16*  qbuf = (bf16*)carve((size_t)NB * NN * CKd * 2);
    bf16*  vb   = (bf16*)carve((size_t)NB * CVd * NN * 2);
    bf16*  wkb  = (bf16*)carve((size_t)CKd * CIN * 2);
    bf16*  wqb  = (bf16*)carve((size_t)CKd * CIN * 2);
    bf16*  wvb  = (bf16*)carve((size_t)CVd * CIN * 2);
    bf16*  wob  = (bf16*)carve((size_t)COd * CVd * 2);
    float* bias = (float*)carve(512 * 4);
    bf16*  ctxT = (bf16*)carve((size_t)NB * NN * CVd * 2);

    const size_t alias_start = off;
    bf16* xT = (bf16*)carve((size_t)NB * NN * CIN * 2);
    bf16* yT = (bf16*)carve((size_t)NB * NN * CIN * 2);

    const size_t region = ws_size - alias_start;
    const size_t per_ks = (size_t)NB * NN * CVd * 2 + (size_t)NB * NN * 4 + 512;
    int KS = 1;
    {
        const int cand[6] = {10, 8, 5, 4, 2, 1};
        for (int i = 0; i < 6; ++i)
            if ((size_t)cand[i] * per_ks <= region) { KS = cand[i]; break; }
    }
    bf16*  pO = (bf16*)(ws + alias_start);
    float* pl = (float*)(ws + alias_start + (size_t)KS * NB * NN * CVd * 2);

    const dim3 blk(256);
    prep_kernel<<<386, blk, 0, stream>>>(fk_w, fk_g, fk_b, fk_m, fk_v,
                                         fq_w, fq_g, fq_b, fq_m, fq_v,
                                         fv_w, fv_b, W_w, W_b,
                                         wkb, wqb, wvb, wob, bias);
    tcvt_kernel<<<dim3(100, 4, 4), blk, 0, stream>>>(x, y, xT, yT);
    projkqv_kernel<<<dim3(100, 4, NB), blk, 0, stream>>>(xT, yT, wkb, wqb, wvb, bias, kb, qbuf, vb);
    attn_kernel<<<dim3(25 * NB * KS), blk, 0, stream>>>(qbuf, kb, vb, pO, pl, KS);
    combine_kernel<<<dim3((NB * NN * CVd / 4) / 256), blk, 0, stream>>>(pO, pl, ctxT, KS);
    outproj_kernel<<<dim3(100, 4, NB), blk, 0, stream>>>(ctxT, wob, bias, x, gamma, out);
}

// Round 9
// 192.424 us; speedup vs baseline: 1.2290x; 1.0041x over previous
//
#include <hip/hip_runtime.h>
#include <math.h>

#define NB   2
#define CIN  256
#define NN   6400
#define CKd  64
#define CVd  128
#define COd  256

using bf16   = __bf16;
using bf16x4 = __attribute__((ext_vector_type(4))) bf16;
using bf16x8 = __attribute__((ext_vector_type(8))) bf16;
using f32x4  = __attribute__((ext_vector_type(4))) float;

__device__ __forceinline__ void lds_cp16(const void* g, void* l) {
    __builtin_amdgcn_global_load_lds((const __attribute__((address_space(1))) void*)g,
                                     (__attribute__((address_space(3))) void*)l, 16, 0, 0);
}

// ---------------------------------------------------------------------------
// Fold BN into bf16 weights + fp32 biases.
// ---------------------------------------------------------------------------
__global__ void prep_kernel(const float* __restrict__ fk_w, const float* __restrict__ fk_g,
                            const float* __restrict__ fk_b, const float* __restrict__ fk_m,
                            const float* __restrict__ fk_v,
                            const float* __restrict__ fq_w, const float* __restrict__ fq_g,
                            const float* __restrict__ fq_b, const float* __restrict__ fq_m,
                            const float* __restrict__ fq_v,
                            const float* __restrict__ fv_w, const float* __restrict__ fv_b,
                            const float* __restrict__ W_w,  const float* __restrict__ W_b,
                            bf16* __restrict__ wkb, bf16* __restrict__ wqb,
                            bf16* __restrict__ wvb, bf16* __restrict__ wob,
                            float* __restrict__ bias)
{
    const int idx = blockIdx.x * 256 + threadIdx.x;
    if (idx < 16384) {
        const int co = idx >> 8;
        const float a = fk_g[co] * rsqrtf(fk_v[co] + 1e-5f);
        wkb[idx] = (bf16)(fk_w[idx] * a);
    } else if (idx < 32768) {
        const int i = idx - 16384, co = i >> 8;
        const float a = fq_g[co] * rsqrtf(fq_v[co] + 1e-5f) * 0.125f;
        wqb[i] = (bf16)(fq_w[i] * a);
    } else if (idx < 65536) {
        const int i = idx - 32768;
        wvb[i] = (bf16)fv_w[i];
    } else if (idx < 98304) {
        const int i = idx - 65536;
        wob[i] = (bf16)W_w[i];
    } else if (idx < 98816) {
        const int j = idx - 98304;
        if (j < 64)       { const float a = fk_g[j] * rsqrtf(fk_v[j] + 1e-5f); bias[j] = fk_b[j] - fk_m[j] * a; }
        else if (j < 128) { const int c = j - 64; const float a = fq_g[c] * rsqrtf(fq_v[c] + 1e-5f); bias[j] = (fq_b[c] - fq_m[c] * a) * 0.125f; }
        else if (j < 256) bias[j] = fv_b[j - 128];
        else              bias[j] = W_b[j - 256];
    }
}

// ---------------------------------------------------------------------------
// x,y [b][256][6400] f32 -> xT,yT [b][6400][256] bf16
// ---------------------------------------------------------------------------
__launch_bounds__(256)
__global__ void tcvt_kernel(const float* __restrict__ x, const float* __restrict__ y,
                            bf16* __restrict__ xT, bf16* __restrict__ yT)
{
    __shared__ __align__(16) bf16 t_lds[64][68];
    const int b = blockIdx.z & 1;
    const float* src = (blockIdx.z >> 1) ? y : x;
    bf16* dst = (blockIdx.z >> 1) ? yT : xT;
    const int n0 = blockIdx.x * 64, c0 = blockIdx.y * 64;
    const int tid = threadIdx.x;
    const int nl = (tid & 15) * 4;
#pragma unroll
    for (int p = 0; p < 4; ++p) {
        const int cl = (tid >> 4) + p * 16;
        const float4 v = *(const float4*)(src + (size_t)(b * CIN + c0 + cl) * NN + n0 + nl);
        t_lds[nl + 0][cl] = (bf16)v.x;
        t_lds[nl + 1][cl] = (bf16)v.y;
        t_lds[nl + 2][cl] = (bf16)v.z;
        t_lds[nl + 3][cl] = (bf16)v.w;
    }
    __syncthreads();
#pragma unroll
    for (int p = 0; p < 4; ++p) {
        const int u = tid + p * 256;
        const int n = u >> 4, c4 = (u & 15) * 4;
        const bf16x4 pk = *(const bf16x4*)&t_lds[n][c4];
        *(bf16x4*)(dst + ((size_t)b * NN + n0 + n) * CIN + c0 + c4) = pk;
    }
}

// ---------------------------------------------------------------------------
// k/q/v projections with LDS-staged src+weight tiles (proven r5/r6 version,
// bf16 V output).  grid (100, 4, NB). LDS 64KB -> 2 blocks/CU.
// ---------------------------------------------------------------------------
__launch_bounds__(256, 2)
__global__ void projkqv_kernel(const bf16* __restrict__ xT, const bf16* __restrict__ yT,
                               const bf16* __restrict__ wkb, const bf16* __restrict__ wqb,
                               const bf16* __restrict__ wvb, const float* __restrict__ bias,
                               bf16* __restrict__ kb, bf16* __restrict__ qb, bf16* __restrict__ vb)
{
    __shared__ __align__(16) bf16 sbuf[64 * 256];
    __shared__ __align__(16) bf16 wbuf[64 * 256];

    const int tid  = threadIdx.x;
    const int lane = tid & 63, wav = tid >> 6;
    const int l15  = lane & 15, quad = lane >> 4;
    const int b    = blockIdx.z, m = blockIdx.y;
    const int n0   = blockIdx.x * 64;

    const bf16* srcg = ((m == 0) ? xT : yT) + ((size_t)b * NN + n0) * CIN;
    const bf16* wg   = (m == 0) ? wkb : (m == 1) ? wqb : (wvb + (size_t)(m - 2) * 64 * CIN);

    const int r2  = lane >> 5;
    const int c32 = lane & 31;
#pragma unroll
    for (int i = 0; i < 8; ++i) {
        const int rg = wav * 16 + i * 2;
        const int r  = rg + r2;
        const int cs = c32 ^ (r & 7);
        lds_cp16(srcg + (size_t)r * 256 + cs * 8, &sbuf[rg * 256]);
        lds_cp16(wg   + (size_t)r * 256 + cs * 8, &wbuf[rg * 256]);
    }
    __syncthreads();

    const int key = l15 & 7;
    f32x4 acc[4];
#pragma unroll
    for (int j = 0; j < 4; ++j) acc[j] = (f32x4){0.f, 0.f, 0.f, 0.f};

    if (m < 2) {
        const int arow = wav * 16 + l15;
#pragma unroll
        for (int k4 = 0; k4 < 32; k4 += 4) {
            const bf16x8 af = *(const bf16x8*)&sbuf[arow * 256 + ((k4 + quad) ^ key) * 8];
#pragma unroll
            for (int nt = 0; nt < 4; ++nt) {
                const int brow = nt * 16 + l15;
                const bf16x8 bfw = *(const bf16x8*)&wbuf[brow * 256 + ((k4 + quad) ^ key) * 8];
                acc[nt] = __builtin_amdgcn_mfma_f32_16x16x32_bf16(af, bfw, acc[nt], 0, 0, 0);
            }
        }
        const float* bs = bias + m * 64;
        bf16* dst = (m == 0) ? kb : qb;
        const int nb = n0 + wav * 16;
#pragma unroll
        for (int nt = 0; nt < 4; ++nt) {
            const float bv = bs[nt * 16 + l15];
#pragma unroll
            for (int r = 0; r < 4; ++r) {
                const int n = nb + quad * 4 + r;
                dst[((size_t)b * NN + n) * CKd + nt * 16 + l15] = (bf16)(acc[nt][r] + bv);
            }
        }
    } else {
        const int arow = wav * 16 + l15;
#pragma unroll
        for (int k4 = 0; k4 < 32; k4 += 4) {
            const bf16x8 af = *(const bf16x8*)&wbuf[arow * 256 + ((k4 + quad) ^ key) * 8];
#pragma unroll
            for (int nt = 0; nt < 4; ++nt) {
                const int brow = nt * 16 + l15;
                const bf16x8 bfy = *(const bf16x8*)&sbuf[brow * 256 + ((k4 + quad) ^ key) * 8];
                acc[nt] = __builtin_amdgcn_mfma_f32_16x16x32_bf16(af, bfy, acc[nt], 0, 0, 0);
            }
        }
        const int cv0 = (m - 2) * 64 + wav * 16;
#pragma unroll
        for (int r = 0; r < 4; ++r) {
            const int cv = cv0 + quad * 4 + r;
            const float bv = bias[128 + cv];
#pragma unroll
            for (int nt = 0; nt < 4; ++nt)
                vb[((size_t)b * CVd + cv) * NN + n0 + nt * 16 + l15] = (bf16)(acc[nt][r] + bv);
        }
    }
}

// ---------------------------------------------------------------------------
// Flash attention — EXACT r5 kernel (proven: passed, 74 us, 84 VGPR, no
// spill).  LDS-staged K/V (XOR swizzle), fixed-shift softmax p=exp(s-8),
// XOR-swizzled p_lds, coalesced pO epilogue.  LDS 40 KB, (256,3).
// 1D grid 50*NB*KS, power-of-2 KS decode pins key-chunks to XCDs.
// ---------------------------------------------------------------------------
__launch_bounds__(256, 3)
__global__ void attn_kernel(const bf16* __restrict__ qb, const bf16* __restrict__ kb,
                            const bf16* __restrict__ vb,
                            bf16* __restrict__ pO, float* __restrict__ pl,
                            int tpc, int kmask, int kbits)
{
    __shared__ __align__(16) bf16 kbuf[64 * 64];         // 8 KB
    __shared__ __align__(16) bf16 vbuf[128 * 64];        // 16 KB
    __shared__ __align__(16) bf16 p_lds[4][2][16][64];   // 16 KB, XOR swizzled

    const int lane = threadIdx.x & 63;
    const int wav  = threadIdx.x >> 6;
    const int l15  = lane & 15;
    const int quad = lane >> 4;
    const int r8   = lane >> 3;
    const int c_st = lane & 7;
    const int c_src = c_st ^ r8;
    const int sw   = l15 & 7;
    const int pkey = (l15 & 7) << 1;

    const int id    = blockIdx.x;
    const int ks    = id & kmask;
    const int b     = (id >> kbits) & 1;
    const int qtile = id >> (kbits + 1);
    const int q0    = qtile * 128 + wav * 32;

    const bf16* qrow = qb + (size_t)b * NN * CKd;
    const bf16* krow = kb + (size_t)b * NN * CKd;
    const bf16* vrow = vb + (size_t)b * CVd * NN;

    bf16x8 qf[2][2];
#pragma unroll
    for (int qt = 0; qt < 2; ++qt)
#pragma unroll
        for (int s = 0; s < 2; ++s)
            qf[qt][s] = *(const bf16x8*)(qrow + (size_t)(q0 + qt * 16 + l15) * CKd + s * 32 + quad * 8);

    f32x4 acc[2][8];
#pragma unroll
    for (int qt = 0; qt < 2; ++qt)
#pragma unroll
        for (int cv = 0; cv < 8; ++cv) acc[qt][cv] = (f32x4){0.f, 0.f, 0.f, 0.f};
    float psum[2] = {0.f, 0.f};

    const int t0  = ks * tpc;
    const int rem = 100 - t0;
    const int nt  = (tpc < rem) ? tpc : rem;

    for (int t = 0; t < nt; ++t) {
        const int key0 = (t0 + t) * 64;

        __syncthreads();
        lds_cp16(krow + (size_t)(key0 + wav * 8 + r8) * CKd + c_src * 8,
                 &kbuf[(wav * 8) * 64]);
        lds_cp16(krow + (size_t)(key0 + (wav + 4) * 8 + r8) * CKd + c_src * 8,
                 &kbuf[((wav + 4) * 8) * 64]);
#pragma unroll
        for (int g4 = 0; g4 < 4; ++g4) {
            const int g = wav * 4 + g4;
            lds_cp16(vrow + (size_t)(g * 8 + r8) * NN + key0 + c_src * 8,
                     &vbuf[(g * 8) * 64]);
        }
        __syncthreads();

        // ---- S^T = K * Q^T ----
        f32x4 s4[2][4];
#pragma unroll
        for (int kt = 0; kt < 4; ++kt) {
            const int rr = kt * 16 + l15;
            const bf16x8 kf0 = *(const bf16x8*)&kbuf[rr * 64 + ((quad ^ sw) * 8)];
            const bf16x8 kf1 = *(const bf16x8*)&kbuf[rr * 64 + (((4 + quad) ^ sw) * 8)];
#pragma unroll
            for (int qt = 0; qt < 2; ++qt) {
                f32x4 z = (f32x4){0.f, 0.f, 0.f, 0.f};
                z = __builtin_amdgcn_mfma_f32_16x16x32_bf16(kf0, qf[qt][0], z, 0, 0, 0);
                z = __builtin_amdgcn_mfma_f32_16x16x32_bf16(kf1, qf[qt][1], z, 0, 0, 0);
                s4[qt][kt] = z;
            }
        }

        // ---- p = exp2(s*log2e - 8*log2e), row-sum, pack to swizzled LDS ----
#pragma unroll
        for (int qt = 0; qt < 2; ++qt) {
            float ps = 0.f;
#pragma unroll
            for (int kt = 0; kt < 4; ++kt) {
                bf16x4 pk;
#pragma unroll
                for (int r = 0; r < 4; ++r) {
                    const float p = exp2f(fmaf(s4[qt][kt][r], 1.4426950408889634f, -11.541560327111707f));
                    ps += p;
                    pk[r] = (bf16)p;
                }
                *(bf16x4*)&p_lds[wav][qt][l15][((kt * 4 + quad) ^ pkey) * 4] = pk;
            }
            psum[qt] += ps;
        }

        // ---- P to B-operand layout ----
        bf16x8 pf[2][2];
#pragma unroll
        for (int qt = 0; qt < 2; ++qt)
#pragma unroll
            for (int sp = 0; sp < 2; ++sp)
                pf[qt][sp] = *(const bf16x8*)&p_lds[wav][qt][l15][((sp * 8 + quad * 2) ^ pkey) * 4];

        // ---- ctx^T += V^T * P^T ----
#pragma unroll
        for (int sp = 0; sp < 2; ++sp)
#pragma unroll
            for (int cvt = 0; cvt < 8; ++cvt) {
                const int rr = cvt * 16 + l15;
                const bf16x8 vf = *(const bf16x8*)&vbuf[rr * 64 + (((sp * 4 + quad) ^ sw) * 8)];
                acc[0][cvt] = __builtin_amdgcn_mfma_f32_16x16x32_bf16(vf, pf[0][sp], acc[0][cvt], 0, 0, 0);
                acc[1][cvt] = __builtin_amdgcn_mfma_f32_16x16x32_bf16(vf, pf[1][sp], acc[1][cvt], 0, 0, 0);
            }
    }

    // ---- epilogue: transpose acc through LDS -> coalesced pO stores ----
    __syncthreads();
    bf16* tbuf = &p_lds[wav][0][0][0];   // per-wave 2048 bf16 = [16 rows][128]
    const size_t pb = (size_t)ks * NB + b;
#pragma unroll
    for (int qt = 0; qt < 2; ++qt) {
        psum[qt] += __shfl_xor(psum[qt], 16);
        psum[qt] += __shfl_xor(psum[qt], 32);
#pragma unroll
        for (int cvt = 0; cvt < 8; ++cvt) {
            bf16x4 pk;
#pragma unroll
            for (int r = 0; r < 4; ++r) pk[r] = (bf16)acc[qt][cvt][r];
            const int u = (cvt * 4 + quad) ^ ((l15 & 15) << 1);
            *(bf16x4*)&tbuf[l15 * 128 + u * 4] = pk;
        }
#pragma unroll
        for (int j = 0; j < 4; ++j) {
            const int row = j * 4 + (lane >> 4);
            const int g   = ((lane & 15) * 2) ^ ((row & 15) << 1);
            const bf16x8 vv = *(const bf16x8*)&tbuf[row * 128 + g * 4];
            *(bf16x8*)(pO + (pb * NN + q0 + qt * 16) * CVd + j * 512 + lane * 8) = vv;
        }
        if (quad == 0) pl[pb * NN + q0 + qt * 16 + l15] = psum[qt];
    }
}

// ---------------------------------------------------------------------------
// Fused combine + output projection (the ONE new piece under test).
// Block = 32 n-rows x all 256 co.  Phase 1: sum KS pO chunks + pl row-sums ->
// normalized ctx bf16 in LDS.  Phase 2: MFMA with full wob tile (64 KB LDS,
// DMA'd at kernel start; drained by the first __syncthreads).
// out = gamma*(W.ctx + W_b) + x.  grid (200, NB).
// ---------------------------------------------------------------------------
__launch_bounds__(256, 2)
__global__ void outproj_kernel(const bf16* __restrict__ pO, const float* __restrict__ pl,
                               const bf16* __restrict__ wob, const float* __restrict__ bias,
                               const float* __restrict__ x, const float* __restrict__ gam,
                               float* __restrict__ out, int KS)
{
    __shared__ __align__(16) bf16 wbuf[256 * 128];   // 64 KB
    __shared__ __align__(16) bf16 cbuf[32 * 128];    // 8 KB
    __shared__ float Lrow[32];

    const int tid  = threadIdx.x;
    const int lane = tid & 63, wav = tid >> 6;
    const int l15  = lane & 15, quad = lane >> 4;
    const int b    = blockIdx.y;
    const int n0   = blockIdx.x * 32;

    {
        const int r4 = lane >> 4;
        const int c  = lane & 15;
#pragma unroll
        for (int i = 0; i < 16; ++i) {
            const int rg = wav * 64 + i * 4;
            const int r  = rg + r4;
            const int cs = c ^ (r & 7);
            lds_cp16(wob + (size_t)r * CVd + cs * 8, &wbuf[rg * 128]);
        }
    }

    // ---- phase 1: accumulate KS chunks of pO, 16 vals/thread ----
    const int tn = tid >> 3;
    const int tc = (tid & 7) * 16;
    float vacc[16];
#pragma unroll
    for (int i = 0; i < 16; ++i) vacc[i] = 0.f;
    for (int ksi = 0; ksi < KS; ++ksi) {
        const bf16* src = pO + ((size_t)(ksi * NB + b) * NN + n0 + tn) * CVd + tc;
#pragma unroll
        for (int j = 0; j < 2; ++j) {
            const bf16x8 v = *(const bf16x8*)(src + j * 8);
#pragma unroll
            for (int e = 0; e < 8; ++e) vacc[j * 8 + e] += (float)v[e];
        }
    }
    if (tid < 32) {
        float L = 0.f;
        for (int ksi = 0; ksi < KS; ++ksi)
            L += pl[(size_t)(ksi * NB + b) * NN + n0 + tid];
        Lrow[tid] = 1.0f / L;
    }
    __syncthreads();
    {
        const float rL = Lrow[tn];
#pragma unroll
        for (int j = 0; j < 2; ++j) {
            bf16x8 o;
#pragma unroll
            for (int e = 0; e < 8; ++e) o[e] = (bf16)(vacc[j * 8 + e] * rL);
            const int c = (tid & 7) * 2 + j;
            *(bf16x8*)&cbuf[tn * 128 + ((c ^ (tn & 7)) * 8)] = o;
        }
    }
    __syncthreads();

    // ---- phase 2: MFMA, wave covers 64 co x 32 n ----
    f32x4 acc[4][2];
#pragma unroll
    for (int i = 0; i < 4; ++i)
#pragma unroll
        for (int j = 0; j < 2; ++j) acc[i][j] = (f32x4){0.f, 0.f, 0.f, 0.f};

#pragma unroll
    for (int kk = 0; kk < 4; ++kk) {
#pragma unroll
        for (int cot = 0; cot < 4; ++cot) {
            const int arow = wav * 64 + cot * 16 + l15;
            const bf16x8 af = *(const bf16x8*)&wbuf[arow * 128 + (((kk * 4 + quad) ^ (arow & 7)) * 8)];
#pragma unroll
            for (int nt = 0; nt < 2; ++nt) {
                const int brow = nt * 16 + l15;
                const bf16x8 bfc = *(const bf16x8*)&cbuf[brow * 128 + (((kk * 4 + quad) ^ (brow & 7)) * 8)];
                acc[cot][nt] = __builtin_amdgcn_mfma_f32_16x16x32_bf16(af, bfc, acc[cot][nt], 0, 0, 0);
            }
        }
    }

    const float gm = gam[0];
#pragma unroll
    for (int cot = 0; cot < 4; ++cot) {
#pragma unroll
        for (int r = 0; r < 4; ++r) {
            const int co = wav * 64 + cot * 16 + quad * 4 + r;
            const float bv = bias[256 + co];
#pragma unroll
            for (int nt = 0; nt < 2; ++nt) {
                const int n = n0 + nt * 16 + l15;
                const size_t a = ((size_t)b * COd + co) * NN + n;
                out[a] = gm * (acc[cot][nt][r] + bv) + x[a];
            }
        }
    }
}

// ---------------------------------------------------------------------------
extern "C" void kernel_launch(void* const* d_in, const int* in_sizes, int n_in,
                              void* d_out, int out_size, void* d_ws, size_t ws_size,
                              hipStream_t stream)
{
    const float* x     = (const float*)d_in[0];
    const float* y     = (const float*)d_in[1];
    const float* fk_w  = (const float*)d_in[2];
    const float* fk_g  = (const float*)d_in[3];
    const float* fk_b  = (const float*)d_in[4];
    const float* fk_m  = (const float*)d_in[5];
    const float* fk_v  = (const float*)d_in[6];
    const float* fq_w  = (const float*)d_in[7];
    const float* fq_g  = (const float*)d_in[8];
    const float* fq_b  = (const float*)d_in[9];
    const float* fq_m  = (const float*)d_in[10];
    const float* fq_v  = (const float*)d_in[11];
    const float* fv_w  = (const float*)d_in[12];
    const float* fv_b  = (const float*)d_in[13];
    const float* W_w   = (const float*)d_in[14];
    const float* W_b   = (const float*)d_in[15];
    const float* gamma = (const float*)d_in[16];
    float* out = (float*)d_out;

    char* ws = (char*)d_ws;
    size_t off = 0;
    auto carve = [&](size_t bytes) -> char* {
        char* p = ws + off;
        off = (off + bytes + 255) & ~(size_t)255;
        return p;
    };

    bf16*  kb   = (bf16*)carve((size_t)NB * NN * CKd * 2);
    bf16*  qbuf = (bf16*)carve((size_t)NB * NN * CKd * 2);
    bf16*  vb   = (bf16*)carve((size_t)NB * CVd * NN * 2);
    bf16*  wkb  = (bf16*)carve((size_t)CKd * CIN * 2);
    bf16*  wqb  = (bf16*)carve((size_t)CKd * CIN * 2);
    bf16*  wvb  = (bf16*)carve((size_t)CVd * CIN * 2);
    bf16*  wob  = (bf16*)carve((size_t)COd * CVd * 2);
    float* bias = (float*)carve(512 * 4);

    const size_t alias_start = off;
    bf16* xT = (bf16*)carve((size_t)NB * NN * CIN * 2);
    bf16* yT = (bf16*)carve((size_t)NB * NN * CIN * 2);

    const size_t region = ws_size - alias_start;
    const size_t per_ks = (size_t)NB * NN * CVd * 2 + (size_t)NB * NN * 4 + 512;
    // KS: power of 2 so id&(KS-1) decodes the chunk AND chunks pin to XCDs
    int KS = 1, kbits = 0;
    {
        const int cand[4] = {8, 4, 2, 1};
        const int cbit[4] = {3, 2, 1, 0};
        for (int i = 0; i < 4; ++i)
            if ((size_t)cand[i] * per_ks <= region) { KS = cand[i]; kbits = cbit[i]; break; }
    }
    bf16*  pO = (bf16*)(ws + alias_start);
    float* pl = (float*)(ws + alias_start + (size_t)KS * NB * NN * CVd * 2);
    const int tpc = (100 + KS - 1) / KS;

    const dim3 blk(256);
    prep_kernel<<<386, blk, 0, stream>>>(fk_w, fk_g, fk_b, fk_m, fk_v,
                                         fq_w, fq_g, fq_b, fq_m, fq_v,
                                         fv_w, fv_b, W_w, W_b,
                                         wkb, wqb, wvb, wob, bias);
    tcvt_kernel<<<dim3(100, 4, 4), blk, 0, stream>>>(x, y, xT, yT);
    projkqv_kernel<<<dim3(100, 4, NB), blk, 0, stream>>>(xT, yT, wkb, wqb, wvb, bias, kb, qbuf, vb);
    attn_kernel<<<dim3(50 * NB * KS), blk, 0, stream>>>(qbuf, kb, vb, pO, pl, tpc, KS - 1, kbits);
    outproj_kernel<<<dim3(200, NB), blk, 0, stream>>>(pO, pl, wob, bias, x, gamma, out, KS);
}

// Round 10
// 189.852 us; speedup vs baseline: 1.2456x; 1.0135x over previous
//
#include <hip/hip_runtime.h>
#include <math.h>

#define NB   2
#define CIN  256
#define NN   6400
#define CKd  64
#define CVd  128
#define COd  256

using bf16   = __bf16;
using bf16x4 = __attribute__((ext_vector_type(4))) bf16;
using bf16x8 = __attribute__((ext_vector_type(8))) bf16;
using f32x4  = __attribute__((ext_vector_type(4))) float;

__device__ __forceinline__ void lds_cp16(const void* g, void* l) {
    __builtin_amdgcn_global_load_lds((const __attribute__((address_space(1))) void*)g,
                                     (__attribute__((address_space(3))) void*)l, 16, 0, 0);
}

// ---------------------------------------------------------------------------
// Fold BN into bf16 weights + fp32 biases.
// ---------------------------------------------------------------------------
__global__ void prep_kernel(const float* __restrict__ fk_w, const float* __restrict__ fk_g,
                            const float* __restrict__ fk_b, const float* __restrict__ fk_m,
                            const float* __restrict__ fk_v,
                            const float* __restrict__ fq_w, const float* __restrict__ fq_g,
                            const float* __restrict__ fq_b, const float* __restrict__ fq_m,
                            const float* __restrict__ fq_v,
                            const float* __restrict__ fv_w, const float* __restrict__ fv_b,
                            const float* __restrict__ W_w,  const float* __restrict__ W_b,
                            bf16* __restrict__ wkb, bf16* __restrict__ wqb,
                            bf16* __restrict__ wvb, bf16* __restrict__ wob,
                            float* __restrict__ bias)
{
    const int idx = blockIdx.x * 256 + threadIdx.x;
    if (idx < 16384) {
        const int co = idx >> 8;
        const float a = fk_g[co] * rsqrtf(fk_v[co] + 1e-5f);
        wkb[idx] = (bf16)(fk_w[idx] * a);
    } else if (idx < 32768) {
        const int i = idx - 16384, co = i >> 8;
        const float a = fq_g[co] * rsqrtf(fq_v[co] + 1e-5f) * 0.125f;
        wqb[i] = (bf16)(fq_w[i] * a);
    } else if (idx < 65536) {
        const int i = idx - 32768;
        wvb[i] = (bf16)fv_w[i];
    } else if (idx < 98304) {
        const int i = idx - 65536;
        wob[i] = (bf16)W_w[i];
    } else if (idx < 98816) {
        const int j = idx - 98304;
        if (j < 64)       { const float a = fk_g[j] * rsqrtf(fk_v[j] + 1e-5f); bias[j] = fk_b[j] - fk_m[j] * a; }
        else if (j < 128) { const int c = j - 64; const float a = fq_g[c] * rsqrtf(fq_v[c] + 1e-5f); bias[j] = (fq_b[c] - fq_m[c] * a) * 0.125f; }
        else if (j < 256) bias[j] = fv_b[j - 128];
        else              bias[j] = W_b[j - 256];
    }
}

// ---------------------------------------------------------------------------
// x,y [b][256][6400] f32 -> xT,yT [b][6400][256] bf16
// ---------------------------------------------------------------------------
__launch_bounds__(256)
__global__ void tcvt_kernel(const float* __restrict__ x, const float* __restrict__ y,
                            bf16* __restrict__ xT, bf16* __restrict__ yT)
{
    __shared__ __align__(16) bf16 t_lds[64][68];
    const int b = blockIdx.z & 1;
    const float* src = (blockIdx.z >> 1) ? y : x;
    bf16* dst = (blockIdx.z >> 1) ? yT : xT;
    const int n0 = blockIdx.x * 64, c0 = blockIdx.y * 64;
    const int tid = threadIdx.x;
    const int nl = (tid & 15) * 4;
#pragma unroll
    for (int p = 0; p < 4; ++p) {
        const int cl = (tid >> 4) + p * 16;
        const float4 v = *(const float4*)(src + (size_t)(b * CIN + c0 + cl) * NN + n0 + nl);
        t_lds[nl + 0][cl] = (bf16)v.x;
        t_lds[nl + 1][cl] = (bf16)v.y;
        t_lds[nl + 2][cl] = (bf16)v.z;
        t_lds[nl + 3][cl] = (bf16)v.w;
    }
    __syncthreads();
#pragma unroll
    for (int p = 0; p < 4; ++p) {
        const int u = tid + p * 256;
        const int n = u >> 4, c4 = (u & 15) * 4;
        const bf16x4 pk = *(const bf16x4*)&t_lds[n][c4];
        *(bf16x4*)(dst + ((size_t)b * NN + n0 + n) * CIN + c0 + c4) = pk;
    }
}

// ---------------------------------------------------------------------------
// k/q/v projections with LDS-staged src+weight tiles (proven r5/r6 version).
// grid (100, 4, NB). LDS 64KB -> 2 blocks/CU.
// ---------------------------------------------------------------------------
__launch_bounds__(256, 2)
__global__ void projkqv_kernel(const bf16* __restrict__ xT, const bf16* __restrict__ yT,
                               const bf16* __restrict__ wkb, const bf16* __restrict__ wqb,
                               const bf16* __restrict__ wvb, const float* __restrict__ bias,
                               bf16* __restrict__ kb, bf16* __restrict__ qb, bf16* __restrict__ vb)
{
    __shared__ __align__(16) bf16 sbuf[64 * 256];
    __shared__ __align__(16) bf16 wbuf[64 * 256];

    const int tid  = threadIdx.x;
    const int lane = tid & 63, wav = tid >> 6;
    const int l15  = lane & 15, quad = lane >> 4;
    const int b    = blockIdx.z, m = blockIdx.y;
    const int n0   = blockIdx.x * 64;

    const bf16* srcg = ((m == 0) ? xT : yT) + ((size_t)b * NN + n0) * CIN;
    const bf16* wg   = (m == 0) ? wkb : (m == 1) ? wqb : (wvb + (size_t)(m - 2) * 64 * CIN);

    const int r2  = lane >> 5;
    const int c32 = lane & 31;
#pragma unroll
    for (int i = 0; i < 8; ++i) {
        const int rg = wav * 16 + i * 2;
        const int r  = rg + r2;
        const int cs = c32 ^ (r & 7);
        lds_cp16(srcg + (size_t)r * 256 + cs * 8, &sbuf[rg * 256]);
        lds_cp16(wg   + (size_t)r * 256 + cs * 8, &wbuf[rg * 256]);
    }
    __syncthreads();

    const int key = l15 & 7;
    f32x4 acc[4];
#pragma unroll
    for (int j = 0; j < 4; ++j) acc[j] = (f32x4){0.f, 0.f, 0.f, 0.f};

    if (m < 2) {
        const int arow = wav * 16 + l15;
#pragma unroll
        for (int k4 = 0; k4 < 32; k4 += 4) {
            const bf16x8 af = *(const bf16x8*)&sbuf[arow * 256 + ((k4 + quad) ^ key) * 8];
#pragma unroll
            for (int nt = 0; nt < 4; ++nt) {
                const int brow = nt * 16 + l15;
                const bf16x8 bfw = *(const bf16x8*)&wbuf[brow * 256 + ((k4 + quad) ^ key) * 8];
                acc[nt] = __builtin_amdgcn_mfma_f32_16x16x32_bf16(af, bfw, acc[nt], 0, 0, 0);
            }
        }
        const float* bs = bias + m * 64;
        bf16* dst = (m == 0) ? kb : qb;
        const int nb = n0 + wav * 16;
#pragma unroll
        for (int nt = 0; nt < 4; ++nt) {
            const float bv = bs[nt * 16 + l15];
#pragma unroll
            for (int r = 0; r < 4; ++r) {
                const int n = nb + quad * 4 + r;
                dst[((size_t)b * NN + n) * CKd + nt * 16 + l15] = (bf16)(acc[nt][r] + bv);
            }
        }
    } else {
        const int arow = wav * 16 + l15;
#pragma unroll
        for (int k4 = 0; k4 < 32; k4 += 4) {
            const bf16x8 af = *(const bf16x8*)&wbuf[arow * 256 + ((k4 + quad) ^ key) * 8];
#pragma unroll
            for (int nt = 0; nt < 4; ++nt) {
                const int brow = nt * 16 + l15;
                const bf16x8 bfy = *(const bf16x8*)&sbuf[brow * 256 + ((k4 + quad) ^ key) * 8];
                acc[nt] = __builtin_amdgcn_mfma_f32_16x16x32_bf16(af, bfy, acc[nt], 0, 0, 0);
            }
        }
        const int cv0 = (m - 2) * 64 + wav * 16;
#pragma unroll
        for (int r = 0; r < 4; ++r) {
            const int cv = cv0 + quad * 4 + r;
            const float bv = bias[128 + cv];
#pragma unroll
            for (int nt = 0; nt < 4; ++nt)
                vb[((size_t)b * CVd + cv) * NN + n0 + nt * 16 + l15] = (bf16)(acc[nt][r] + bv);
        }
    }
}

// ---------------------------------------------------------------------------
// Flash attention — r5/r9 compute, DOUBLE-BUFFERED K/V DMA, ONE barrier/iter:
//   top-of-iter barrier drains DMA(t) [issued last iter, a full compute phase
//   ago -> latency hidden] and guards buffer reuse [DMA(t+1) overwrites the
//   buffer last read in compute(t-1), separated by this barrier].
// r5/r9 structure exposed the full DMA latency between its two barriers at
// ~1.4 resident blocks/CU (no cross-block overlap to hide it).
// LDS 64 KB (K 2x8 + V 2x16 + P 16) -> 2 blocks/CU; regs 84+64, (256,3).
// ---------------------------------------------------------------------------
__launch_bounds__(256, 3)
__global__ void attn_kernel(const bf16* __restrict__ qb, const bf16* __restrict__ kb,
                            const bf16* __restrict__ vb,
                            bf16* __restrict__ pO, float* __restrict__ pl,
                            int tpc, int kmask, int kbits)
{
    __shared__ __align__(16) bf16 kbuf[2][64 * 64];      // 16 KB
    __shared__ __align__(16) bf16 vbuf[2][128 * 64];     // 32 KB
    __shared__ __align__(16) bf16 p_lds[4][2][16][64];   // 16 KB, XOR swizzled

    const int lane = threadIdx.x & 63;
    const int wav  = threadIdx.x >> 6;
    const int l15  = lane & 15;
    const int quad = lane >> 4;
    const int r8   = lane >> 3;
    const int c_src = (lane & 7) ^ r8;
    const int sw   = l15 & 7;
    const int pkey = (l15 & 7) << 1;

    const int id    = blockIdx.x;
    const int ks    = id & kmask;
    const int b     = (id >> kbits) & 1;
    const int qtile = id >> (kbits + 1);
    const int q0    = qtile * 128 + wav * 32;

    const bf16* qrow = qb + (size_t)b * NN * CKd;
    const bf16* krow = kb + (size_t)b * NN * CKd;
    const bf16* vrow = vb + (size_t)b * CVd * NN;

    bf16x8 qf[2][2];
#pragma unroll
    for (int qt = 0; qt < 2; ++qt)
#pragma unroll
        for (int s = 0; s < 2; ++s)
            qf[qt][s] = *(const bf16x8*)(qrow + (size_t)(q0 + qt * 16 + l15) * CKd + s * 32 + quad * 8);

    f32x4 acc[2][8];
#pragma unroll
    for (int qt = 0; qt < 2; ++qt)
#pragma unroll
        for (int cv = 0; cv < 8; ++cv) acc[qt][cv] = (f32x4){0.f, 0.f, 0.f, 0.f};
    float psum[2] = {0.f, 0.f};

    const int t0  = ks * tpc;
    const int rem = 100 - t0;
    const int nt  = (tpc < rem) ? tpc : rem;

    // stage tile t (global key-tile index) into buffer bi
    auto stage = [&](int t, int bi) {
        const int key0 = t * 64;
        lds_cp16(krow + (size_t)(key0 + wav * 8 + r8) * CKd + c_src * 8,
                 &kbuf[bi][(wav * 8) * 64]);
        lds_cp16(krow + (size_t)(key0 + (wav + 4) * 8 + r8) * CKd + c_src * 8,
                 &kbuf[bi][((wav + 4) * 8) * 64]);
#pragma unroll
        for (int g4 = 0; g4 < 4; ++g4) {
            const int g = wav * 4 + g4;
            lds_cp16(vrow + (size_t)(g * 8 + r8) * NN + key0 + c_src * 8,
                     &vbuf[bi][(g * 8) * 64]);
        }
    };

    stage(t0, 0);   // prologue

    for (int t = 0; t < nt; ++t) {
        __syncthreads();                    // drains DMA(t); guards buf reuse
        if (t + 1 < nt) stage(t0 + t + 1, (t + 1) & 1);
        const bf16* kcur = &kbuf[t & 1][0];
        const bf16* vcur = &vbuf[t & 1][0];

        // ---- S^T = K * Q^T ----
        f32x4 s4[2][4];
#pragma unroll
        for (int kt = 0; kt < 4; ++kt) {
            const int rr = kt * 16 + l15;
            const bf16x8 kf0 = *(const bf16x8*)&kcur[rr * 64 + ((quad ^ sw) * 8)];
            const bf16x8 kf1 = *(const bf16x8*)&kcur[rr * 64 + (((4 + quad) ^ sw) * 8)];
#pragma unroll
            for (int qt = 0; qt < 2; ++qt) {
                f32x4 z = (f32x4){0.f, 0.f, 0.f, 0.f};
                z = __builtin_amdgcn_mfma_f32_16x16x32_bf16(kf0, qf[qt][0], z, 0, 0, 0);
                z = __builtin_amdgcn_mfma_f32_16x16x32_bf16(kf1, qf[qt][1], z, 0, 0, 0);
                s4[qt][kt] = z;
            }
        }

        // ---- p = exp2(s*log2e - 8*log2e), row-sum, pack to swizzled LDS ----
#pragma unroll
        for (int qt = 0; qt < 2; ++qt) {
            float ps = 0.f;
#pragma unroll
            for (int kt = 0; kt < 4; ++kt) {
                bf16x4 pk;
#pragma unroll
                for (int r = 0; r < 4; ++r) {
                    const float p = exp2f(fmaf(s4[qt][kt][r], 1.4426950408889634f, -11.541560327111707f));
                    ps += p;
                    pk[r] = (bf16)p;
                }
                *(bf16x4*)&p_lds[wav][qt][l15][((kt * 4 + quad) ^ pkey) * 4] = pk;
            }
            psum[qt] += ps;
        }

        // ---- P to B-operand layout ----
        bf16x8 pf[2][2];
#pragma unroll
        for (int qt = 0; qt < 2; ++qt)
#pragma unroll
            for (int sp = 0; sp < 2; ++sp)
                pf[qt][sp] = *(const bf16x8*)&p_lds[wav][qt][l15][((sp * 8 + quad * 2) ^ pkey) * 4];

        // ---- ctx^T += V^T * P^T ----
#pragma unroll
        for (int sp = 0; sp < 2; ++sp)
#pragma unroll
            for (int cvt = 0; cvt < 8; ++cvt) {
                const int rr = cvt * 16 + l15;
                const bf16x8 vf = *(const bf16x8*)&vcur[rr * 64 + (((sp * 4 + quad) ^ sw) * 8)];
                acc[0][cvt] = __builtin_amdgcn_mfma_f32_16x16x32_bf16(vf, pf[0][sp], acc[0][cvt], 0, 0, 0);
                acc[1][cvt] = __builtin_amdgcn_mfma_f32_16x16x32_bf16(vf, pf[1][sp], acc[1][cvt], 0, 0, 0);
            }
    }

    // ---- epilogue: transpose acc through LDS -> coalesced pO stores ----
    __syncthreads();
    bf16* tbuf = &p_lds[wav][0][0][0];   // per-wave 2048 bf16 = [16 rows][128]
    const size_t pb = (size_t)ks * NB + b;
#pragma unroll
    for (int qt = 0; qt < 2; ++qt) {
        psum[qt] += __shfl_xor(psum[qt], 16);
        psum[qt] += __shfl_xor(psum[qt], 32);
#pragma unroll
        for (int cvt = 0; cvt < 8; ++cvt) {
            bf16x4 pk;
#pragma unroll
            for (int r = 0; r < 4; ++r) pk[r] = (bf16)acc[qt][cvt][r];
            const int u = (cvt * 4 + quad) ^ ((l15 & 15) << 1);
            *(bf16x4*)&tbuf[l15 * 128 + u * 4] = pk;
        }
#pragma unroll
        for (int j = 0; j < 4; ++j) {
            const int row = j * 4 + (lane >> 4);
            const int g   = ((lane & 15) * 2) ^ ((row & 15) << 1);
            const bf16x8 vv = *(const bf16x8*)&tbuf[row * 128 + g * 4];
            *(bf16x8*)(pO + (pb * NN + q0 + qt * 16) * CVd + j * 512 + lane * 8) = vv;
        }
        if (quad == 0) pl[pb * NN + q0 + qt * 16 + l15] = psum[qt];
    }
}

// ---------------------------------------------------------------------------
// Fused combine + output projection (proven r9).
// out = gamma*(W.ctx + W_b) + x.  grid (200, NB).
// ---------------------------------------------------------------------------
__launch_bounds__(256, 2)
__global__ void outproj_kernel(const bf16* __restrict__ pO, const float* __restrict__ pl,
                               const bf16* __restrict__ wob, const float* __restrict__ bias,
                               const float* __restrict__ x, const float* __restrict__ gam,
                               float* __restrict__ out, int KS)
{
    __shared__ __align__(16) bf16 wbuf[256 * 128];   // 64 KB
    __shared__ __align__(16) bf16 cbuf[32 * 128];    // 8 KB
    __shared__ float Lrow[32];

    const int tid  = threadIdx.x;
    const int lane = tid & 63, wav = tid >> 6;
    const int l15  = lane & 15, quad = lane >> 4;
    const int b    = blockIdx.y;
    const int n0   = blockIdx.x * 32;

    {
        const int r4 = lane >> 4;
        const int c  = lane & 15;
#pragma unroll
        for (int i = 0; i < 16; ++i) {
            const int rg = wav * 64 + i * 4;
            const int r  = rg + r4;
            const int cs = c ^ (r & 7);
            lds_cp16(wob + (size_t)r * CVd + cs * 8, &wbuf[rg * 128]);
        }
    }

    // ---- phase 1: accumulate KS chunks of pO, 16 vals/thread ----
    const int tn = tid >> 3;
    const int tc = (tid & 7) * 16;
    float vacc[16];
#pragma unroll
    for (int i = 0; i < 16; ++i) vacc[i] = 0.f;
    for (int ksi = 0; ksi < KS; ++ksi) {
        const bf16* src = pO + ((size_t)(ksi * NB + b) * NN + n0 + tn) * CVd + tc;
#pragma unroll
        for (int j = 0; j < 2; ++j) {
            const bf16x8 v = *(const bf16x8*)(src + j * 8);
#pragma unroll
            for (int e = 0; e < 8; ++e) vacc[j * 8 + e] += (float)v[e];
        }
    }
    if (tid < 32) {
        float L = 0.f;
        for (int ksi = 0; ksi < KS; ++ksi)
            L += pl[(size_t)(ksi * NB + b) * NN + n0 + tid];
        Lrow[tid] = 1.0f / L;
    }
    __syncthreads();
    {
        const float rL = Lrow[tn];
#pragma unroll
        for (int j = 0; j < 2; ++j) {
            bf16x8 o;
#pragma unroll
            for (int e = 0; e < 8; ++e) o[e] = (bf16)(vacc[j * 8 + e] * rL);
            const int c = (tid & 7) * 2 + j;
            *(bf16x8*)&cbuf[tn * 128 + ((c ^ (tn & 7)) * 8)] = o;
        }
    }
    __syncthreads();

    // ---- phase 2: MFMA, wave covers 64 co x 32 n ----
    f32x4 acc[4][2];
#pragma unroll
    for (int i = 0; i < 4; ++i)
#pragma unroll
        for (int j = 0; j < 2; ++j) acc[i][j] = (f32x4){0.f, 0.f, 0.f, 0.f};

#pragma unroll
    for (int kk = 0; kk < 4; ++kk) {
#pragma unroll
        for (int cot = 0; cot < 4; ++cot) {
            const int arow = wav * 64 + cot * 16 + l15;
            const bf16x8 af = *(const bf16x8*)&wbuf[arow * 128 + (((kk * 4 + quad) ^ (arow & 7)) * 8)];
#pragma unroll
            for (int nt = 0; nt < 2; ++nt) {
                const int brow = nt * 16 + l15;
                const bf16x8 bfc = *(const bf16x8*)&cbuf[brow * 128 + (((kk * 4 + quad) ^ (brow & 7)) * 8)];
                acc[cot][nt] = __builtin_amdgcn_mfma_f32_16x16x32_bf16(af, bfc, acc[cot][nt], 0, 0, 0);
            }
        }
    }

    const float gm = gam[0];
#pragma unroll
    for (int cot = 0; cot < 4; ++cot) {
#pragma unroll
        for (int r = 0; r < 4; ++r) {
            const int co = wav * 64 + cot * 16 + quad * 4 + r;
            const float bv = bias[256 + co];
#pragma unroll
            for (int nt = 0; nt < 2; ++nt) {
                const int n = n0 + nt * 16 + l15;
                const size_t a = ((size_t)b * COd + co) * NN + n;
                out[a] = gm * (acc[cot][nt][r] + bv) + x[a];
            }
        }
    }
}

// ---------------------------------------------------------------------------
extern "C" void kernel_launch(void* const* d_in, const int* in_sizes, int n_in,
                              void* d_out, int out_size, void* d_ws, size_t ws_size,
                              hipStream_t stream)
{
    const float* x     = (const float*)d_in[0];
    const float* y     = (const float*)d_in[1];
    const float* fk_w  = (const float*)d_in[2];
    const float* fk_g  = (const float*)d_in[3];
    const float* fk_b  = (const float*)d_in[4];
    const float* fk_m  = (const float*)d_in[5];
    const float* fk_v  = (const float*)d_in[6];
    const float* fq_w  = (const float*)d_in[7];
    const float* fq_g  = (const float*)d_in[8];
    const float* fq_b  = (const float*)d_in[9];
    const float* fq_m  = (const float*)d_in[10];
    const float* fq_v  = (const float*)d_in[11];
    const float* fv_w  = (const float*)d_in[12];
    const float* fv_b  = (const float*)d_in[13];
    const float* W_w   = (const float*)d_in[14];
    const float* W_b   = (const float*)d_in[15];
    const float* gamma = (const float*)d_in[16];
    float* out = (float*)d_out;

    char* ws = (char*)d_ws;
    size_t off = 0;
    auto carve = [&](size_t bytes) -> char* {
        char* p = ws + off;
        off = (off + bytes + 255) & ~(size_t)255;
        return p;
    };

    bf16*  kb   = (bf16*)carve((size_t)NB * NN * CKd * 2);
    bf16*  qbuf = (bf16*)carve((size_t)NB * NN * CKd * 2);
    bf16*  vb   = (bf16*)carve((size_t)NB * CVd * NN * 2);
    bf16*  wkb  = (bf16*)carve((size_t)CKd * CIN * 2);
    bf16*  wqb  = (bf16*)carve((size_t)CKd * CIN * 2);
    bf16*  wvb  = (bf16*)carve((size_t)CVd * CIN * 2);
    bf16*  wob  = (bf16*)carve((size_t)COd * CVd * 2);
    float* bias = (float*)carve(512 * 4);

    const size_t alias_start = off;
    bf16* xT = (bf16*)carve((size_t)NB * NN * CIN * 2);
    bf16* yT = (bf16*)carve((size_t)NB * NN * CIN * 2);

    const size_t region = ws_size - alias_start;
    const size_t per_ks = (size_t)NB * NN * CVd * 2 + (size_t)NB * NN * 4 + 512;
    // KS: power of 2 so id&(KS-1) decodes the chunk AND chunks pin to XCDs
    int KS = 1, kbits = 0;
    {
        const int cand[4] = {8, 4, 2, 1};
        const int cbit[4] = {3, 2, 1, 0};
        for (int i = 0; i < 4; ++i)
            if ((size_t)cand[i] * per_ks <= region) { KS = cand[i]; kbits = cbit[i]; break; }
    }
    bf16*  pO = (bf16*)(ws + alias_start);
    float* pl = (float*)(ws + alias_start + (size_t)KS * NB * NN * CVd * 2);
    const int tpc = (100 + KS - 1) / KS;

    const dim3 blk(256);
    prep_kernel<<<386, blk, 0, stream>>>(fk_w, fk_g, fk_b, fk_m, fk_v,
                                         fq_w, fq_g, fq_b, fq_m, fq_v,
                                         fv_w, fv_b, W_w, W_b,
                                         wkb, wqb, wvb, wob, bias);
    tcvt_kernel<<<dim3(100, 4, 4), blk, 0, stream>>>(x, y, xT, yT);
    projkqv_kernel<<<dim3(100, 4, NB), blk, 0, stream>>>(xT, yT, wkb, wqb, wvb, bias, kb, qbuf, vb);
    attn_kernel<<<dim3(50 * NB * KS), blk, 0, stream>>>(qbuf, kb, vb, pO, pl, tpc, KS - 1, kbits);
    outproj_kernel<<<dim3(200, NB), blk, 0, stream>>>(pO, pl, wob, bias, x, gamma, out, KS);
}

// Round 11
// 174.362 us; speedup vs baseline: 1.3563x; 1.0888x over previous
//
#include <hip/hip_runtime.h>
#include <math.h>

#define NB   2
#define CIN  256
#define NN   6400
#define CKd  64
#define CVd  128
#define COd  256

using bf16   = __bf16;
using bf16x4 = __attribute__((ext_vector_type(4))) bf16;
using bf16x8 = __attribute__((ext_vector_type(8))) bf16;
using f32x4  = __attribute__((ext_vector_type(4))) float;

__device__ __forceinline__ void lds_cp16(const void* g, void* l) {
    __builtin_amdgcn_global_load_lds((const __attribute__((address_space(1))) void*)g,
                                     (__attribute__((address_space(3))) void*)l, 16, 0, 0);
}

// ---------------------------------------------------------------------------
// z<4: transpose x,y [b][256][6400] f32 -> xT,yT [b][6400][256] bf16.
// z==4: fold BN into bf16 weights + fp32 biases (prep), merged launch.
// wqb and its bias are additionally scaled by log2(e) so attn's softmax is
// exp2(s + const) with no per-score multiply.
// ---------------------------------------------------------------------------
__launch_bounds__(256)
__global__ void tcvt_prep_kernel(const float* __restrict__ x, const float* __restrict__ y,
                                 bf16* __restrict__ xT, bf16* __restrict__ yT,
                                 const float* __restrict__ fk_w, const float* __restrict__ fk_g,
                                 const float* __restrict__ fk_b, const float* __restrict__ fk_m,
                                 const float* __restrict__ fk_v,
                                 const float* __restrict__ fq_w, const float* __restrict__ fq_g,
                                 const float* __restrict__ fq_b, const float* __restrict__ fq_m,
                                 const float* __restrict__ fq_v,
                                 const float* __restrict__ fv_w, const float* __restrict__ fv_b,
                                 const float* __restrict__ W_w,  const float* __restrict__ W_b,
                                 bf16* __restrict__ wkb, bf16* __restrict__ wqb,
                                 bf16* __restrict__ wvb, bf16* __restrict__ wob,
                                 float* __restrict__ bias)
{
    __shared__ __align__(16) bf16 t_lds[64][68];

    if (blockIdx.z == 4) {
        const int idx = (blockIdx.y * 100 + blockIdx.x) * 256 + threadIdx.x;
        const float QS = 0.18033688011112042f;   // 0.125 * log2(e)
        if (idx < 16384) {
            const int co = idx >> 8;
            const float a = fk_g[co] * rsqrtf(fk_v[co] + 1e-5f);
            wkb[idx] = (bf16)(fk_w[idx] * a);
        } else if (idx < 32768) {
            const int i = idx - 16384, co = i >> 8;
            const float a = fq_g[co] * rsqrtf(fq_v[co] + 1e-5f) * QS;
            wqb[i] = (bf16)(fq_w[i] * a);
        } else if (idx < 65536) {
            const int i = idx - 32768;
            wvb[i] = (bf16)fv_w[i];
        } else if (idx < 98304) {
            const int i = idx - 65536;
            wob[i] = (bf16)W_w[i];
        } else if (idx < 98816) {
            const int j = idx - 98304;
            if (j < 64)       { const float a = fk_g[j] * rsqrtf(fk_v[j] + 1e-5f); bias[j] = fk_b[j] - fk_m[j] * a; }
            else if (j < 128) { const int c = j - 64; const float a = fq_g[c] * rsqrtf(fq_v[c] + 1e-5f); bias[j] = (fq_b[c] - fq_m[c] * a) * QS; }
            else if (j < 256) bias[j] = fv_b[j - 128];
            else              bias[j] = W_b[j - 256];
        }
        return;
    }

    const int b = blockIdx.z & 1;
    const float* src = (blockIdx.z >> 1) ? y : x;
    bf16* dst = (blockIdx.z >> 1) ? yT : xT;
    const int n0 = blockIdx.x * 64, c0 = blockIdx.y * 64;
    const int tid = threadIdx.x;
    const int nl = (tid & 15) * 4;
#pragma unroll
    for (int p = 0; p < 4; ++p) {
        const int cl = (tid >> 4) + p * 16;
        const float4 v = *(const float4*)(src + (size_t)(b * CIN + c0 + cl) * NN + n0 + nl);
        t_lds[nl + 0][cl] = (bf16)v.x;
        t_lds[nl + 1][cl] = (bf16)v.y;
        t_lds[nl + 2][cl] = (bf16)v.z;
        t_lds[nl + 3][cl] = (bf16)v.w;
    }
    __syncthreads();
#pragma unroll
    for (int p = 0; p < 4; ++p) {
        const int u = tid + p * 256;
        const int n = u >> 4, c4 = (u & 15) * 4;
        const bf16x4 pk = *(const bf16x4*)&t_lds[n][c4];
        *(bf16x4*)(dst + ((size_t)b * NN + n0 + n) * CIN + c0 + c4) = pk;
    }
}

// ---------------------------------------------------------------------------
// k/q/v projections with LDS-staged src+weight tiles (proven r5-r10 version).
// grid (100, 4, NB). LDS 64KB -> 2 blocks/CU.
// ---------------------------------------------------------------------------
__launch_bounds__(256, 2)
__global__ void projkqv_kernel(const bf16* __restrict__ xT, const bf16* __restrict__ yT,
                               const bf16* __restrict__ wkb, const bf16* __restrict__ wqb,
                               const bf16* __restrict__ wvb, const float* __restrict__ bias,
                               bf16* __restrict__ kb, bf16* __restrict__ qb, bf16* __restrict__ vb)
{
    __shared__ __align__(16) bf16 sbuf[64 * 256];
    __shared__ __align__(16) bf16 wbuf[64 * 256];

    const int tid  = threadIdx.x;
    const int lane = tid & 63, wav = tid >> 6;
    const int l15  = lane & 15, quad = lane >> 4;
    const int b    = blockIdx.z, m = blockIdx.y;
    const int n0   = blockIdx.x * 64;

    const bf16* srcg = ((m == 0) ? xT : yT) + ((size_t)b * NN + n0) * CIN;
    const bf16* wg   = (m == 0) ? wkb : (m == 1) ? wqb : (wvb + (size_t)(m - 2) * 64 * CIN);

    const int r2  = lane >> 5;
    const int c32 = lane & 31;
#pragma unroll
    for (int i = 0; i < 8; ++i) {
        const int rg = wav * 16 + i * 2;
        const int r  = rg + r2;
        const int cs = c32 ^ (r & 7);
        lds_cp16(srcg + (size_t)r * 256 + cs * 8, &sbuf[rg * 256]);
        lds_cp16(wg   + (size_t)r * 256 + cs * 8, &wbuf[rg * 256]);
    }
    __syncthreads();

    const int key = l15 & 7;
    f32x4 acc[4];
#pragma unroll
    for (int j = 0; j < 4; ++j) acc[j] = (f32x4){0.f, 0.f, 0.f, 0.f};

    if (m < 2) {
        const int arow = wav * 16 + l15;
#pragma unroll
        for (int k4 = 0; k4 < 32; k4 += 4) {
            const bf16x8 af = *(const bf16x8*)&sbuf[arow * 256 + ((k4 + quad) ^ key) * 8];
#pragma unroll
            for (int nt = 0; nt < 4; ++nt) {
                const int brow = nt * 16 + l15;
                const bf16x8 bfw = *(const bf16x8*)&wbuf[brow * 256 + ((k4 + quad) ^ key) * 8];
                acc[nt] = __builtin_amdgcn_mfma_f32_16x16x32_bf16(af, bfw, acc[nt], 0, 0, 0);
            }
        }
        const float* bs = bias + m * 64;
        bf16* dst = (m == 0) ? kb : qb;
        const int nb = n0 + wav * 16;
#pragma unroll
        for (int nt = 0; nt < 4; ++nt) {
            const float bv = bs[nt * 16 + l15];
#pragma unroll
            for (int r = 0; r < 4; ++r) {
                const int n = nb + quad * 4 + r;
                dst[((size_t)b * NN + n) * CKd + nt * 16 + l15] = (bf16)(acc[nt][r] + bv);
            }
        }
    } else {
        const int arow = wav * 16 + l15;
#pragma unroll
        for (int k4 = 0; k4 < 32; k4 += 4) {
            const bf16x8 af = *(const bf16x8*)&wbuf[arow * 256 + ((k4 + quad) ^ key) * 8];
#pragma unroll
            for (int nt = 0; nt < 4; ++nt) {
                const int brow = nt * 16 + l15;
                const bf16x8 bfy = *(const bf16x8*)&sbuf[brow * 256 + ((k4 + quad) ^ key) * 8];
                acc[nt] = __builtin_amdgcn_mfma_f32_16x16x32_bf16(af, bfy, acc[nt], 0, 0, 0);
            }
        }
        const int cv0 = (m - 2) * 64 + wav * 16;
#pragma unroll
        for (int r = 0; r < 4; ++r) {
            const int cv = cv0 + quad * 4 + r;
            const float bv = bias[128 + cv];
#pragma unroll
            for (int nt = 0; nt < 4; ++nt)
                vb[((size_t)b * CVd + cv) * NN + n0 + nt * 16 + l15] = (bf16)(acc[nt][r] + bv);
        }
    }
}

// ---------------------------------------------------------------------------
// Flash attention v4: q=64/wave (4 q-tiles, 256 q/block) processed in TWO
// qt-pair phases (QK -> exp -> PV per pair) so live s4 stays 32 VGPR and the
// P-LDS stays 16 KB -- r6's q=64 spilled because all 4 qt were live at once.
// r10 counters: VALUBusy 41.6% = 2.4x MfmaUtil -> VALU-issue bound; q=64
// halves per-iteration VALU overhead and DMA traffic per score.
// Double-buffered K/V DMA, one barrier/iter.  q pre-scaled by log2e in prep
// -> p = exp2(s + c), no per-score fma.  LDS 64 KB, (256,2) = 256-reg budget
// (acc 128 + qf 32 + s4 32 + pf 8 + bases ~40 = ~240, no spill).
// grid 25*NB*KS (KS=10 -> 500 blocks, one balanced round, tpc exactly 10).
// ---------------------------------------------------------------------------
__launch_bounds__(256, 2)
__global__ void attn_kernel(const bf16* __restrict__ qb, const bf16* __restrict__ kb,
                            const bf16* __restrict__ vb,
                            bf16* __restrict__ pO, float* __restrict__ pl, int KS)
{
    __shared__ __align__(16) bf16 kbuf[2][64 * 64];        // 16 KB
    __shared__ __align__(16) bf16 vbuf[2][128 * 64];       // 32 KB
    __shared__ __align__(16) bf16 p_lds[4][2][16][64];     // 16 KB per-wave/qt-pair

    const int lane = threadIdx.x & 63;
    const int wav  = threadIdx.x >> 6;
    const int l15  = lane & 15;
    const int quad = lane >> 4;
    const int r8   = lane >> 3;
    const int c_src = (lane & 7) ^ r8;
    const int sw   = l15 & 7;
    const int pkey = (l15 & 7) << 1;

    const int id    = blockIdx.x;
    const int ks    = id % KS;
    const int rst   = id / KS;
    const int b     = rst & 1;
    const int qtile = rst >> 1;
    const int q0    = qtile * 256 + wav * 64;

    const bf16* qrow = qb + (size_t)b * NN * CKd;
    const bf16* krow = kb + (size_t)b * NN * CKd;
    const bf16* vrow = vb + (size_t)b * CVd * NN;

    bf16x8 qf[4][2];
#pragma unroll
    for (int qt = 0; qt < 4; ++qt)
#pragma unroll
        for (int s = 0; s < 2; ++s)
            qf[qt][s] = *(const bf16x8*)(qrow + (size_t)(q0 + qt * 16 + l15) * CKd + s * 32 + quad * 8);

    f32x4 acc[4][8];
#pragma unroll
    for (int qt = 0; qt < 4; ++qt)
#pragma unroll
        for (int cv = 0; cv < 8; ++cv) acc[qt][cv] = (f32x4){0.f, 0.f, 0.f, 0.f};
    float psum[4] = {0.f, 0.f, 0.f, 0.f};

    const int t0 = (100 * ks) / KS;
    const int nt = (100 * (ks + 1)) / KS - t0;

    auto stage = [&](int t, int bi) {
        const int key0 = t * 64;
        lds_cp16(krow + (size_t)(key0 + wav * 8 + r8) * CKd + c_src * 8,
                 &kbuf[bi][(wav * 8) * 64]);
        lds_cp16(krow + (size_t)(key0 + (wav + 4) * 8 + r8) * CKd + c_src * 8,
                 &kbuf[bi][((wav + 4) * 8) * 64]);
#pragma unroll
        for (int g4 = 0; g4 < 4; ++g4) {
            const int g = wav * 4 + g4;
            lds_cp16(vrow + (size_t)(g * 8 + r8) * NN + key0 + c_src * 8,
                     &vbuf[bi][(g * 8) * 64]);
        }
    };

    stage(t0, 0);   // prologue

    for (int t = 0; t < nt; ++t) {
        __syncthreads();                    // drains DMA(t); guards buf reuse
        if (t + 1 < nt) stage(t0 + t + 1, (t + 1) & 1);
        const bf16* kcur = &kbuf[t & 1][0];
        const bf16* vcur = &vbuf[t & 1][0];

#pragma unroll
        for (int ph = 0; ph < 2; ++ph) {
            // ---- S^T = K * Q^T for this qt-pair ----
            f32x4 s4[2][4];
#pragma unroll
            for (int kt = 0; kt < 4; ++kt) {
                const int rr = kt * 16 + l15;
                const bf16x8 kf0 = *(const bf16x8*)&kcur[rr * 64 + ((quad ^ sw) * 8)];
                const bf16x8 kf1 = *(const bf16x8*)&kcur[rr * 64 + (((4 + quad) ^ sw) * 8)];
#pragma unroll
                for (int qtl = 0; qtl < 2; ++qtl) {
                    const int qt = ph * 2 + qtl;
                    f32x4 z = (f32x4){0.f, 0.f, 0.f, 0.f};
                    z = __builtin_amdgcn_mfma_f32_16x16x32_bf16(kf0, qf[qt][0], z, 0, 0, 0);
                    z = __builtin_amdgcn_mfma_f32_16x16x32_bf16(kf1, qf[qt][1], z, 0, 0, 0);
                    s4[qtl][kt] = z;
                }
            }

            // ---- p = exp2(s + c) [q pre-scaled by log2e], pack to LDS ----
#pragma unroll
            for (int qtl = 0; qtl < 2; ++qtl) {
                float ps = 0.f;
#pragma unroll
                for (int kt = 0; kt < 4; ++kt) {
                    bf16x4 pk;
#pragma unroll
                    for (int r = 0; r < 4; ++r) {
                        const float p = exp2f(s4[qtl][kt][r] - 11.541560327111707f);
                        ps += p;
                        pk[r] = (bf16)p;
                    }
                    *(bf16x4*)&p_lds[wav][qtl][l15][((kt * 4 + quad) ^ pkey) * 4] = pk;
                }
                psum[ph * 2 + qtl] += ps;
            }

            // ---- ctx^T += V^T * P^T for this qt-pair ----
#pragma unroll
            for (int sp = 0; sp < 2; ++sp) {
                const bf16x8 pf0 = *(const bf16x8*)&p_lds[wav][0][l15][((sp * 8 + quad * 2) ^ pkey) * 4];
                const bf16x8 pf1 = *(const bf16x8*)&p_lds[wav][1][l15][((sp * 8 + quad * 2) ^ pkey) * 4];
#pragma unroll
                for (int cvt = 0; cvt < 8; ++cvt) {
                    const int rr = cvt * 16 + l15;
                    const bf16x8 vf = *(const bf16x8*)&vcur[rr * 64 + (((sp * 4 + quad) ^ sw) * 8)];
                    acc[ph * 2 + 0][cvt] = __builtin_amdgcn_mfma_f32_16x16x32_bf16(vf, pf0, acc[ph * 2 + 0][cvt], 0, 0, 0);
                    acc[ph * 2 + 1][cvt] = __builtin_amdgcn_mfma_f32_16x16x32_bf16(vf, pf1, acc[ph * 2 + 1][cvt], 0, 0, 0);
                }
            }
        }
    }

    // ---- epilogue: transpose acc through LDS -> coalesced pO stores ----
    __syncthreads();
    bf16* tbuf = &p_lds[wav][0][0][0];   // per-wave 2048 bf16 = [16 rows][128]
    const size_t pb = (size_t)ks * NB + b;
#pragma unroll
    for (int qt = 0; qt < 4; ++qt) {
        psum[qt] += __shfl_xor(psum[qt], 16);
        psum[qt] += __shfl_xor(psum[qt], 32);
#pragma unroll
        for (int cvt = 0; cvt < 8; ++cvt) {
            bf16x4 pk;
#pragma unroll
            for (int r = 0; r < 4; ++r) pk[r] = (bf16)acc[qt][cvt][r];
            const int u = (cvt * 4 + quad) ^ (l15 << 1);
            *(bf16x4*)&tbuf[l15 * 128 + u * 4] = pk;
        }
#pragma unroll
        for (int j = 0; j < 4; ++j) {
            const int row = j * 4 + (lane >> 4);
            const int g   = ((lane & 15) * 2) ^ ((row & 15) << 1);
            const bf16x8 vv = *(const bf16x8*)&tbuf[row * 128 + g * 4];
            *(bf16x8*)(pO + (pb * NN + q0 + qt * 16) * CVd + j * 512 + lane * 8) = vv;
        }
        if (quad == 0) pl[pb * NN + q0 + qt * 16 + l15] = psum[qt];
    }
}

// ---------------------------------------------------------------------------
// Fused combine + output projection (proven r9/r10).
// out = gamma*(W.ctx + W_b) + x.  grid (200, NB).
// ---------------------------------------------------------------------------
__launch_bounds__(256, 2)
__global__ void outproj_kernel(const bf16* __restrict__ pO, const float* __restrict__ pl,
                               const bf16* __restrict__ wob, const float* __restrict__ bias,
                               const float* __restrict__ x, const float* __restrict__ gam,
                               float* __restrict__ out, int KS)
{
    __shared__ __align__(16) bf16 wbuf[256 * 128];   // 64 KB
    __shared__ __align__(16) bf16 cbuf[32 * 128];    // 8 KB
    __shared__ float Lrow[32];

    const int tid  = threadIdx.x;
    const int lane = tid & 63, wav = tid >> 6;
    const int l15  = lane & 15, quad = lane >> 4;
    const int b    = blockIdx.y;
    const int n0   = blockIdx.x * 32;

    {
        const int r4 = lane >> 4;
        const int c  = lane & 15;
#pragma unroll
        for (int i = 0; i < 16; ++i) {
            const int rg = wav * 64 + i * 4;
            const int r  = rg + r4;
            const int cs = c ^ (r & 7);
            lds_cp16(wob + (size_t)r * CVd + cs * 8, &wbuf[rg * 128]);
        }
    }

    // ---- phase 1: accumulate KS chunks of pO, 16 vals/thread ----
    const int tn = tid >> 3;
    const int tc = (tid & 7) * 16;
    float vacc[16];
#pragma unroll
    for (int i = 0; i < 16; ++i) vacc[i] = 0.f;
    for (int ksi = 0; ksi < KS; ++ksi) {
        const bf16* src = pO + ((size_t)(ksi * NB + b) * NN + n0 + tn) * CVd + tc;
#pragma unroll
        for (int j = 0; j < 2; ++j) {
            const bf16x8 v = *(const bf16x8*)(src + j * 8);
#pragma unroll
            for (int e = 0; e < 8; ++e) vacc[j * 8 + e] += (float)v[e];
        }
    }
    if (tid < 32) {
        float L = 0.f;
        for (int ksi = 0; ksi < KS; ++ksi)
            L += pl[(size_t)(ksi * NB + b) * NN + n0 + tid];
        Lrow[tid] = 1.0f / L;
    }
    __syncthreads();
    {
        const float rL = Lrow[tn];
#pragma unroll
        for (int j = 0; j < 2; ++j) {
            bf16x8 o;
#pragma unroll
            for (int e = 0; e < 8; ++e) o[e] = (bf16)(vacc[j * 8 + e] * rL);
            const int c = (tid & 7) * 2 + j;
            *(bf16x8*)&cbuf[tn * 128 + ((c ^ (tn & 7)) * 8)] = o;
        }
    }
    __syncthreads();

    // ---- phase 2: MFMA, wave covers 64 co x 32 n ----
    f32x4 acc[4][2];
#pragma unroll
    for (int i = 0; i < 4; ++i)
#pragma unroll
        for (int j = 0; j < 2; ++j) acc[i][j] = (f32x4){0.f, 0.f, 0.f, 0.f};

#pragma unroll
    for (int kk = 0; kk < 4; ++kk) {
#pragma unroll
        for (int cot = 0; cot < 4; ++cot) {
            const int arow = wav * 64 + cot * 16 + l15;
            const bf16x8 af = *(const bf16x8*)&wbuf[arow * 128 + (((kk * 4 + quad) ^ (arow & 7)) * 8)];
#pragma unroll
            for (int nt = 0; nt < 2; ++nt) {
                const int brow = nt * 16 + l15;
                const bf16x8 bfc = *(const bf16x8*)&cbuf[brow * 128 + (((kk * 4 + quad) ^ (brow & 7)) * 8)];
                acc[cot][nt] = __builtin_amdgcn_mfma_f32_16x16x32_bf16(af, bfc, acc[cot][nt], 0, 0, 0);
            }
        }
    }

    const float gm = gam[0];
#pragma unroll
    for (int cot = 0; cot < 4; ++cot) {
#pragma unroll
        for (int r = 0; r < 4; ++r) {
            const int co = wav * 64 + cot * 16 + quad * 4 + r;
            const float bv = bias[256 + co];
#pragma unroll
            for (int nt = 0; nt < 2; ++nt) {
                const int n = n0 + nt * 16 + l15;
                const size_t a = ((size_t)b * COd + co) * NN + n;
                out[a] = gm * (acc[cot][nt][r] + bv) + x[a];
            }
        }
    }
}

// ---------------------------------------------------------------------------
extern "C" void kernel_launch(void* const* d_in, const int* in_sizes, int n_in,
                              void* d_out, int out_size, void* d_ws, size_t ws_size,
                              hipStream_t stream)
{
    const float* x     = (const float*)d_in[0];
    const float* y     = (const float*)d_in[1];
    const float* fk_w  = (const float*)d_in[2];
    const float* fk_g  = (const float*)d_in[3];
    const float* fk_b  = (const float*)d_in[4];
    const float* fk_m  = (const float*)d_in[5];
    const float* fk_v  = (const float*)d_in[6];
    const float* fq_w  = (const float*)d_in[7];
    const float* fq_g  = (const float*)d_in[8];
    const float* fq_b  = (const float*)d_in[9];
    const float* fq_m  = (const float*)d_in[10];
    const float* fq_v  = (const float*)d_in[11];
    const float* fv_w  = (const float*)d_in[12];
    const float* fv_b  = (const float*)d_in[13];
    const float* W_w   = (const float*)d_in[14];
    const float* W_b   = (const float*)d_in[15];
    const float* gamma = (const float*)d_in[16];
    float* out = (float*)d_out;

    char* ws = (char*)d_ws;
    size_t off = 0;
    auto carve = [&](size_t bytes) -> char* {
        char* p = ws + off;
        off = (off + bytes + 255) & ~(size_t)255;
        return p;
    };

    bf16*  kb   = (bf16*)carve((size_t)NB * NN * CKd * 2);
    bf16*  qbuf = (bf16*)carve((size_t)NB * NN * CKd * 2);
    bf16*  vb   = (bf16*)carve((size_t)NB * CVd * NN * 2);
    bf16*  wkb  = (bf16*)carve((size_t)CKd * CIN * 2);
    bf16*  wqb  = (bf16*)carve((size_t)CKd * CIN * 2);
    bf16*  wvb  = (bf16*)carve((size_t)CVd * CIN * 2);
    bf16*  wob  = (bf16*)carve((size_t)COd * CVd * 2);
    float* bias = (float*)carve(512 * 4);

    const size_t alias_start = off;
    bf16* xT = (bf16*)carve((size_t)NB * NN * CIN * 2);
    bf16* yT = (bf16*)carve((size_t)NB * NN * CIN * 2);

    const size_t region = ws_size - alias_start;
    const size_t per_ks = (size_t)NB * NN * CVd * 2 + (size_t)NB * NN * 4 + 512;
    int KS = 1;
    {
        const int cand[6] = {10, 8, 5, 4, 2, 1};
        for (int i = 0; i < 6; ++i)
            if ((size_t)cand[i] * per_ks <= region) { KS = cand[i]; break; }
    }
    bf16*  pO = (bf16*)(ws + alias_start);
    float* pl = (float*)(ws + alias_start + (size_t)KS * NB * NN * CVd * 2);

    const dim3 blk(256);
    tcvt_prep_kernel<<<dim3(100, 4, 5), blk, 0, stream>>>(x, y, xT, yT,
                                                          fk_w, fk_g, fk_b, fk_m, fk_v,
                                                          fq_w, fq_g, fq_b, fq_m, fq_v,
                                                          fv_w, fv_b, W_w, W_b,
                                                          wkb, wqb, wvb, wob, bias);
    projkqv_kernel<<<dim3(100, 4, NB), blk, 0, stream>>>(xT, yT, wkb, wqb, wvb, bias, kb, qbuf, vb);
    attn_kernel<<<dim3(25 * NB * KS), blk, 0, stream>>>(qbuf, kb, vb, pO, pl, KS);
    outproj_kernel<<<dim3(200, NB), blk, 0, stream>>>(pO, pl, wob, bias, x, gamma, out, KS);
}

// Round 13
// 173.689 us; speedup vs baseline: 1.3615x; 1.0039x over previous
//
#include <hip/hip_runtime.h>
#include <math.h>

#define NB   2
#define CIN  256
#define NN   6400
#define CKd  64
#define CVd  128
#define COd  256

using bf16   = __bf16;
using bf16x4 = __attribute__((ext_vector_type(4))) bf16;
using bf16x8 = __attribute__((ext_vector_type(8))) bf16;
using f32x4  = __attribute__((ext_vector_type(4))) float;

__device__ __forceinline__ void lds_cp16(const void* g, void* l) {
    __builtin_amdgcn_global_load_lds((const __attribute__((address_space(1))) void*)g,
                                     (__attribute__((address_space(3))) void*)l, 16, 0, 0);
}

// ---------------------------------------------------------------------------
// Fold BN into bf16 weights + fp32 biases.  q weights/bias pre-scaled by
// 0.125*log2(e) so attn softmax is p = exp2(s + c).
// ---------------------------------------------------------------------------
__global__ void prep_kernel(const float* __restrict__ fk_w, const float* __restrict__ fk_g,
                            const float* __restrict__ fk_b, const float* __restrict__ fk_m,
                            const float* __restrict__ fk_v,
                            const float* __restrict__ fq_w, const float* __restrict__ fq_g,
                            const float* __restrict__ fq_b, const float* __restrict__ fq_m,
                            const float* __restrict__ fq_v,
                            const float* __restrict__ fv_w, const float* __restrict__ fv_b,
                            const float* __restrict__ W_w,  const float* __restrict__ W_b,
                            bf16* __restrict__ wkb, bf16* __restrict__ wqb,
                            bf16* __restrict__ wvb, bf16* __restrict__ wob,
                            float* __restrict__ bias)
{
    const int idx = blockIdx.x * 256 + threadIdx.x;
    const float QS = 0.18033688011112042f;   // 0.125 * log2(e)
    if (idx < 16384) {
        const int co = idx >> 8;
        const float a = fk_g[co] * rsqrtf(fk_v[co] + 1e-5f);
        wkb[idx] = (bf16)(fk_w[idx] * a);
    } else if (idx < 32768) {
        const int i = idx - 16384, co = i >> 8;
        const float a = fq_g[co] * rsqrtf(fq_v[co] + 1e-5f) * QS;
        wqb[i] = (bf16)(fq_w[i] * a);
    } else if (idx < 65536) {
        const int i = idx - 32768;
        wvb[i] = (bf16)fv_w[i];
    } else if (idx < 98304) {
        const int i = idx - 65536;
        wob[i] = (bf16)W_w[i];
    } else if (idx < 98816) {
        const int j = idx - 98304;
        if (j < 64)       { const float a = fk_g[j] * rsqrtf(fk_v[j] + 1e-5f); bias[j] = fk_b[j] - fk_m[j] * a; }
        else if (j < 128) { const int c = j - 64; const float a = fq_g[c] * rsqrtf(fq_v[c] + 1e-5f); bias[j] = (fq_b[c] - fq_m[c] * a) * QS; }
        else if (j < 256) bias[j] = fv_b[j - 128];
        else              bias[j] = W_b[j - 256];
    }
}

// ---------------------------------------------------------------------------
// FUSED transpose+cvt + k/q/v projection (kills the 78 MB xT/yT round-trip):
// src tile staged in-kernel: coalesced float4 loads from x/y [c][n], cvt to
// bf16, scalar-scatter into sbuf[n][c] with the SAME 16B-chunk XOR swizzle
// the proven MFMA read path uses (write chunk (c>>3)^(n&7); read chunk
// L^(arow&7), arow&7==l15&7 — verified consistent).
// Weights staged via global_load_lds DMA as before.
// grid (100, 4, NB): m=0 k (from x), m=1 q, m=2,3 v halves (from y).
// LDS 64 KB -> 2 blocks/CU.
// ---------------------------------------------------------------------------
__launch_bounds__(256, 2)
__global__ void projkqv_kernel(const float* __restrict__ x, const float* __restrict__ y,
                               const bf16* __restrict__ wkb, const bf16* __restrict__ wqb,
                               const bf16* __restrict__ wvb, const float* __restrict__ bias,
                               bf16* __restrict__ kb, bf16* __restrict__ qb, bf16* __restrict__ vb)
{
    __shared__ __align__(16) bf16 sbuf[64 * 256];   // src [n][c], XOR chunks
    __shared__ __align__(16) bf16 wbuf[64 * 256];   // weights, XOR chunks

    const int tid  = threadIdx.x;
    const int lane = tid & 63, wav = tid >> 6;
    const int l15  = lane & 15, quad = lane >> 4;
    const int b    = blockIdx.z, m = blockIdx.y;
    const int n0   = blockIdx.x * 64;

    const float* srcg = ((m == 0) ? x : y) + (size_t)b * CIN * NN;
    const bf16* wg    = (m == 0) ? wkb : (m == 1) ? wqb : (wvb + (size_t)(m - 2) * 64 * CIN);

    // weights DMA (2 rows / inst, source-side XOR)
    {
        const int r2  = lane >> 5;
        const int c32 = lane & 31;
#pragma unroll
        for (int i = 0; i < 8; ++i) {
            const int rg = wav * 16 + i * 2;
            const int r  = rg + r2;
            const int cs = c32 ^ (r & 7);
            lds_cp16(wg + (size_t)r * 256 + cs * 8, &wbuf[rg * 256]);
        }
    }

    // src load + cvt + swizzled scatter (fused tcvt)
    {
        const int cb = tid >> 4;            // base c row
        const int nl = (tid & 15) * 4;      // 4 consecutive n
#pragma unroll
        for (int p = 0; p < 16; ++p) {
            const int c = cb + p * 16;
            const float4 v = *(const float4*)(srcg + (size_t)c * NN + n0 + nl);
            const int c16 = c >> 3, ce = c & 7;
#pragma unroll
            for (int i = 0; i < 4; ++i) {
                const int n = nl + i;
                sbuf[n * 256 + ((c16 ^ (n & 7)) << 3) + ce] = (bf16)(&v.x)[i];
            }
        }
    }
    __syncthreads();

    const int key = l15 & 7;
    f32x4 acc[4];
#pragma unroll
    for (int j = 0; j < 4; ++j) acc[j] = (f32x4){0.f, 0.f, 0.f, 0.f};

    if (m < 2) {
        const int arow = wav * 16 + l15;
#pragma unroll
        for (int k4 = 0; k4 < 32; k4 += 4) {
            const bf16x8 af = *(const bf16x8*)&sbuf[arow * 256 + ((k4 + quad) ^ key) * 8];
#pragma unroll
            for (int nt = 0; nt < 4; ++nt) {
                const int brow = nt * 16 + l15;
                const bf16x8 bfw = *(const bf16x8*)&wbuf[brow * 256 + ((k4 + quad) ^ key) * 8];
                acc[nt] = __builtin_amdgcn_mfma_f32_16x16x32_bf16(af, bfw, acc[nt], 0, 0, 0);
            }
        }
        const float* bs = bias + m * 64;
        bf16* dst = (m == 0) ? kb : qb;
        const int nb = n0 + wav * 16;
#pragma unroll
        for (int nt = 0; nt < 4; ++nt) {
            const float bv = bs[nt * 16 + l15];
#pragma unroll
            for (int r = 0; r < 4; ++r) {
                const int n = nb + quad * 4 + r;
                dst[((size_t)b * NN + n) * CKd + nt * 16 + l15] = (bf16)(acc[nt][r] + bv);
            }
        }
    } else {
        const int arow = wav * 16 + l15;
#pragma unroll
        for (int k4 = 0; k4 < 32; k4 += 4) {
            const bf16x8 af = *(const bf16x8*)&wbuf[arow * 256 + ((k4 + quad) ^ key) * 8];
#pragma unroll
            for (int nt = 0; nt < 4; ++nt) {
                const int brow = nt * 16 + l15;
                const bf16x8 bfy = *(const bf16x8*)&sbuf[brow * 256 + ((k4 + quad) ^ key) * 8];
                acc[nt] = __builtin_amdgcn_mfma_f32_16x16x32_bf16(af, bfy, acc[nt], 0, 0, 0);
            }
        }
        const int cv0 = (m - 2) * 64 + wav * 16;
#pragma unroll
        for (int r = 0; r < 4; ++r) {
            const int cv = cv0 + quad * 4 + r;
            const float bv = bias[128 + cv];
#pragma unroll
            for (int nt = 0; nt < 4; ++nt)
                vb[((size_t)b * CVd + cv) * NN + n0 + nt * 16 + l15] = (bf16)(acc[nt][r] + bv);
        }
    }
}

// ---------------------------------------------------------------------------
// Flash attention v4 — EXACT r11 kernel (passed, 55.3 us).  NO wave-stagger:
// r12's stagger used runtime ph to index acc[4][8] (128 regs) / qf / psum —
// dynamic register indexing (v_movrel/scratch lowering) is the prime suspect
// for r12's GPU fault.  All indices here are compile-time.
// q=64/wave in two qt-pair phases; double-buffered K/V DMA, 1 barrier/iter;
// p = exp2(s + c) (q pre-scaled by log2e).  LDS 64 KB, (256,2), no spill.
// grid 25*NB*KS (KS=10 -> 500 blocks, one balanced round).
// ---------------------------------------------------------------------------
__launch_bounds__(256, 2)
__global__ void attn_kernel(const bf16* __restrict__ qb, const bf16* __restrict__ kb,
                            const bf16* __restrict__ vb,
                            bf16* __restrict__ pO, float* __restrict__ pl, int KS)
{
    __shared__ __align__(16) bf16 kbuf[2][64 * 64];        // 16 KB
    __shared__ __align__(16) bf16 vbuf[2][128 * 64];       // 32 KB
    __shared__ __align__(16) bf16 p_lds[4][2][16][64];     // 16 KB per-wave/qt-pair

    const int lane = threadIdx.x & 63;
    const int wav  = threadIdx.x >> 6;
    const int l15  = lane & 15;
    const int quad = lane >> 4;
    const int r8   = lane >> 3;
    const int c_src = (lane & 7) ^ r8;
    const int sw   = l15 & 7;
    const int pkey = (l15 & 7) << 1;

    const int id    = blockIdx.x;
    const int ks    = id % KS;
    const int rst   = id / KS;
    const int b     = rst & 1;
    const int qtile = rst >> 1;
    const int q0    = qtile * 256 + wav * 64;

    const bf16* qrow = qb + (size_t)b * NN * CKd;
    const bf16* krow = kb + (size_t)b * NN * CKd;
    const bf16* vrow = vb + (size_t)b * CVd * NN;

    bf16x8 qf[4][2];
#pragma unroll
    for (int qt = 0; qt < 4; ++qt)
#pragma unroll
        for (int s = 0; s < 2; ++s)
            qf[qt][s] = *(const bf16x8*)(qrow + (size_t)(q0 + qt * 16 + l15) * CKd + s * 32 + quad * 8);

    f32x4 acc[4][8];
#pragma unroll
    for (int qt = 0; qt < 4; ++qt)
#pragma unroll
        for (int cv = 0; cv < 8; ++cv) acc[qt][cv] = (f32x4){0.f, 0.f, 0.f, 0.f};
    float psum[4] = {0.f, 0.f, 0.f, 0.f};

    const int t0 = (100 * ks) / KS;
    const int nt = (100 * (ks + 1)) / KS - t0;

    auto stage = [&](int t, int bi) {
        const int key0 = t * 64;
        lds_cp16(krow + (size_t)(key0 + wav * 8 + r8) * CKd + c_src * 8,
                 &kbuf[bi][(wav * 8) * 64]);
        lds_cp16(krow + (size_t)(key0 + (wav + 4) * 8 + r8) * CKd + c_src * 8,
                 &kbuf[bi][((wav + 4) * 8) * 64]);
#pragma unroll
        for (int g4 = 0; g4 < 4; ++g4) {
            const int g = wav * 4 + g4;
            lds_cp16(vrow + (size_t)(g * 8 + r8) * NN + key0 + c_src * 8,
                     &vbuf[bi][(g * 8) * 64]);
        }
    };

    stage(t0, 0);   // prologue

    for (int t = 0; t < nt; ++t) {
        __syncthreads();                    // drains DMA(t); guards buf reuse
        if (t + 1 < nt) stage(t0 + t + 1, (t + 1) & 1);
        const bf16* kcur = &kbuf[t & 1][0];
        const bf16* vcur = &vbuf[t & 1][0];

#pragma unroll
        for (int ph = 0; ph < 2; ++ph) {
            // ---- S^T = K * Q^T for this qt-pair ----
            f32x4 s4[2][4];
#pragma unroll
            for (int kt = 0; kt < 4; ++kt) {
                const int rr = kt * 16 + l15;
                const bf16x8 kf0 = *(const bf16x8*)&kcur[rr * 64 + ((quad ^ sw) * 8)];
                const bf16x8 kf1 = *(const bf16x8*)&kcur[rr * 64 + (((4 + quad) ^ sw) * 8)];
#pragma unroll
                for (int qtl = 0; qtl < 2; ++qtl) {
                    const int qt = ph * 2 + qtl;
                    f32x4 z = (f32x4){0.f, 0.f, 0.f, 0.f};
                    z = __builtin_amdgcn_mfma_f32_16x16x32_bf16(kf0, qf[qt][0], z, 0, 0, 0);
                    z = __builtin_amdgcn_mfma_f32_16x16x32_bf16(kf1, qf[qt][1], z, 0, 0, 0);
                    s4[qtl][kt] = z;
                }
            }

            // ---- p = exp2(s + c) [q pre-scaled by log2e], pack to LDS ----
#pragma unroll
            for (int qtl = 0; qtl < 2; ++qtl) {
                float ps = 0.f;
#pragma unroll
                for (int kt = 0; kt < 4; ++kt) {
                    bf16x4 pk;
#pragma unroll
                    for (int r = 0; r < 4; ++r) {
                        const float p = exp2f(s4[qtl][kt][r] - 11.541560327111707f);
                        ps += p;
                        pk[r] = (bf16)p;
                    }
                    *(bf16x4*)&p_lds[wav][qtl][l15][((kt * 4 + quad) ^ pkey) * 4] = pk;
                }
                psum[ph * 2 + qtl] += ps;
            }

            // ---- ctx^T += V^T * P^T for this qt-pair ----
#pragma unroll
            for (int sp = 0; sp < 2; ++sp) {
                const bf16x8 pf0 = *(const bf16x8*)&p_lds[wav][0][l15][((sp * 8 + quad * 2) ^ pkey) * 4];
                const bf16x8 pf1 = *(const bf16x8*)&p_lds[wav][1][l15][((sp * 8 + quad * 2) ^ pkey) * 4];
#pragma unroll
                for (int cvt = 0; cvt < 8; ++cvt) {
                    const int rr = cvt * 16 + l15;
                    const bf16x8 vf = *(const bf16x8*)&vcur[rr * 64 + (((sp * 4 + quad) ^ sw) * 8)];
                    acc[ph * 2 + 0][cvt] = __builtin_amdgcn_mfma_f32_16x16x32_bf16(vf, pf0, acc[ph * 2 + 0][cvt], 0, 0, 0);
                    acc[ph * 2 + 1][cvt] = __builtin_amdgcn_mfma_f32_16x16x32_bf16(vf, pf1, acc[ph * 2 + 1][cvt], 0, 0, 0);
                }
            }
        }
    }

    // ---- epilogue: transpose acc through LDS -> coalesced pO stores ----
    __syncthreads();
    bf16* tbuf = &p_lds[wav][0][0][0];   // per-wave 2048 bf16 = [16 rows][128]
    const size_t pb = (size_t)ks * NB + b;
#pragma unroll
    for (int qt = 0; qt < 4; ++qt) {
        psum[qt] += __shfl_xor(psum[qt], 16);
        psum[qt] += __shfl_xor(psum[qt], 32);
#pragma unroll
        for (int cvt = 0; cvt < 8; ++cvt) {
            bf16x4 pk;
#pragma unroll
            for (int r = 0; r < 4; ++r) pk[r] = (bf16)acc[qt][cvt][r];
            const int u = (cvt * 4 + quad) ^ (l15 << 1);
            *(bf16x4*)&tbuf[l15 * 128 + u * 4] = pk;
        }
#pragma unroll
        for (int j = 0; j < 4; ++j) {
            const int row = j * 4 + (lane >> 4);
            const int g   = ((lane & 15) * 2) ^ ((row & 15) << 1);
            const bf16x8 vv = *(const bf16x8*)&tbuf[row * 128 + g * 4];
            *(bf16x8*)(pO + (pb * NN + q0 + qt * 16) * CVd + j * 512 + lane * 8) = vv;
        }
        if (quad == 0) pl[pb * NN + q0 + qt * 16 + l15] = psum[qt];
    }
}

// ---------------------------------------------------------------------------
// Fused combine + output projection (proven r9-r11).
// out = gamma*(W.ctx + W_b) + x.  grid (200, NB).
// ---------------------------------------------------------------------------
__launch_bounds__(256, 2)
__global__ void outproj_kernel(const bf16* __restrict__ pO, const float* __restrict__ pl,
                               const bf16* __restrict__ wob, const float* __restrict__ bias,
                               const float* __restrict__ x, const float* __restrict__ gam,
                               float* __restrict__ out, int KS)
{
    __shared__ __align__(16) bf16 wbuf[256 * 128];   // 64 KB
    __shared__ __align__(16) bf16 cbuf[32 * 128];    // 8 KB
    __shared__ float Lrow[32];

    const int tid  = threadIdx.x;
    const int lane = tid & 63, wav = tid >> 6;
    const int l15  = lane & 15, quad = lane >> 4;
    const int b    = blockIdx.y;
    const int n0   = blockIdx.x * 32;

    {
        const int r4 = lane >> 4;
        const int c  = lane & 15;
#pragma unroll
        for (int i = 0; i < 16; ++i) {
            const int rg = wav * 64 + i * 4;
            const int r  = rg + r4;
            const int cs = c ^ (r & 7);
            lds_cp16(wob + (size_t)r * CVd + cs * 8, &wbuf[rg * 128]);
        }
    }

    // ---- phase 1: accumulate KS chunks of pO, 16 vals/thread ----
    const int tn = tid >> 3;
    const int tc = (tid & 7) * 16;
    float vacc[16];
#pragma unroll
    for (int i = 0; i < 16; ++i) vacc[i] = 0.f;
    for (int ksi = 0; ksi < KS; ++ksi) {
        const bf16* src = pO + ((size_t)(ksi * NB + b) * NN + n0 + tn) * CVd + tc;
#pragma unroll
        for (int j = 0; j < 2; ++j) {
            const bf16x8 v = *(const bf16x8*)(src + j * 8);
#pragma unroll
            for (int e = 0; e < 8; ++e) vacc[j * 8 + e] += (float)v[e];
        }
    }
    if (tid < 32) {
        float L = 0.f;
        for (int ksi = 0; ksi < KS; ++ksi)
            L += pl[(size_t)(ksi * NB + b) * NN + n0 + tid];
        Lrow[tid] = 1.0f / L;
    }
    __syncthreads();
    {
        const float rL = Lrow[tn];
#pragma unroll
        for (int j = 0; j < 2; ++j) {
            bf16x8 o;
#pragma unroll
            for (int e = 0; e < 8; ++e) o[e] = (bf16)(vacc[j * 8 + e] * rL);
            const int c = (tid & 7) * 2 + j;
            *(bf16x8*)&cbuf[tn * 128 + ((c ^ (tn & 7)) * 8)] = o;
        }
    }
    __syncthreads();

    // ---- phase 2: MFMA, wave covers 64 co x 32 n ----
    f32x4 acc[4][2];
#pragma unroll
    for (int i = 0; i < 4; ++i)
#pragma unroll
        for (int j = 0; j < 2; ++j) acc[i][j] = (f32x4){0.f, 0.f, 0.f, 0.f};

#pragma unroll
    for (int kk = 0; kk < 4; ++kk) {
#pragma unroll
        for (int cot = 0; cot < 4; ++cot) {
            const int arow = wav * 64 + cot * 16 + l15;
            const bf16x8 af = *(const bf16x8*)&wbuf[arow * 128 + (((kk * 4 + quad) ^ (arow & 7)) * 8)];
#pragma unroll
            for (int nt = 0; nt < 2; ++nt) {
                const int brow = nt * 16 + l15;
                const bf16x8 bfc = *(const bf16x8*)&cbuf[brow * 128 + (((kk * 4 + quad) ^ (brow & 7)) * 8)];
                acc[cot][nt] = __builtin_amdgcn_mfma_f32_16x16x32_bf16(af, bfc, acc[cot][nt], 0, 0, 0);
            }
        }
    }

    const float gm = gam[0];
#pragma unroll
    for (int cot = 0; cot < 4; ++cot) {
#pragma unroll
        for (int r = 0; r < 4; ++r) {
            const int co = wav * 64 + cot * 16 + quad * 4 + r;
            const float bv = bias[256 + co];
#pragma unroll
            for (int nt = 0; nt < 2; ++nt) {
                const int n = n0 + nt * 16 + l15;
                const size_t a = ((size_t)b * COd + co) * NN + n;
                out[a] = gm * (acc[cot][nt][r] + bv) + x[a];
            }
        }
    }
}

// ---------------------------------------------------------------------------
extern "C" void kernel_launch(void* const* d_in, const int* in_sizes, int n_in,
                              void* d_out, int out_size, void* d_ws, size_t ws_size,
                              hipStream_t stream)
{
    const float* x     = (const float*)d_in[0];
    const float* y     = (const float*)d_in[1];
    const float* fk_w  = (const float*)d_in[2];
    const float* fk_g  = (const float*)d_in[3];
    const float* fk_b  = (const float*)d_in[4];
    const float* fk_m  = (const float*)d_in[5];
    const float* fk_v  = (const float*)d_in[6];
    const float* fq_w  = (const float*)d_in[7];
    const float* fq_g  = (const float*)d_in[8];
    const float* fq_b  = (const float*)d_in[9];
    const float* fq_m  = (const float*)d_in[10];
    const float* fq_v  = (const float*)d_in[11];
    const float* fv_w  = (const float*)d_in[12];
    const float* fv_b  = (const float*)d_in[13];
    const float* W_w   = (const float*)d_in[14];
    const float* W_b   = (const float*)d_in[15];
    const float* gamma = (const float*)d_in[16];
    float* out = (float*)d_out;

    char* ws = (char*)d_ws;
    size_t off = 0;
    auto carve = [&](size_t bytes) -> char* {
        char* p = ws + off;
        off = (off + bytes + 255) & ~(size_t)255;
        return p;
    };

    bf16*  kb   = (bf16*)carve((size_t)NB * NN * CKd * 2);
    bf16*  qbuf = (bf16*)carve((size_t)NB * NN * CKd * 2);
    bf16*  vb   = (bf16*)carve((size_t)NB * CVd * NN * 2);
    bf16*  wkb  = (bf16*)carve((size_t)CKd * CIN * 2);
    bf16*  wqb  = (bf16*)carve((size_t)CKd * CIN * 2);
    bf16*  wvb  = (bf16*)carve((size_t)CVd * CIN * 2);
    bf16*  wob  = (bf16*)carve((size_t)COd * CVd * 2);
    float* bias = (float*)carve(512 * 4);

    const size_t region = ws_size - off;
    const size_t per_ks = (size_t)NB * NN * CVd * 2 + (size_t)NB * NN * 4 + 512;
    int KS = 1;
    {
        const int cand[6] = {10, 8, 5, 4, 2, 1};
        for (int i = 0; i < 6; ++i)
            if ((size_t)cand[i] * per_ks <= region) { KS = cand[i]; break; }
    }
    bf16*  pO = (bf16*)carve((size_t)KS * NB * NN * CVd * 2);
    float* pl = (float*)carve((size_t)KS * NB * NN * 4);

    const dim3 blk(256);
    prep_kernel<<<386, blk, 0, stream>>>(fk_w, fk_g, fk_b, fk_m, fk_v,
                                         fq_w, fq_g, fq_b, fq_m, fq_v,
                                         fv_w, fv_b, W_w, W_b,
                                         wkb, wqb, wvb, wob, bias);
    projkqv_kernel<<<dim3(100, 4, NB), blk, 0, stream>>>(x, y, wkb, wqb, wvb, bias, kb, qbuf, vb);
    attn_kernel<<<dim3(25 * NB * KS), blk, 0, stream>>>(qbuf, kb, vb, pO, pl, KS);
    outproj_kernel<<<dim3(200, NB), blk, 0, stream>>>(pO, pl, wob, bias, x, gamma, out, KS);
}

// Round 14
// 171.293 us; speedup vs baseline: 1.3806x; 1.0140x over previous
//
#include <hip/hip_runtime.h>
#include <math.h>

#define NB   2
#define CIN  256
#define NN   6400
#define CKd  64
#define CVd  128
#define COd  256

using bf16   = __bf16;
using bf16x4 = __attribute__((ext_vector_type(4))) bf16;
using bf16x8 = __attribute__((ext_vector_type(8))) bf16;
using f32x4  = __attribute__((ext_vector_type(4))) float;

__device__ __forceinline__ void lds_cp16(const void* g, void* l) {
    __builtin_amdgcn_global_load_lds((const __attribute__((address_space(1))) void*)g,
                                     (__attribute__((address_space(3))) void*)l, 16, 0, 0);
}

// ---------------------------------------------------------------------------
// Fold BN into bf16 weights + fp32 biases.  q weights/bias pre-scaled by
// 0.125*log2(e) so attn softmax is p = exp2(s + c).
// ---------------------------------------------------------------------------
__global__ void prep_kernel(const float* __restrict__ fk_w, const float* __restrict__ fk_g,
                            const float* __restrict__ fk_b, const float* __restrict__ fk_m,
                            const float* __restrict__ fk_v,
                            const float* __restrict__ fq_w, const float* __restrict__ fq_g,
                            const float* __restrict__ fq_b, const float* __restrict__ fq_m,
                            const float* __restrict__ fq_v,
                            const float* __restrict__ fv_w, const float* __restrict__ fv_b,
                            const float* __restrict__ W_w,  const float* __restrict__ W_b,
                            bf16* __restrict__ wkb, bf16* __restrict__ wqb,
                            bf16* __restrict__ wvb, bf16* __restrict__ wob,
                            float* __restrict__ bias)
{
    const int idx = blockIdx.x * 256 + threadIdx.x;
    const float QS = 0.18033688011112042f;   // 0.125 * log2(e)
    if (idx < 16384) {
        const int co = idx >> 8;
        const float a = fk_g[co] * rsqrtf(fk_v[co] + 1e-5f);
        wkb[idx] = (bf16)(fk_w[idx] * a);
    } else if (idx < 32768) {
        const int i = idx - 16384, co = i >> 8;
        const float a = fq_g[co] * rsqrtf(fq_v[co] + 1e-5f) * QS;
        wqb[i] = (bf16)(fq_w[i] * a);
    } else if (idx < 65536) {
        const int i = idx - 32768;
        wvb[i] = (bf16)fv_w[i];
    } else if (idx < 98304) {
        const int i = idx - 65536;
        wob[i] = (bf16)W_w[i];
    } else if (idx < 98816) {
        const int j = idx - 98304;
        if (j < 64)       { const float a = fk_g[j] * rsqrtf(fk_v[j] + 1e-5f); bias[j] = fk_b[j] - fk_m[j] * a; }
        else if (j < 128) { const int c = j - 64; const float a = fq_g[c] * rsqrtf(fq_v[c] + 1e-5f); bias[j] = (fq_b[c] - fq_m[c] * a) * QS; }
        else if (j < 256) bias[j] = fv_b[j - 128];
        else              bias[j] = W_b[j - 256];
    }
}

// ---------------------------------------------------------------------------
// FUSED transpose+cvt + k/q/v projection.  v2 staging: each thread loads 8
// ROWS (float4 = 4 n each), packs 8 c per n in registers, writes ONE
// ds_write_b128 per n (8 b128/thread vs r13's 64 scalar b16 — LDS issue 4x
// down; r13's fusion was perf-neutral because the scalar scatter re-paid the
// tcvt cost in-kernel).  Chunk mapping (c>>3)^(n&7) identical to r13 ->
// MFMA read path untouched.  grid (100, 4, NB), LDS 64 KB -> 2 blocks/CU.
// ---------------------------------------------------------------------------
__launch_bounds__(256, 2)
__global__ void projkqv_kernel(const float* __restrict__ x, const float* __restrict__ y,
                               const bf16* __restrict__ wkb, const bf16* __restrict__ wqb,
                               const bf16* __restrict__ wvb, const float* __restrict__ bias,
                               bf16* __restrict__ kb, bf16* __restrict__ qb, bf16* __restrict__ vb)
{
    __shared__ __align__(16) bf16 sbuf[64 * 256];   // src [n][c], XOR chunks
    __shared__ __align__(16) bf16 wbuf[64 * 256];   // weights, XOR chunks

    const int tid  = threadIdx.x;
    const int lane = tid & 63, wav = tid >> 6;
    const int l15  = lane & 15, quad = lane >> 4;
    const int b    = blockIdx.z, m = blockIdx.y;
    const int n0   = blockIdx.x * 64;

    const float* srcg = ((m == 0) ? x : y) + (size_t)b * CIN * NN;
    const bf16* wg    = (m == 0) ? wkb : (m == 1) ? wqb : (wvb + (size_t)(m - 2) * 64 * CIN);

    // weights DMA (2 rows / inst, source-side XOR)
    {
        const int r2  = lane >> 5;
        const int c32 = lane & 31;
#pragma unroll
        for (int i = 0; i < 8; ++i) {
            const int rg = wav * 16 + i * 2;
            const int r  = rg + r2;
            const int cs = c32 ^ (r & 7);
            lds_cp16(wg + (size_t)r * 256 + cs * 8, &wbuf[rg * 256]);
        }
    }

    // src load + cvt + packed b128 scatter (fused tcvt, registers transpose)
    {
        const int nl = (tid & 15) * 4;
        const int cq = tid >> 4;            // 0..15
#pragma unroll
        for (int g = 0; g < 2; ++g) {
            const int cb = (cq + g * 16) * 8;   // 8-aligned c group
            float4 v[8];
#pragma unroll
            for (int e = 0; e < 8; ++e)
                v[e] = *(const float4*)(srcg + (size_t)(cb + e) * NN + n0 + nl);
#pragma unroll
            for (int i = 0; i < 4; ++i) {
                const int n = nl + i;
                bf16x8 pk;
#pragma unroll
                for (int e = 0; e < 8; ++e) pk[e] = (bf16)(&v[e].x)[i];
                *(bf16x8*)&sbuf[n * 256 + (((cb >> 3) ^ (n & 7)) * 8)] = pk;
            }
        }
    }
    __syncthreads();

    const int key = l15 & 7;
    f32x4 acc[4];
#pragma unroll
    for (int j = 0; j < 4; ++j) acc[j] = (f32x4){0.f, 0.f, 0.f, 0.f};

    if (m < 2) {
        const int arow = wav * 16 + l15;
#pragma unroll
        for (int k4 = 0; k4 < 32; k4 += 4) {
            const bf16x8 af = *(const bf16x8*)&sbuf[arow * 256 + ((k4 + quad) ^ key) * 8];
#pragma unroll
            for (int nt = 0; nt < 4; ++nt) {
                const int brow = nt * 16 + l15;
                const bf16x8 bfw = *(const bf16x8*)&wbuf[brow * 256 + ((k4 + quad) ^ key) * 8];
                acc[nt] = __builtin_amdgcn_mfma_f32_16x16x32_bf16(af, bfw, acc[nt], 0, 0, 0);
            }
        }
        const float* bs = bias + m * 64;
        bf16* dst = (m == 0) ? kb : qb;
        const int nb = n0 + wav * 16;
#pragma unroll
        for (int nt = 0; nt < 4; ++nt) {
            const float bv = bs[nt * 16 + l15];
#pragma unroll
            for (int r = 0; r < 4; ++r) {
                const int n = nb + quad * 4 + r;
                dst[((size_t)b * NN + n) * CKd + nt * 16 + l15] = (bf16)(acc[nt][r] + bv);
            }
        }
    } else {
        const int arow = wav * 16 + l15;
#pragma unroll
        for (int k4 = 0; k4 < 32; k4 += 4) {
            const bf16x8 af = *(const bf16x8*)&wbuf[arow * 256 + ((k4 + quad) ^ key) * 8];
#pragma unroll
            for (int nt = 0; nt < 4; ++nt) {
                const int brow = nt * 16 + l15;
                const bf16x8 bfy = *(const bf16x8*)&sbuf[brow * 256 + ((k4 + quad) ^ key) * 8];
                acc[nt] = __builtin_amdgcn_mfma_f32_16x16x32_bf16(af, bfy, acc[nt], 0, 0, 0);
            }
        }
        const int cv0 = (m - 2) * 64 + wav * 16;
#pragma unroll
        for (int r = 0; r < 4; ++r) {
            const int cv = cv0 + quad * 4 + r;
            const float bv = bias[128 + cv];
#pragma unroll
            for (int nt = 0; nt < 4; ++nt)
                vb[((size_t)b * CVd + cv) * NN + n0 + nt * 16 + l15] = (bf16)(acc[nt][r] + bv);
        }
    }
}

// ---------------------------------------------------------------------------
// Flash attention v5: r13 + static software-pipeline:
//   QK(0) -> exp/pack(0) -> QK(1) -> hoist pf(0) -> PV(0) -> exp/pack(1)
//   -> pf(1) -> PV(1)
// exp(1) depends only on QK(1) (completed long before), so its VALU work
// issues while PV(0)'s 16 MFMAs occupy the matrix pipe — intra-wave
// VALU/MFMA overlap with ALL indices compile-time (r12's fault was runtime
// register indexing; none here).  pack(1) writes p_lds after pf(0) reads in
// program order (same-wave LDS ordering + compiler lgkmcnt keeps it safe).
// Live regs: acc 128 + qf 32 + s4b 32 + pf 16 + misc ~25 = ~235 < 256 (256,2).
// Everything else identical to r13.  grid 25*NB*KS (KS=10 -> 500 blocks).
// ---------------------------------------------------------------------------
__launch_bounds__(256, 2)
__global__ void attn_kernel(const bf16* __restrict__ qb, const bf16* __restrict__ kb,
                            const bf16* __restrict__ vb,
                            bf16* __restrict__ pO, float* __restrict__ pl, int KS)
{
    __shared__ __align__(16) bf16 kbuf[2][64 * 64];        // 16 KB
    __shared__ __align__(16) bf16 vbuf[2][128 * 64];       // 32 KB
    __shared__ __align__(16) bf16 p_lds[4][2][16][64];     // 16 KB per-wave/qt-pair

    const int lane = threadIdx.x & 63;
    const int wav  = threadIdx.x >> 6;
    const int l15  = lane & 15;
    const int quad = lane >> 4;
    const int r8   = lane >> 3;
    const int c_src = (lane & 7) ^ r8;
    const int sw   = l15 & 7;
    const int pkey = (l15 & 7) << 1;

    const int id    = blockIdx.x;
    const int ks    = id % KS;
    const int rst   = id / KS;
    const int b     = rst & 1;
    const int qtile = rst >> 1;
    const int q0    = qtile * 256 + wav * 64;

    const bf16* qrow = qb + (size_t)b * NN * CKd;
    const bf16* krow = kb + (size_t)b * NN * CKd;
    const bf16* vrow = vb + (size_t)b * CVd * NN;

    bf16x8 qf[4][2];
#pragma unroll
    for (int qt = 0; qt < 4; ++qt)
#pragma unroll
        for (int s = 0; s < 2; ++s)
            qf[qt][s] = *(const bf16x8*)(qrow + (size_t)(q0 + qt * 16 + l15) * CKd + s * 32 + quad * 8);

    f32x4 acc[4][8];
#pragma unroll
    for (int qt = 0; qt < 4; ++qt)
#pragma unroll
        for (int cv = 0; cv < 8; ++cv) acc[qt][cv] = (f32x4){0.f, 0.f, 0.f, 0.f};
    float psum[4] = {0.f, 0.f, 0.f, 0.f};

    const int t0 = (100 * ks) / KS;
    const int nt = (100 * (ks + 1)) / KS - t0;

    auto stage = [&](int t, int bi) {
        const int key0 = t * 64;
        lds_cp16(krow + (size_t)(key0 + wav * 8 + r8) * CKd + c_src * 8,
                 &kbuf[bi][(wav * 8) * 64]);
        lds_cp16(krow + (size_t)(key0 + (wav + 4) * 8 + r8) * CKd + c_src * 8,
                 &kbuf[bi][((wav + 4) * 8) * 64]);
#pragma unroll
        for (int g4 = 0; g4 < 4; ++g4) {
            const int g = wav * 4 + g4;
            lds_cp16(vrow + (size_t)(g * 8 + r8) * NN + key0 + c_src * 8,
                     &vbuf[bi][(g * 8) * 64]);
        }
    };

    stage(t0, 0);   // prologue

    for (int t = 0; t < nt; ++t) {
        __syncthreads();                    // drains DMA(t); guards buf reuse
        if (t + 1 < nt) stage(t0 + t + 1, (t + 1) & 1);
        const bf16* kcur = &kbuf[t & 1][0];
        const bf16* vcur = &vbuf[t & 1][0];

        // ---- QK phase 0 (qt 0,1) ----
        f32x4 s4a[2][4];
#pragma unroll
        for (int kt = 0; kt < 4; ++kt) {
            const int rr = kt * 16 + l15;
            const bf16x8 kf0 = *(const bf16x8*)&kcur[rr * 64 + ((quad ^ sw) * 8)];
            const bf16x8 kf1 = *(const bf16x8*)&kcur[rr * 64 + (((4 + quad) ^ sw) * 8)];
#pragma unroll
            for (int qtl = 0; qtl < 2; ++qtl) {
                f32x4 z = (f32x4){0.f, 0.f, 0.f, 0.f};
                z = __builtin_amdgcn_mfma_f32_16x16x32_bf16(kf0, qf[qtl][0], z, 0, 0, 0);
                z = __builtin_amdgcn_mfma_f32_16x16x32_bf16(kf1, qf[qtl][1], z, 0, 0, 0);
                s4a[qtl][kt] = z;
            }
        }

        // ---- exp/pack phase 0 ----
#pragma unroll
        for (int qtl = 0; qtl < 2; ++qtl) {
            float ps = 0.f;
#pragma unroll
            for (int kt = 0; kt < 4; ++kt) {
                bf16x4 pk;
#pragma unroll
                for (int r = 0; r < 4; ++r) {
                    const float p = exp2f(s4a[qtl][kt][r] - 11.541560327111707f);
                    ps += p;
                    pk[r] = (bf16)p;
                }
                *(bf16x4*)&p_lds[wav][qtl][l15][((kt * 4 + quad) ^ pkey) * 4] = pk;
            }
            psum[qtl] += ps;
        }

        // ---- QK phase 1 (qt 2,3) — independent MFMA, issues early ----
        f32x4 s4b[2][4];
#pragma unroll
        for (int kt = 0; kt < 4; ++kt) {
            const int rr = kt * 16 + l15;
            const bf16x8 kf0 = *(const bf16x8*)&kcur[rr * 64 + ((quad ^ sw) * 8)];
            const bf16x8 kf1 = *(const bf16x8*)&kcur[rr * 64 + (((4 + quad) ^ sw) * 8)];
#pragma unroll
            for (int qtl = 0; qtl < 2; ++qtl) {
                f32x4 z = (f32x4){0.f, 0.f, 0.f, 0.f};
                z = __builtin_amdgcn_mfma_f32_16x16x32_bf16(kf0, qf[2 + qtl][0], z, 0, 0, 0);
                z = __builtin_amdgcn_mfma_f32_16x16x32_bf16(kf1, qf[2 + qtl][1], z, 0, 0, 0);
                s4b[qtl][kt] = z;
            }
        }

        // ---- hoist pf(0), then PV(0) into acc[0],acc[1] ----
        {
            bf16x8 pf[2][2];
#pragma unroll
            for (int qtl = 0; qtl < 2; ++qtl)
#pragma unroll
                for (int sp = 0; sp < 2; ++sp)
                    pf[qtl][sp] = *(const bf16x8*)&p_lds[wav][qtl][l15][((sp * 8 + quad * 2) ^ pkey) * 4];
#pragma unroll
            for (int sp = 0; sp < 2; ++sp)
#pragma unroll
                for (int cvt = 0; cvt < 8; ++cvt) {
                    const int rr = cvt * 16 + l15;
                    const bf16x8 vf = *(const bf16x8*)&vcur[rr * 64 + (((sp * 4 + quad) ^ sw) * 8)];
                    acc[0][cvt] = __builtin_amdgcn_mfma_f32_16x16x32_bf16(vf, pf[0][sp], acc[0][cvt], 0, 0, 0);
                    acc[1][cvt] = __builtin_amdgcn_mfma_f32_16x16x32_bf16(vf, pf[1][sp], acc[1][cvt], 0, 0, 0);
                }
        }

        // ---- exp/pack phase 1 (VALU — overlaps PV(0) MFMAs in flight) ----
#pragma unroll
        for (int qtl = 0; qtl < 2; ++qtl) {
            float ps = 0.f;
#pragma unroll
            for (int kt = 0; kt < 4; ++kt) {
                bf16x4 pk;
#pragma unroll
                for (int r = 0; r < 4; ++r) {
                    const float p = exp2f(s4b[qtl][kt][r] - 11.541560327111707f);
                    ps += p;
                    pk[r] = (bf16)p;
                }
                *(bf16x4*)&p_lds[wav][qtl][l15][((kt * 4 + quad) ^ pkey) * 4] = pk;
            }
            psum[2 + qtl] += ps;
        }

        // ---- pf(1), PV(1) into acc[2],acc[3] ----
        {
            bf16x8 pf[2][2];
#pragma unroll
            for (int qtl = 0; qtl < 2; ++qtl)
#pragma unroll
                for (int sp = 0; sp < 2; ++sp)
                    pf[qtl][sp] = *(const bf16x8*)&p_lds[wav][qtl][l15][((sp * 8 + quad * 2) ^ pkey) * 4];
#pragma unroll
            for (int sp = 0; sp < 2; ++sp)
#pragma unroll
                for (int cvt = 0; cvt < 8; ++cvt) {
                    const int rr = cvt * 16 + l15;
                    const bf16x8 vf = *(const bf16x8*)&vcur[rr * 64 + (((sp * 4 + quad) ^ sw) * 8)];
                    acc[2][cvt] = __builtin_amdgcn_mfma_f32_16x16x32_bf16(vf, pf[0][sp], acc[2][cvt], 0, 0, 0);
                    acc[3][cvt] = __builtin_amdgcn_mfma_f32_16x16x32_bf16(vf, pf[1][sp], acc[3][cvt], 0, 0, 0);
                }
        }
    }

    // ---- epilogue: transpose acc through LDS -> coalesced pO stores ----
    __syncthreads();
    bf16* tbuf = &p_lds[wav][0][0][0];   // per-wave 2048 bf16 = [16 rows][128]
    const size_t pb = (size_t)ks * NB + b;
#pragma unroll
    for (int qt = 0; qt < 4; ++qt) {
        psum[qt] += __shfl_xor(psum[qt], 16);
        psum[qt] += __shfl_xor(psum[qt], 32);
#pragma unroll
        for (int cvt = 0; cvt < 8; ++cvt) {
            bf16x4 pk;
#pragma unroll
            for (int r = 0; r < 4; ++r) pk[r] = (bf16)acc[qt][cvt][r];
            const int u = (cvt * 4 + quad) ^ (l15 << 1);
            *(bf16x4*)&tbuf[l15 * 128 + u * 4] = pk;
        }
#pragma unroll
        for (int j = 0; j < 4; ++j) {
            const int row = j * 4 + (lane >> 4);
            const int g   = ((lane & 15) * 2) ^ ((row & 15) << 1);
            const bf16x8 vv = *(const bf16x8*)&tbuf[row * 128 + g * 4];
            *(bf16x8*)(pO + (pb * NN + q0 + qt * 16) * CVd + j * 512 + lane * 8) = vv;
        }
        if (quad == 0) pl[pb * NN + q0 + qt * 16 + l15] = psum[qt];
    }
}

// ---------------------------------------------------------------------------
// Fused combine + output projection (proven r9-r13).
// out = gamma*(W.ctx + W_b) + x.  grid (200, NB).
// ---------------------------------------------------------------------------
__launch_bounds__(256, 2)
__global__ void outproj_kernel(const bf16* __restrict__ pO, const float* __restrict__ pl,
                               const bf16* __restrict__ wob, const float* __restrict__ bias,
                               const float* __restrict__ x, const float* __restrict__ gam,
                               float* __restrict__ out, int KS)
{
    __shared__ __align__(16) bf16 wbuf[256 * 128];   // 64 KB
    __shared__ __align__(16) bf16 cbuf[32 * 128];    // 8 KB
    __shared__ float Lrow[32];

    const int tid  = threadIdx.x;
    const int lane = tid & 63, wav = tid >> 6;
    const int l15  = lane & 15, quad = lane >> 4;
    const int b    = blockIdx.y;
    const int n0   = blockIdx.x * 32;

    {
        const int r4 = lane >> 4;
        const int c  = lane & 15;
#pragma unroll
        for (int i = 0; i < 16; ++i) {
            const int rg = wav * 64 + i * 4;
            const int r  = rg + r4;
            const int cs = c ^ (r & 7);
            lds_cp16(wob + (size_t)r * CVd + cs * 8, &wbuf[rg * 128]);
        }
    }

    // ---- phase 1: accumulate KS chunks of pO, 16 vals/thread ----
    const int tn = tid >> 3;
    const int tc = (tid & 7) * 16;
    float vacc[16];
#pragma unroll
    for (int i = 0; i < 16; ++i) vacc[i] = 0.f;
    for (int ksi = 0; ksi < KS; ++ksi) {
        const bf16* src = pO + ((size_t)(ksi * NB + b) * NN + n0 + tn) * CVd + tc;
#pragma unroll
        for (int j = 0; j < 2; ++j) {
            const bf16x8 v = *(const bf16x8*)(src + j * 8);
#pragma unroll
            for (int e = 0; e < 8; ++e) vacc[j * 8 + e] += (float)v[e];
        }
    }
    if (tid < 32) {
        float L = 0.f;
        for (int ksi = 0; ksi < KS; ++ksi)
            L += pl[(size_t)(ksi * NB + b) * NN + n0 + tid];
        Lrow[tid] = 1.0f / L;
    }
    __syncthreads();
    {
        const float rL = Lrow[tn];
#pragma unroll
        for (int j = 0; j < 2; ++j) {
            bf16x8 o;
#pragma unroll
            for (int e = 0; e < 8; ++e) o[e] = (bf16)(vacc[j * 8 + e] * rL);
            const int c = (tid & 7) * 2 + j;
            *(bf16x8*)&cbuf[tn * 128 + ((c ^ (tn & 7)) * 8)] = o;
        }
    }
    __syncthreads();

    // ---- phase 2: MFMA, wave covers 64 co x 32 n ----
    f32x4 acc[4][2];
#pragma unroll
    for (int i = 0; i < 4; ++i)
#pragma unroll
        for (int j = 0; j < 2; ++j) acc[i][j] = (f32x4){0.f, 0.f, 0.f, 0.f};

#pragma unroll
    for (int kk = 0; kk < 4; ++kk) {
#pragma unroll
        for (int cot = 0; cot < 4; ++cot) {
            const int arow = wav * 64 + cot * 16 + l15;
            const bf16x8 af = *(const bf16x8*)&wbuf[arow * 128 + (((kk * 4 + quad) ^ (arow & 7)) * 8)];
#pragma unroll
            for (int nt = 0; nt < 2; ++nt) {
                const int brow = nt * 16 + l15;
                const bf16x8 bfc = *(const bf16x8*)&cbuf[brow * 128 + (((kk * 4 + quad) ^ (brow & 7)) * 8)];
                acc[cot][nt] = __builtin_amdgcn_mfma_f32_16x16x32_bf16(af, bfc, acc[cot][nt], 0, 0, 0);
            }
        }
    }

    const float gm = gam[0];
#pragma unroll
    for (int cot = 0; cot < 4; ++cot) {
#pragma unroll
        for (int r = 0; r < 4; ++r) {
            const int co = wav * 64 + cot * 16 + quad * 4 + r;
            const float bv = bias[256 + co];
#pragma unroll
            for (int nt = 0; nt < 2; ++nt) {
                const int n = n0 + nt * 16 + l15;
                const size_t a = ((size_t)b * COd + co) * NN + n;
                out[a] = gm * (acc[cot][nt][r] + bv) + x[a];
            }
        }
    }
}

// ---------------------------------------------------------------------------
extern "C" void kernel_launch(void* const* d_in, const int* in_sizes, int n_in,
                              void* d_out, int out_size, void* d_ws, size_t ws_size,
                              hipStream_t stream)
{
    const float* x     = (const float*)d_in[0];
    const float* y     = (const float*)d_in[1];
    const float* fk_w  = (const float*)d_in[2];
    const float* fk_g  = (const float*)d_in[3];
    const float* fk_b  = (const float*)d_in[4];
    const float* fk_m  = (const float*)d_in[5];
    const float* fk_v  = (const float*)d_in[6];
    const float* fq_w  = (const float*)d_in[7];
    const float* fq_g  = (const float*)d_in[8];
    const float* fq_b  = (const float*)d_in[9];
    const float* fq_m  = (const float*)d_in[10];
    const float* fq_v  = (const float*)d_in[11];
    const float* fv_w  = (const float*)d_in[12];
    const float* fv_b  = (const float*)d_in[13];
    const float* W_w   = (const float*)d_in[14];
    const float* W_b   = (const float*)d_in[15];
    const float* gamma = (const float*)d_in[16];
    float* out = (float*)d_out;

    char* ws = (char*)d_ws;
    size_t off = 0;
    auto carve = [&](size_t bytes) -> char* {
        char* p = ws + off;
        off = (off + bytes + 255) & ~(size_t)255;
        return p;
    };

    bf16*  kb   = (bf16*)carve((size_t)NB * NN * CKd * 2);
    bf16*  qbuf = (bf16*)carve((size_t)NB * NN * CKd * 2);
    bf16*  vb   = (bf16*)carve((size_t)NB * CVd * NN * 2);
    bf16*  wkb  = (bf16*)carve((size_t)CKd * CIN * 2);
    bf16*  wqb  = (bf16*)carve((size_t)CKd * CIN * 2);
    bf16*  wvb  = (bf16*)carve((size_t)CVd * CIN * 2);
    bf16*  wob  = (bf16*)carve((size_t)COd * CVd * 2);
    float* bias = (float*)carve(512 * 4);

    const size_t region = ws_size - off;
    const size_t per_ks = (size_t)NB * NN * CVd * 2 + (size_t)NB * NN * 4 + 512;
    int KS = 1;
    {
        const int cand[6] = {10, 8, 5, 4, 2, 1};
        for (int i = 0; i < 6; ++i)
            if ((size_t)cand[i] * per_ks <= region) { KS = cand[i]; break; }
    }
    bf16*  pO = (bf16*)carve((size_t)KS * NB * NN * CVd * 2);
    float* pl = (float*)carve((size_t)KS * NB * NN * 4);

    const dim3 blk(256);
    prep_kernel<<<386, blk, 0, stream>>>(fk_w, fk_g, fk_b, fk_m, fk_v,
                                         fq_w, fq_g, fq_b, fq_m, fq_v,
                                         fv_w, fv_b, W_w, W_b,
                                         wkb, wqb, wvb, wob, bias);
    projkqv_kernel<<<dim3(100, 4, NB), blk, 0, stream>>>(x, y, wkb, wqb, wvb, bias, kb, qbuf, vb);
    attn_kernel<<<dim3(25 * NB * KS), blk, 0, stream>>>(qbuf, kb, vb, pO, pl, KS);
    outproj_kernel<<<dim3(200, NB), blk, 0, stream>>>(pO, pl, wob, bias, x, gamma, out, KS);
}

// Round 15
// 169.851 us; speedup vs baseline: 1.3923x; 1.0085x over previous
//
#include <hip/hip_runtime.h>
#include <math.h>

#define NB   2
#define CIN  256
#define NN   6400
#define CKd  64
#define CVd  128
#define COd  256

using bf16   = __bf16;
using bf16x4 = __attribute__((ext_vector_type(4))) bf16;
using bf16x8 = __attribute__((ext_vector_type(8))) bf16;
using f32x4  = __attribute__((ext_vector_type(4))) float;

__device__ __forceinline__ void lds_cp16(const void* g, void* l) {
    __builtin_amdgcn_global_load_lds((const __attribute__((address_space(1))) void*)g,
                                     (__attribute__((address_space(3))) void*)l, 16, 0, 0);
}

// ---------------------------------------------------------------------------
// Fold BN into bf16 weights + fp32 biases.  q weights/bias pre-scaled by
// 0.125*log2(e) so attn softmax is p = exp2(s + c).
// ---------------------------------------------------------------------------
__global__ void prep_kernel(const float* __restrict__ fk_w, const float* __restrict__ fk_g,
                            const float* __restrict__ fk_b, const float* __restrict__ fk_m,
                            const float* __restrict__ fk_v,
                            const float* __restrict__ fq_w, const float* __restrict__ fq_g,
                            const float* __restrict__ fq_b, const float* __restrict__ fq_m,
                            const float* __restrict__ fq_v,
                            const float* __restrict__ fv_w, const float* __restrict__ fv_b,
                            const float* __restrict__ W_w,  const float* __restrict__ W_b,
                            bf16* __restrict__ wkb, bf16* __restrict__ wqb,
                            bf16* __restrict__ wvb, bf16* __restrict__ wob,
                            float* __restrict__ bias)
{
    const int idx = blockIdx.x * 256 + threadIdx.x;
    const float QS = 0.18033688011112042f;   // 0.125 * log2(e)
    if (idx < 16384) {
        const int co = idx >> 8;
        const float a = fk_g[co] * rsqrtf(fk_v[co] + 1e-5f);
        wkb[idx] = (bf16)(fk_w[idx] * a);
    } else if (idx < 32768) {
        const int i = idx - 16384, co = i >> 8;
        const float a = fq_g[co] * rsqrtf(fq_v[co] + 1e-5f) * QS;
        wqb[i] = (bf16)(fq_w[i] * a);
    } else if (idx < 65536) {
        const int i = idx - 32768;
        wvb[i] = (bf16)fv_w[i];
    } else if (idx < 98304) {
        const int i = idx - 65536;
        wob[i] = (bf16)W_w[i];
    } else if (idx < 98816) {
        const int j = idx - 98304;
        if (j < 64)       { const float a = fk_g[j] * rsqrtf(fk_v[j] + 1e-5f); bias[j] = fk_b[j] - fk_m[j] * a; }
        else if (j < 128) { const int c = j - 64; const float a = fq_g[c] * rsqrtf(fq_v[c] + 1e-5f); bias[j] = (fq_b[c] - fq_m[c] * a) * QS; }
        else if (j < 256) bias[j] = fv_b[j - 128];
        else              bias[j] = W_b[j - 256];
    }
}

// ---------------------------------------------------------------------------
// FUSED transpose+cvt + k/q/v projection (r14 v2 staging — proven: cut
// non-attn 116 -> 105 us).  Each thread loads 8 rows (float4 = 4 n each),
// packs 8 c per n in registers, one ds_write_b128 per n.  Chunk mapping
// (c>>3)^(n&7) matches the MFMA read path.  grid (100, 4, NB), LDS 64 KB.
// ---------------------------------------------------------------------------
__launch_bounds__(256, 2)
__global__ void projkqv_kernel(const float* __restrict__ x, const float* __restrict__ y,
                               const bf16* __restrict__ wkb, const bf16* __restrict__ wqb,
                               const bf16* __restrict__ wvb, const float* __restrict__ bias,
                               bf16* __restrict__ kb, bf16* __restrict__ qb, bf16* __restrict__ vb)
{
    __shared__ __align__(16) bf16 sbuf[64 * 256];   // src [n][c], XOR chunks
    __shared__ __align__(16) bf16 wbuf[64 * 256];   // weights, XOR chunks

    const int tid  = threadIdx.x;
    const int lane = tid & 63, wav = tid >> 6;
    const int l15  = lane & 15, quad = lane >> 4;
    const int b    = blockIdx.z, m = blockIdx.y;
    const int n0   = blockIdx.x * 64;

    const float* srcg = ((m == 0) ? x : y) + (size_t)b * CIN * NN;
    const bf16* wg    = (m == 0) ? wkb : (m == 1) ? wqb : (wvb + (size_t)(m - 2) * 64 * CIN);

    // weights DMA (2 rows / inst, source-side XOR)
    {
        const int r2  = lane >> 5;
        const int c32 = lane & 31;
#pragma unroll
        for (int i = 0; i < 8; ++i) {
            const int rg = wav * 16 + i * 2;
            const int r  = rg + r2;
            const int cs = c32 ^ (r & 7);
            lds_cp16(wg + (size_t)r * 256 + cs * 8, &wbuf[rg * 256]);
        }
    }

    // src load + cvt + packed b128 scatter (fused tcvt, register transpose)
    {
        const int nl = (tid & 15) * 4;
        const int cq = tid >> 4;            // 0..15
#pragma unroll
        for (int g = 0; g < 2; ++g) {
            const int cb = (cq + g * 16) * 8;   // 8-aligned c group
            float4 v[8];
#pragma unroll
            for (int e = 0; e < 8; ++e)
                v[e] = *(const float4*)(srcg + (size_t)(cb + e) * NN + n0 + nl);
#pragma unroll
            for (int i = 0; i < 4; ++i) {
                const int n = nl + i;
                bf16x8 pk;
#pragma unroll
                for (int e = 0; e < 8; ++e) pk[e] = (bf16)(&v[e].x)[i];
                *(bf16x8*)&sbuf[n * 256 + (((cb >> 3) ^ (n & 7)) * 8)] = pk;
            }
        }
    }
    __syncthreads();

    const int key = l15 & 7;
    f32x4 acc[4];
#pragma unroll
    for (int j = 0; j < 4; ++j) acc[j] = (f32x4){0.f, 0.f, 0.f, 0.f};

    if (m < 2) {
        const int arow = wav * 16 + l15;
#pragma unroll
        for (int k4 = 0; k4 < 32; k4 += 4) {
            const bf16x8 af = *(const bf16x8*)&sbuf[arow * 256 + ((k4 + quad) ^ key) * 8];
#pragma unroll
            for (int nt = 0; nt < 4; ++nt) {
                const int brow = nt * 16 + l15;
                const bf16x8 bfw = *(const bf16x8*)&wbuf[brow * 256 + ((k4 + quad) ^ key) * 8];
                acc[nt] = __builtin_amdgcn_mfma_f32_16x16x32_bf16(af, bfw, acc[nt], 0, 0, 0);
            }
        }
        const float* bs = bias + m * 64;
        bf16* dst = (m == 0) ? kb : qb;
        const int nb = n0 + wav * 16;
#pragma unroll
        for (int nt = 0; nt < 4; ++nt) {
            const float bv = bs[nt * 16 + l15];
#pragma unroll
            for (int r = 0; r < 4; ++r) {
                const int n = nb + quad * 4 + r;
                dst[((size_t)b * NN + n) * CKd + nt * 16 + l15] = (bf16)(acc[nt][r] + bv);
            }
        }
    } else {
        const int arow = wav * 16 + l15;
#pragma unroll
        for (int k4 = 0; k4 < 32; k4 += 4) {
            const bf16x8 af = *(const bf16x8*)&wbuf[arow * 256 + ((k4 + quad) ^ key) * 8];
#pragma unroll
            for (int nt = 0; nt < 4; ++nt) {
                const int brow = nt * 16 + l15;
                const bf16x8 bfy = *(const bf16x8*)&sbuf[brow * 256 + ((k4 + quad) ^ key) * 8];
                acc[nt] = __builtin_amdgcn_mfma_f32_16x16x32_bf16(af, bfy, acc[nt], 0, 0, 0);
            }
        }
        const int cv0 = (m - 2) * 64 + wav * 16;
#pragma unroll
        for (int r = 0; r < 4; ++r) {
            const int cv = cv0 + quad * 4 + r;
            const float bv = bias[128 + cv];
#pragma unroll
            for (int nt = 0; nt < 4; ++nt)
                vb[((size_t)b * CVd + cv) * NN + n0 + nt * 16 + l15] = (bf16)(acc[nt][r] + bv);
        }
    }
}

// ---------------------------------------------------------------------------
// Flash attention — EXACT r11/r13 kernel (proven 55.3-57.6 us band).
// r14's software-pipeline REGRESSED (57.6 -> 66.6): pack(1) wrote the same
// p_lds lines pf(0) read -> compiler lgkmcnt(0) serialization.  Reverted.
// q=64/wave in two qt-pair phases; double-buffered K/V DMA, 1 barrier/iter;
// p = exp2(s + c) (q pre-scaled by log2e).  LDS 64 KB, (256,2), no spill.
// grid 25*NB*KS (KS=10 -> 500 blocks, one balanced round).
// ---------------------------------------------------------------------------
__launch_bounds__(256, 2)
__global__ void attn_kernel(const bf16* __restrict__ qb, const bf16* __restrict__ kb,
                            const bf16* __restrict__ vb,
                            bf16* __restrict__ pO, float* __restrict__ pl, int KS)
{
    __shared__ __align__(16) bf16 kbuf[2][64 * 64];        // 16 KB
    __shared__ __align__(16) bf16 vbuf[2][128 * 64];       // 32 KB
    __shared__ __align__(16) bf16 p_lds[4][2][16][64];     // 16 KB per-wave/qt-pair

    const int lane = threadIdx.x & 63;
    const int wav  = threadIdx.x >> 6;
    const int l15  = lane & 15;
    const int quad = lane >> 4;
    const int r8   = lane >> 3;
    const int c_src = (lane & 7) ^ r8;
    const int sw   = l15 & 7;
    const int pkey = (l15 & 7) << 1;

    const int id    = blockIdx.x;
    const int ks    = id % KS;
    const int rst   = id / KS;
    const int b     = rst & 1;
    const int qtile = rst >> 1;
    const int q0    = qtile * 256 + wav * 64;

    const bf16* qrow = qb + (size_t)b * NN * CKd;
    const bf16* krow = kb + (size_t)b * NN * CKd;
    const bf16* vrow = vb + (size_t)b * CVd * NN;

    bf16x8 qf[4][2];
#pragma unroll
    for (int qt = 0; qt < 4; ++qt)
#pragma unroll
        for (int s = 0; s < 2; ++s)
            qf[qt][s] = *(const bf16x8*)(qrow + (size_t)(q0 + qt * 16 + l15) * CKd + s * 32 + quad * 8);

    f32x4 acc[4][8];
#pragma unroll
    for (int qt = 0; qt < 4; ++qt)
#pragma unroll
        for (int cv = 0; cv < 8; ++cv) acc[qt][cv] = (f32x4){0.f, 0.f, 0.f, 0.f};
    float psum[4] = {0.f, 0.f, 0.f, 0.f};

    const int t0 = (100 * ks) / KS;
    const int nt = (100 * (ks + 1)) / KS - t0;

    auto stage = [&](int t, int bi) {
        const int key0 = t * 64;
        lds_cp16(krow + (size_t)(key0 + wav * 8 + r8) * CKd + c_src * 8,
                 &kbuf[bi][(wav * 8) * 64]);
        lds_cp16(krow + (size_t)(key0 + (wav + 4) * 8 + r8) * CKd + c_src * 8,
                 &kbuf[bi][((wav + 4) * 8) * 64]);
#pragma unroll
        for (int g4 = 0; g4 < 4; ++g4) {
            const int g = wav * 4 + g4;
            lds_cp16(vrow + (size_t)(g * 8 + r8) * NN + key0 + c_src * 8,
                     &vbuf[bi][(g * 8) * 64]);
        }
    };

    stage(t0, 0);   // prologue

    for (int t = 0; t < nt; ++t) {
        __syncthreads();                    // drains DMA(t); guards buf reuse
        if (t + 1 < nt) stage(t0 + t + 1, (t + 1) & 1);
        const bf16* kcur = &kbuf[t & 1][0];
        const bf16* vcur = &vbuf[t & 1][0];

#pragma unroll
        for (int ph = 0; ph < 2; ++ph) {
            // ---- S^T = K * Q^T for this qt-pair ----
            f32x4 s4[2][4];
#pragma unroll
            for (int kt = 0; kt < 4; ++kt) {
                const int rr = kt * 16 + l15;
                const bf16x8 kf0 = *(const bf16x8*)&kcur[rr * 64 + ((quad ^ sw) * 8)];
                const bf16x8 kf1 = *(const bf16x8*)&kcur[rr * 64 + (((4 + quad) ^ sw) * 8)];
#pragma unroll
                for (int qtl = 0; qtl < 2; ++qtl) {
                    const int qt = ph * 2 + qtl;
                    f32x4 z = (f32x4){0.f, 0.f, 0.f, 0.f};
                    z = __builtin_amdgcn_mfma_f32_16x16x32_bf16(kf0, qf[qt][0], z, 0, 0, 0);
                    z = __builtin_amdgcn_mfma_f32_16x16x32_bf16(kf1, qf[qt][1], z, 0, 0, 0);
                    s4[qtl][kt] = z;
                }
            }

            // ---- p = exp2(s + c) [q pre-scaled by log2e], pack to LDS ----
#pragma unroll
            for (int qtl = 0; qtl < 2; ++qtl) {
                float ps = 0.f;
#pragma unroll
                for (int kt = 0; kt < 4; ++kt) {
                    bf16x4 pk;
#pragma unroll
                    for (int r = 0; r < 4; ++r) {
                        const float p = exp2f(s4[qtl][kt][r] - 11.541560327111707f);
                        ps += p;
                        pk[r] = (bf16)p;
                    }
                    *(bf16x4*)&p_lds[wav][qtl][l15][((kt * 4 + quad) ^ pkey) * 4] = pk;
                }
                psum[ph * 2 + qtl] += ps;
            }

            // ---- ctx^T += V^T * P^T for this qt-pair ----
#pragma unroll
            for (int sp = 0; sp < 2; ++sp) {
                const bf16x8 pf0 = *(const bf16x8*)&p_lds[wav][0][l15][((sp * 8 + quad * 2) ^ pkey) * 4];
                const bf16x8 pf1 = *(const bf16x8*)&p_lds[wav][1][l15][((sp * 8 + quad * 2) ^ pkey) * 4];
#pragma unroll
                for (int cvt = 0; cvt < 8; ++cvt) {
                    const int rr = cvt * 16 + l15;
                    const bf16x8 vf = *(const bf16x8*)&vcur[rr * 64 + (((sp * 4 + quad) ^ sw) * 8)];
                    acc[ph * 2 + 0][cvt] = __builtin_amdgcn_mfma_f32_16x16x32_bf16(vf, pf0, acc[ph * 2 + 0][cvt], 0, 0, 0);
                    acc[ph * 2 + 1][cvt] = __builtin_amdgcn_mfma_f32_16x16x32_bf16(vf, pf1, acc[ph * 2 + 1][cvt], 0, 0, 0);
                }
            }
        }
    }

    // ---- epilogue: transpose acc through LDS -> coalesced pO stores ----
    __syncthreads();
    bf16* tbuf = &p_lds[wav][0][0][0];   // per-wave 2048 bf16 = [16 rows][128]
    const size_t pb = (size_t)ks * NB + b;
#pragma unroll
    for (int qt = 0; qt < 4; ++qt) {
        psum[qt] += __shfl_xor(psum[qt], 16);
        psum[qt] += __shfl_xor(psum[qt], 32);
#pragma unroll
        for (int cvt = 0; cvt < 8; ++cvt) {
            bf16x4 pk;
#pragma unroll
            for (int r = 0; r < 4; ++r) pk[r] = (bf16)acc[qt][cvt][r];
            const int u = (cvt * 4 + quad) ^ (l15 << 1);
            *(bf16x4*)&tbuf[l15 * 128 + u * 4] = pk;
        }
#pragma unroll
        for (int j = 0; j < 4; ++j) {
            const int row = j * 4 + (lane >> 4);
            const int g   = ((lane & 15) * 2) ^ ((row & 15) << 1);
            const bf16x8 vv = *(const bf16x8*)&tbuf[row * 128 + g * 4];
            *(bf16x8*)(pO + (pb * NN + q0 + qt * 16) * CVd + j * 512 + lane * 8) = vv;
        }
        if (quad == 0) pl[pb * NN + q0 + qt * 16 + l15] = psum[qt];
    }
}

// ---------------------------------------------------------------------------
// Fused combine + output projection (proven r9-r14).
// out = gamma*(W.ctx + W_b) + x.  grid (200, NB).
// ---------------------------------------------------------------------------
__launch_bounds__(256, 2)
__global__ void outproj_kernel(const bf16* __restrict__ pO, const float* __restrict__ pl,
                               const bf16* __restrict__ wob, const float* __restrict__ bias,
                               const float* __restrict__ x, const float* __restrict__ gam,
                               float* __restrict__ out, int KS)
{
    __shared__ __align__(16) bf16 wbuf[256 * 128];   // 64 KB
    __shared__ __align__(16) bf16 cbuf[32 * 128];    // 8 KB
    __shared__ float Lrow[32];

    const int tid  = threadIdx.x;
    const int lane = tid & 63, wav = tid >> 6;
    const int l15  = lane & 15, quad = lane >> 4;
    const int b    = blockIdx.y;
    const int n0   = blockIdx.x * 32;

    {
        const int r4 = lane >> 4;
        const int c  = lane & 15;
#pragma unroll
        for (int i = 0; i < 16; ++i) {
            const int rg = wav * 64 + i * 4;
            const int r  = rg + r4;
            const int cs = c ^ (r & 7);
            lds_cp16(wob + (size_t)r * CVd + cs * 8, &wbuf[rg * 128]);
        }
    }

    // ---- phase 1: accumulate KS chunks of pO, 16 vals/thread ----
    const int tn = tid >> 3;
    const int tc = (tid & 7) * 16;
    float vacc[16];
#pragma unroll
    for (int i = 0; i < 16; ++i) vacc[i] = 0.f;
    for (int ksi = 0; ksi < KS; ++ksi) {
        const bf16* src = pO + ((size_t)(ksi * NB + b) * NN + n0 + tn) * CVd + tc;
#pragma unroll
        for (int j = 0; j < 2; ++j) {
            const bf16x8 v = *(const bf16x8*)(src + j * 8);
#pragma unroll
            for (int e = 0; e < 8; ++e) vacc[j * 8 + e] += (float)v[e];
        }
    }
    if (tid < 32) {
        float L = 0.f;
        for (int ksi = 0; ksi < KS; ++ksi)
            L += pl[(size_t)(ksi * NB + b) * NN + n0 + tid];
        Lrow[tid] = 1.0f / L;
    }
    __syncthreads();
    {
        const float rL = Lrow[tn];
#pragma unroll
        for (int j = 0; j < 2; ++j) {
            bf16x8 o;
#pragma unroll
            for (int e = 0; e < 8; ++e) o[e] = (bf16)(vacc[j * 8 + e] * rL);
            const int c = (tid & 7) * 2 + j;
            *(bf16x8*)&cbuf[tn * 128 + ((c ^ (tn & 7)) * 8)] = o;
        }
    }
    __syncthreads();

    // ---- phase 2: MFMA, wave covers 64 co x 32 n ----
    f32x4 acc[4][2];
#pragma unroll
    for (int i = 0; i < 4; ++i)
#pragma unroll
        for (int j = 0; j < 2; ++j) acc[i][j] = (f32x4){0.f, 0.f, 0.f, 0.f};

#pragma unroll
    for (int kk = 0; kk < 4; ++kk) {
#pragma unroll
        for (int cot = 0; cot < 4; ++cot) {
            const int arow = wav * 64 + cot * 16 + l15;
            const bf16x8 af = *(const bf16x8*)&wbuf[arow * 128 + (((kk * 4 + quad) ^ (arow & 7)) * 8)];
#pragma unroll
            for (int nt = 0; nt < 2; ++nt) {
                const int brow = nt * 16 + l15;
                const bf16x8 bfc = *(const bf16x8*)&cbuf[brow * 128 + (((kk * 4 + quad) ^ (brow & 7)) * 8)];
                acc[cot][nt] = __builtin_amdgcn_mfma_f32_16x16x32_bf16(af, bfc, acc[cot][nt], 0, 0, 0);
            }
        }
    }

    const float gm = gam[0];
#pragma unroll
    for (int cot = 0; cot < 4; ++cot) {
#pragma unroll
        for (int r = 0; r < 4; ++r) {
            const int co = wav * 64 + cot * 16 + quad * 4 + r;
            const float bv = bias[256 + co];
#pragma unroll
            for (int nt = 0; nt < 2; ++nt) {
                const int n = n0 + nt * 16 + l15;
                const size_t a = ((size_t)b * COd + co) * NN + n;
                out[a] = gm * (acc[cot][nt][r] + bv) + x[a];
            }
        }
    }
}

// ---------------------------------------------------------------------------
extern "C" void kernel_launch(void* const* d_in, const int* in_sizes, int n_in,
                              void* d_out, int out_size, void* d_ws, size_t ws_size,
                              hipStream_t stream)
{
    const float* x     = (const float*)d_in[0];
    const float* y     = (const float*)d_in[1];
    const float* fk_w  = (const float*)d_in[2];
    const float* fk_g  = (const float*)d_in[3];
    const float* fk_b  = (const float*)d_in[4];
    const float* fk_m  = (const float*)d_in[5];
    const float* fk_v  = (const float*)d_in[6];
    const float* fq_w  = (const float*)d_in[7];
    const float* fq_g  = (const float*)d_in[8];
    const float* fq_b  = (const float*)d_in[9];
    const float* fq_m  = (const float*)d_in[10];
    const float* fq_v  = (const float*)d_in[11];
    const float* fv_w  = (const float*)d_in[12];
    const float* fv_b  = (const float*)d_in[13];
    const float* W_w   = (const float*)d_in[14];
    const float* W_b   = (const float*)d_in[15];
    const float* gamma = (const float*)d_in[16];
    float* out = (float*)d_out;

    char* ws = (char*)d_ws;
    size_t off = 0;
    auto carve = [&](size_t bytes) -> char* {
        char* p = ws + off;
        off = (off + bytes + 255) & ~(size_t)255;
        return p;
    };

    bf16*  kb   = (bf16*)carve((size_t)NB * NN * CKd * 2);
    bf16*  qbuf = (bf16*)carve((size_t)NB * NN * CKd * 2);
    bf16*  vb   = (bf16*)carve((size_t)NB * CVd * NN * 2);
    bf16*  wkb  = (bf16*)carve((size_t)CKd * CIN * 2);
    bf16*  wqb  = (bf16*)carve((size_t)CKd * CIN * 2);
    bf16*  wvb  = (bf16*)carve((size_t)CVd * CIN * 2);
    bf16*  wob  = (bf16*)carve((size_t)COd * CVd * 2);
    float* bias = (float*)carve(512 * 4);

    const size_t region = ws_size - off;
    const size_t per_ks = (size_t)NB * NN * CVd * 2 + (size_t)NB * NN * 4 + 512;
    int KS = 1;
    {
        const int cand[6] = {10, 8, 5, 4, 2, 1};
        for (int i = 0; i < 6; ++i)
            if ((size_t)cand[i] * per_ks <= region) { KS = cand[i]; break; }
    }
    bf16*  pO = (bf16*)carve((size_t)KS * NB * NN * CVd * 2);
    float* pl = (float*)carve((size_t)KS * NB * NN * 4);

    const dim3 blk(256);
    prep_kernel<<<386, blk, 0, stream>>>(fk_w, fk_g, fk_b, fk_m, fk_v,
                                         fq_w, fq_g, fq_b, fq_m, fq_v,
                                         fv_w, fv_b, W_w, W_b,
                                         wkb, wqb, wvb, wob, bias);
    projkqv_kernel<<<dim3(100, 4, NB), blk, 0, stream>>>(x, y, wkb, wqb, wvb, bias, kb, qbuf, vb);
    attn_kernel<<<dim3(25 * NB * KS), blk, 0, stream>>>(qbuf, kb, vb, pO, pl, KS);
    outproj_kernel<<<dim3(200, NB), blk, 0, stream>>>(pO, pl, wob, bias, x, gamma, out, KS);
}